// Round 18
// baseline (384.989 us; speedup 1.0000x reference)
//
#include <hip/hip_runtime.h>

#define NN 50000
#define EE 800000
#define FF 128
#define DD 64
#define GG 512

typedef unsigned short u16;

// ---------------- bf16 storage helpers (compute stays fp32) ----------------

__device__ __forceinline__ float bf2f(u16 h) {
    unsigned u = ((unsigned)h) << 16;
    return __builtin_bit_cast(float, u);
}
__device__ __forceinline__ u16 f2bf(float f) {
    unsigned u = __builtin_bit_cast(unsigned, f);
    u += 0x7fffu + ((u >> 16) & 1u);   // RNE
    return (u16)(u >> 16);
}
__device__ __forceinline__ float4 ldbf4(const u16* p) {
    uint2 v = *(const uint2*)p;
    float4 r;
    r.x = bf2f((u16)(v.x & 0xffffu)); r.y = bf2f((u16)(v.x >> 16));
    r.z = bf2f((u16)(v.y & 0xffffu)); r.w = bf2f((u16)(v.y >> 16));
    return r;
}
__device__ __forceinline__ float4 bfu2f4(uint2 v) {
    float4 r;
    r.x = bf2f((u16)(v.x & 0xffffu)); r.y = bf2f((u16)(v.x >> 16));
    r.z = bf2f((u16)(v.y & 0xffffu)); r.w = bf2f((u16)(v.y >> 16));
    return r;
}
__device__ __forceinline__ void stbf4(u16* p, float4 v) {
    uint2 o;
    o.x = (unsigned)f2bf(v.x) | ((unsigned)f2bf(v.y) << 16);
    o.y = (unsigned)f2bf(v.z) | ((unsigned)f2bf(v.w) << 16);
    *(uint2*)p = o;
}
__device__ __forceinline__ void fma4(float4& a, const float4& w, float s) {
    a.x = fmaf(s, w.x, a.x); a.y = fmaf(s, w.y, a.y);
    a.z = fmaf(s, w.z, a.z); a.w = fmaf(s, w.w, a.w);
}
__device__ __forceinline__ void add4(float4& a, float4 b) {
    a.x += b.x; a.y += b.y; a.z += b.z; a.w += b.w;
}

// 8-wide unrolled neighbor gather: 8 independent loads in flight per group
__device__ __forceinline__ void gather16(float4& acc, const u16* __restrict__ in,
                                         const u16* __restrict__ csr, int e0s, int e1s,
                                         int l16, int gbase) {
    for (int e0 = e0s; e0 < e1s; e0 += 16) {
        int cnt = min(16, e1s - e0);
        int srcv = (l16 < cnt) ? (int)csr[e0 + l16] : 0;
        int j = 0;
        for (; j + 8 <= cnt; j += 8) {
            int i0 = __shfl(srcv, gbase + j);
            int i1 = __shfl(srcv, gbase + j + 1);
            int i2 = __shfl(srcv, gbase + j + 2);
            int i3 = __shfl(srcv, gbase + j + 3);
            int i4 = __shfl(srcv, gbase + j + 4);
            int i5 = __shfl(srcv, gbase + j + 5);
            int i6 = __shfl(srcv, gbase + j + 6);
            int i7 = __shfl(srcv, gbase + j + 7);
            float4 h0 = ldbf4(in + (size_t)i0 * 64 + l16 * 4);
            float4 h1 = ldbf4(in + (size_t)i1 * 64 + l16 * 4);
            float4 h2 = ldbf4(in + (size_t)i2 * 64 + l16 * 4);
            float4 h3 = ldbf4(in + (size_t)i3 * 64 + l16 * 4);
            float4 h4 = ldbf4(in + (size_t)i4 * 64 + l16 * 4);
            float4 h5 = ldbf4(in + (size_t)i5 * 64 + l16 * 4);
            float4 h6 = ldbf4(in + (size_t)i6 * 64 + l16 * 4);
            float4 h7 = ldbf4(in + (size_t)i7 * 64 + l16 * 4);
            add4(h0, h1); add4(h2, h3); add4(h4, h5); add4(h6, h7);
            add4(h0, h2); add4(h4, h6);
            add4(h0, h4);
            add4(acc, h0);
        }
        for (; j + 4 <= cnt; j += 4) {
            int i0 = __shfl(srcv, gbase + j);
            int i1 = __shfl(srcv, gbase + j + 1);
            int i2 = __shfl(srcv, gbase + j + 2);
            int i3 = __shfl(srcv, gbase + j + 3);
            float4 h0 = ldbf4(in + (size_t)i0 * 64 + l16 * 4);
            float4 h1 = ldbf4(in + (size_t)i1 * 64 + l16 * 4);
            float4 h2 = ldbf4(in + (size_t)i2 * 64 + l16 * 4);
            float4 h3 = ldbf4(in + (size_t)i3 * 64 + l16 * 4);
            add4(h0, h1); add4(h2, h3); add4(h0, h2);
            add4(acc, h0);
        }
        for (; j < cnt; ++j) {
            int s = __shfl(srcv, gbase + j);
            float4 hv = ldbf4(in + (size_t)s * 64 + l16 * 4);
            add4(acc, hv);
        }
    }
}

// ---------------- init: zero cursor/stats + segment bounds (merged) ----------------

__global__ void init_k(int* __restrict__ cursor, float* __restrict__ stats_all,
                       const int* __restrict__ batch, int* __restrict__ segstart) {
    int i = blockIdx.x * blockDim.x + threadIdx.x;
    if (i < NN) cursor[i] = 0;
    if (i < 7 * 128) stats_all[i] = 0.f;
    if (i <= GG) {
        int lo = 0, hi = NN;
        while (lo < hi) {
            int mid = (lo + hi) >> 1;
            if (batch[mid] < i) lo = mid + 1; else hi = mid;
        }
        segstart[i] = lo;
    }
}

// ---------------- CSR build (counting sort by dst), 4 edges/thread ----------------

__global__ void hist_k(const int* __restrict__ dst, int* __restrict__ deg) {
    int e = (blockIdx.x * 256 + threadIdx.x) * 4;
    if (e + 4 <= EE) {
        int4 d = *(const int4*)&dst[e];
        atomicAdd(&deg[d.x], 1); atomicAdd(&deg[d.y], 1);
        atomicAdd(&deg[d.z], 1); atomicAdd(&deg[d.w], 1);
    } else {
        for (; e < EE; ++e) atomicAdd(&deg[dst[e]], 1);
    }
}

__global__ __launch_bounds__(1024) void scanA_k(const int* __restrict__ deg,
                                                int* __restrict__ rowstart,
                                                int* __restrict__ blocksum) {
    __shared__ int buf[1024];
    int tid = threadIdx.x;
    int base = blockIdx.x * 1024;
    int v = (base + tid < NN) ? deg[base + tid] : 0;
    buf[tid] = v;
    __syncthreads();
    for (int o = 1; o < 1024; o <<= 1) {
        int t = (tid >= o) ? buf[tid - o] : 0;
        __syncthreads();
        buf[tid] += t;
        __syncthreads();
    }
    if (base + tid < NN) rowstart[base + tid + 1] = buf[tid];
    if (tid == 1023) blocksum[blockIdx.x] = buf[1023];
}

__global__ void scanB_k(const int* __restrict__ blocksum, int* __restrict__ bofs, int nb) {
    int lane = threadIdx.x;  // 64 threads
    int v = (lane < nb) ? blocksum[lane] : 0;
    int orig = v;
    for (int o = 1; o < 64; o <<= 1) {
        int t = __shfl_up(v, o);
        if (lane >= o) v += t;
    }
    if (lane < nb) bofs[lane] = v - orig;
}

__global__ void scanC_k(int* __restrict__ rowstart, const int* __restrict__ bofs,
                        int* __restrict__ cursor) {
    int i = blockIdx.x * blockDim.x + threadIdx.x;
    if (i >= NN) return;
    int val = rowstart[i + 1] + bofs[i >> 10];
    rowstart[i + 1] = val;
    if (i + 1 < NN) cursor[i + 1] = val;
    if (i == 0) { rowstart[0] = 0; cursor[0] = 0; }
}

__global__ void fill_k(const int* __restrict__ src, const int* __restrict__ dst,
                       int* __restrict__ cursor, u16* __restrict__ csr16) {
    int e = (blockIdx.x * 256 + threadIdx.x) * 4;
    if (e + 4 <= EE) {
        int4 d = *(const int4*)&dst[e];
        int4 s = *(const int4*)&src[e];
        int p0 = atomicAdd(&cursor[d.x], 1);
        int p1 = atomicAdd(&cursor[d.y], 1);
        int p2 = atomicAdd(&cursor[d.z], 1);
        int p3 = atomicAdd(&cursor[d.w], 1);
        csr16[p0] = (u16)s.x; csr16[p1] = (u16)s.y;
        csr16[p2] = (u16)s.z; csr16[p3] = (u16)s.w;
    } else {
        for (; e < EE; ++e) { int p = atomicAdd(&cursor[dst[e]], 1); csr16[p] = (u16)src[e]; }
    }
}

// ---------------- layer-0 first GEMM: out_bf16[NN x 64] = x[NN x 128] @ W1(bf16) ----------------
// 16-row tiles, bf16 W in LDS (16KB) -> ~6 blocks/CU, grid 3125.  (verified in round 12)

__global__ __launch_bounds__(256) void gemm128_k(const float* __restrict__ x,
                                                 const float* __restrict__ W,
                                                 u16* __restrict__ out) {
    __shared__ u16 sW16[128 * 64];
    __shared__ float sIn[16 * 132];
    const int tid = threadIdx.x;
    for (int i = tid * 4; i < 128 * 64; i += 1024) {
        float4 w = *(const float4*)(W + i);
        uint2 pk;
        pk.x = (unsigned)f2bf(w.x) | ((unsigned)f2bf(w.y) << 16);
        pk.y = (unsigned)f2bf(w.z) | ((unsigned)f2bf(w.w) << 16);
        *(uint2*)&sW16[i] = pk;
    }
    const int tile = blockIdx.x * 16;
    const int nrows = min(16, NN - tile);
    for (int i = tid; i < 16 * 32; i += 256) {
        int rr = i >> 5, kk = (i & 31) * 4;
        float4 t = (rr < nrows) ? *(const float4*)(x + (size_t)(tile + rr) * 128 + kk)
                                : make_float4(0.f, 0.f, 0.f, 0.f);
        *(float4*)&sIn[rr * 132 + kk] = t;
    }
    __syncthreads();
    int rg = tid >> 4, c0 = (tid & 15) << 2;
    float4 acc = make_float4(0.f, 0.f, 0.f, 0.f);
#pragma unroll 4
    for (int k4 = 0; k4 < 32; ++k4) {
        float4 av = *(const float4*)&sIn[rg * 132 + k4 * 4];
        float as[4] = {av.x, av.y, av.z, av.w};
#pragma unroll
        for (int kk = 0; kk < 4; ++kk) {
            uint2 wp = *(const uint2*)&sW16[(k4 * 4 + kk) * 64 + c0];
            fma4(acc, bfu2f4(wp), as[kk]);
        }
    }
    if (rg < nrows) stbf4(out + (size_t)(tile + rg) * 64 + c0, acc);
}

// ---------------- fused gather + W2 GEMM (layer 0 tail), 64-row tiles ----------------

__global__ __launch_bounds__(256) void agg_gemm_k(
    const u16* __restrict__ in,
    const int* __restrict__ rowstart, const u16* __restrict__ csr,
    const float* __restrict__ bias1,
    const float* __restrict__ W2, const float* __restrict__ bias2,
    u16* __restrict__ out, float* __restrict__ gstats)
{
    constexpr int KP = 68;
    __shared__ float sW[64 * 64];
    __shared__ float sIn[64 * KP];
    __shared__ float sStat[128];
    const int tid = threadIdx.x;

    for (int i = tid; i < 64 * 16; i += 256) ((float4*)sW)[i] = ((const float4*)W2)[i];

    const int tile = blockIdx.x * 64;
    const int nrows = min(64, NN - tile);
    const int l16 = tid & 15, gbase = tid & 48, grp = tid >> 4;
    float4 b1v = ((const float4*)bias1)[l16];
    for (int r = grp; r < nrows; r += 16) {
        int node = tile + r;
        float4 acc = ldbf4(in + (size_t)node * 64 + l16 * 4);
        gather16(acc, in, csr, rowstart[node], rowstart[node + 1], l16, gbase);
        acc.x = fmaxf(acc.x + b1v.x, 0.f); acc.y = fmaxf(acc.y + b1v.y, 0.f);
        acc.z = fmaxf(acc.z + b1v.z, 0.f); acc.w = fmaxf(acc.w + b1v.w, 0.f);
        *(float4*)&sIn[r * KP + l16 * 4] = acc;
    }
    __syncthreads();

    const int rg = (tid >> 4) * 4, c0 = (tid & 15) << 2;
    float4 bb = *(const float4*)&bias2[c0];
    float4 acc[4];
#pragma unroll
    for (int j = 0; j < 4; ++j) acc[j] = bb;
#pragma unroll 2
    for (int k4 = 0; k4 < 16; ++k4) {
        float4 av[4];
#pragma unroll
        for (int j = 0; j < 4; ++j) av[j] = *(const float4*)&sIn[(rg + j) * KP + k4 * 4];
        const float* wp = &sW[k4 * 4 * 64 + c0];
        float4 w0 = *(const float4*)(wp);
        float4 w1 = *(const float4*)(wp + 64);
        float4 w2 = *(const float4*)(wp + 128);
        float4 w3 = *(const float4*)(wp + 192);
#pragma unroll
        for (int j = 0; j < 4; ++j) {
            fma4(acc[j], w0, av[j].x); fma4(acc[j], w1, av[j].y);
            fma4(acc[j], w2, av[j].z); fma4(acc[j], w3, av[j].w);
        }
    }
#pragma unroll
    for (int j = 0; j < 4; ++j) {
        acc[j].x = fmaxf(acc[j].x, 0.f); acc[j].y = fmaxf(acc[j].y, 0.f);
        acc[j].z = fmaxf(acc[j].z, 0.f); acc[j].w = fmaxf(acc[j].w, 0.f);
        if (rg + j < nrows) stbf4(out + (size_t)(tile + rg + j) * 64 + c0, acc[j]);
    }
    if (tid < 128) sStat[tid] = 0.f;
    __syncthreads();
    float sx = 0, sy = 0, sz = 0, sw = 0, qx = 0, qy = 0, qz = 0, qw = 0;
#pragma unroll
    for (int j = 0; j < 4; ++j) {
        if (rg + j < nrows) {
            sx += acc[j].x; sy += acc[j].y; sz += acc[j].z; sw += acc[j].w;
            qx += acc[j].x * acc[j].x; qy += acc[j].y * acc[j].y;
            qz += acc[j].z * acc[j].z; qw += acc[j].w * acc[j].w;
        }
    }
    atomicAdd(&sStat[c0 + 0], sx); atomicAdd(&sStat[c0 + 1], sy);
    atomicAdd(&sStat[c0 + 2], sz); atomicAdd(&sStat[c0 + 3], sw);
    atomicAdd(&sStat[64 + c0 + 0], qx); atomicAdd(&sStat[64 + c0 + 1], qy);
    atomicAdd(&sStat[64 + c0 + 2], qz); atomicAdd(&sStat[64 + c0 + 3], qw);
    __syncthreads();
    if (tid < 128) atomicAdd(&gstats[tid], sStat[tid]);
}

// ---------------- fully fused GIN layer (layers 1,2), 64-row tiles ----------------

__global__ __launch_bounds__(256) void fused_layer_k(
    const u16* __restrict__ in,
    const int* __restrict__ rowstart, const u16* __restrict__ csr,
    const float* __restrict__ bnst, const float* __restrict__ gam, const float* __restrict__ bet,
    const float* __restrict__ W1, const float* __restrict__ b1,
    const float* __restrict__ W2, const float* __restrict__ b2,
    u16* __restrict__ out, float* __restrict__ gstats)
{
    constexpr int KP = 68;
    __shared__ float sW[64 * 64];      // W1 then reloaded with W2
    __shared__ float sAgg[64 * KP];
    __shared__ float sStat[128];
    __shared__ float aL[64], dL[64];
    const int tid = threadIdx.x;

    for (int i = tid; i < 64 * 16; i += 256) ((float4*)sW)[i] = ((const float4*)W1)[i];
    if (tid < 64) {
        float m = bnst[tid] * (1.f / NN);
        float v = bnst[64 + tid] * (1.f / NN) - m * m;
        float a = rsqrtf(v + 1e-5f) * gam[tid];
        aL[tid] = a;
        dL[tid] = bet[tid] - m * a;
    }
    __syncthreads();

    const int tile = blockIdx.x * 64;
    const int nrows = min(64, NN - tile);
    const int l16 = tid & 15, gbase = tid & 48, grp = tid >> 4;
    float4 av4 = *(const float4*)&aL[l16 * 4];
    float4 dv4 = *(const float4*)&dL[l16 * 4];
    for (int r = grp; r < nrows; r += 16) {
        int node = tile + r;
        int e0s = rowstart[node], e1s = rowstart[node + 1];
        float4 acc = ldbf4(in + (size_t)node * 64 + l16 * 4);
        gather16(acc, in, csr, e0s, e1s, l16, gbase);
        float dp1 = (float)(e1s - e0s + 1);
        acc.x = fmaf(av4.x, acc.x, dp1 * dv4.x);
        acc.y = fmaf(av4.y, acc.y, dp1 * dv4.y);
        acc.z = fmaf(av4.z, acc.z, dp1 * dv4.z);
        acc.w = fmaf(av4.w, acc.w, dp1 * dv4.w);
        *(float4*)&sAgg[r * KP + l16 * 4] = acc;
    }
    __syncthreads();

    const int rg = (tid >> 4) * 4, c0 = (tid & 15) << 2;
    float4 t[4];
    {
        float4 bb = *(const float4*)&b1[c0];
#pragma unroll
        for (int j = 0; j < 4; ++j) t[j] = bb;
#pragma unroll 2
        for (int k4 = 0; k4 < 16; ++k4) {
            float4 a0[4];
#pragma unroll
            for (int j = 0; j < 4; ++j) a0[j] = *(const float4*)&sAgg[(rg + j) * KP + k4 * 4];
            const float* wp = &sW[k4 * 4 * 64 + c0];
            float4 w0 = *(const float4*)(wp);
            float4 w1 = *(const float4*)(wp + 64);
            float4 w2 = *(const float4*)(wp + 128);
            float4 w3 = *(const float4*)(wp + 192);
#pragma unroll
            for (int j = 0; j < 4; ++j) {
                fma4(t[j], w0, a0[j].x); fma4(t[j], w1, a0[j].y);
                fma4(t[j], w2, a0[j].z); fma4(t[j], w3, a0[j].w);
            }
        }
#pragma unroll
        for (int j = 0; j < 4; ++j) {
            t[j].x = fmaxf(t[j].x, 0.f); t[j].y = fmaxf(t[j].y, 0.f);
            t[j].z = fmaxf(t[j].z, 0.f); t[j].w = fmaxf(t[j].w, 0.f);
        }
    }
    __syncthreads();

    for (int i = tid; i < 64 * 16; i += 256) ((float4*)sW)[i] = ((const float4*)W2)[i];
#pragma unroll
    for (int j = 0; j < 4; ++j) *(float4*)&sAgg[(rg + j) * KP + c0] = t[j];
    __syncthreads();

    float4 acc[4];
    {
        float4 bb = *(const float4*)&b2[c0];
#pragma unroll
        for (int j = 0; j < 4; ++j) acc[j] = bb;
#pragma unroll 2
        for (int k4 = 0; k4 < 16; ++k4) {
            float4 a0[4];
#pragma unroll
            for (int j = 0; j < 4; ++j) a0[j] = *(const float4*)&sAgg[(rg + j) * KP + k4 * 4];
            const float* wp = &sW[k4 * 4 * 64 + c0];
            float4 w0 = *(const float4*)(wp);
            float4 w1 = *(const float4*)(wp + 64);
            float4 w2 = *(const float4*)(wp + 128);
            float4 w3 = *(const float4*)(wp + 192);
#pragma unroll
            for (int j = 0; j < 4; ++j) {
                fma4(acc[j], w0, a0[j].x); fma4(acc[j], w1, a0[j].y);
                fma4(acc[j], w2, a0[j].z); fma4(acc[j], w3, a0[j].w);
            }
        }
    }
#pragma unroll
    for (int j = 0; j < 4; ++j) {
        acc[j].x = fmaxf(acc[j].x, 0.f); acc[j].y = fmaxf(acc[j].y, 0.f);
        acc[j].z = fmaxf(acc[j].z, 0.f); acc[j].w = fmaxf(acc[j].w, 0.f);
        if (rg + j < nrows) stbf4(out + (size_t)(tile + rg + j) * 64 + c0, acc[j]);
    }
    if (tid < 128) sStat[tid] = 0.f;
    __syncthreads();
    float sx = 0, sy = 0, sz = 0, sw = 0, qx = 0, qy = 0, qz = 0, qw = 0;
#pragma unroll
    for (int j = 0; j < 4; ++j) {
        if (rg + j < nrows) {
            sx += acc[j].x; sy += acc[j].y; sz += acc[j].z; sw += acc[j].w;
            qx += acc[j].x * acc[j].x; qy += acc[j].y * acc[j].y;
            qz += acc[j].z * acc[j].z; qw += acc[j].w * acc[j].w;
        }
    }
    atomicAdd(&sStat[c0 + 0], sx); atomicAdd(&sStat[c0 + 1], sy);
    atomicAdd(&sStat[c0 + 2], sz); atomicAdd(&sStat[c0 + 3], sw);
    atomicAdd(&sStat[64 + c0 + 0], qx); atomicAdd(&sStat[64 + c0 + 1], qy);
    atomicAdd(&sStat[64 + c0 + 2], qz); atomicAdd(&sStat[64 + c0 + 3], qw);
    __syncthreads();
    if (tid < 128) atomicAdd(&gstats[tid], sStat[tid]);
}

// ---------------- skinny fp32 GEMM (K=64 paths), templated bf16 in/out ----------------

template<int K, bool BIAS, bool RELU, bool STATS, bool ROWSCALE, bool BNIN, bool DUAL,
         bool INBF, bool OUTBF>
__global__ __launch_bounds__(256) void gemm_k(
    const void* __restrict__ in, const float* __restrict__ W, const float* __restrict__ Wb,
    const float* __restrict__ bias, const float* __restrict__ bias2,
    void* __restrict__ out, void* __restrict__ out2, int rows,
    float* __restrict__ gstats, float* __restrict__ gstats2,
    const float* __restrict__ attn, const float* __restrict__ noise,
    const float* __restrict__ bnstats, const float* __restrict__ gamma,
    const float* __restrict__ beta)
{
    constexpr int RPT = (K == 128) ? 2 : 4;
    constexpr int TR  = 16 * RPT;
    constexpr int KP  = K + 4;
    constexpr int SS  = DUAL ? 256 : 128;
    __shared__ float sW[K * 64];
    __shared__ float sWb[DUAL ? K * 64 : 4];
    __shared__ float sIn[TR * KP];
    __shared__ float sStat[STATS ? SS : 4];
    __shared__ float sA[BNIN ? 64 : 4];
    __shared__ float sD[BNIN ? 64 : 4];

    const int tid = threadIdx.x;
    for (int i = tid; i < K * 16; i += 256) ((float4*)sW)[i] = ((const float4*)W)[i];
    if (DUAL)
        for (int i = tid; i < K * 16; i += 256) ((float4*)sWb)[i] = ((const float4*)Wb)[i];
    if (BNIN && tid < 64) {
        float m   = bnstats[tid] * (1.f / NN);
        float v   = bnstats[64 + tid] * (1.f / NN) - m * m;
        float a   = rsqrtf(v + 1e-5f) * gamma[tid];
        sA[tid] = a;
        sD[tid] = beta[tid] - m * a;
    }

    int rg = (tid >> 4) * RPT;
    int c0 = (tid & 15) << 2;
    float4 bb  = make_float4(0.f, 0.f, 0.f, 0.f);
    float4 bb2 = make_float4(0.f, 0.f, 0.f, 0.f);
    if (BIAS) bb = *(const float4*)&bias[c0];
    if (BIAS && DUAL) bb2 = *(const float4*)&bias2[c0];

    for (int tile = blockIdx.x * TR; tile < rows; tile += gridDim.x * TR) {
        __syncthreads();
        int nrows = min(TR, rows - tile);
        const float4* igf = INBF ? nullptr : (const float4*)((const float*)in + (size_t)tile * K);
        const u16*    igb = INBF ? ((const u16*)in + (size_t)tile * K) : nullptr;
        const float4* ng  = ROWSCALE ? (const float4*)(noise + (size_t)tile * K) : nullptr;
        for (int i = tid; i < nrows * (K / 4); i += 256) {
            int rr = i / (K / 4), kk = (i - rr * (K / 4)) * 4;
            float4 t = INBF ? ldbf4(igb + i * 4) : igf[i];
            if (BNIN) {
                t.x = fmaf(sA[kk + 0], t.x, sD[kk + 0]);
                t.y = fmaf(sA[kk + 1], t.y, sD[kk + 1]);
                t.z = fmaf(sA[kk + 2], t.z, sD[kk + 2]);
                t.w = fmaf(sA[kk + 3], t.w, sD[kk + 3]);
            }
            if (ROWSCALE) {
                float4 nv = ng[i];
                float at = attn[tile + rr];
                t.x = fmaf(at, t.x, nv.x); t.y = fmaf(at, t.y, nv.y);
                t.z = fmaf(at, t.z, nv.z); t.w = fmaf(at, t.w, nv.w);
            }
            *(float4*)&sIn[rr * KP + kk] = t;
        }
        __syncthreads();

        float4 acc[RPT];
        float4 acc2[DUAL ? RPT : 1];
#pragma unroll
        for (int j = 0; j < RPT; ++j) acc[j] = bb;
        if (DUAL) {
#pragma unroll
            for (int j = 0; j < RPT; ++j) acc2[j] = bb2;
        }
#pragma unroll 2
        for (int k4 = 0; k4 < K / 4; ++k4) {
            float4 av[RPT];
#pragma unroll
            for (int j = 0; j < RPT; ++j)
                av[j] = *(const float4*)&sIn[(rg + j) * KP + k4 * 4];
            const float* wp = &sW[k4 * 4 * 64 + c0];
            float4 w0 = *(const float4*)(wp);
            float4 w1 = *(const float4*)(wp + 64);
            float4 w2 = *(const float4*)(wp + 128);
            float4 w3 = *(const float4*)(wp + 192);
#pragma unroll
            for (int j = 0; j < RPT; ++j) {
                fma4(acc[j], w0, av[j].x); fma4(acc[j], w1, av[j].y);
                fma4(acc[j], w2, av[j].z); fma4(acc[j], w3, av[j].w);
            }
            if (DUAL) {
                const float* wq = &sWb[k4 * 4 * 64 + c0];
                float4 u0 = *(const float4*)(wq);
                float4 u1 = *(const float4*)(wq + 64);
                float4 u2 = *(const float4*)(wq + 128);
                float4 u3 = *(const float4*)(wq + 192);
#pragma unroll
                for (int j = 0; j < RPT; ++j) {
                    fma4(acc2[j], u0, av[j].x); fma4(acc2[j], u1, av[j].y);
                    fma4(acc2[j], u2, av[j].z); fma4(acc2[j], u3, av[j].w);
                }
            }
        }
        if (RELU) {
#pragma unroll
            for (int j = 0; j < RPT; ++j) {
                acc[j].x = fmaxf(acc[j].x, 0.f); acc[j].y = fmaxf(acc[j].y, 0.f);
                acc[j].z = fmaxf(acc[j].z, 0.f); acc[j].w = fmaxf(acc[j].w, 0.f);
                if (DUAL) {
                    acc2[j].x = fmaxf(acc2[j].x, 0.f); acc2[j].y = fmaxf(acc2[j].y, 0.f);
                    acc2[j].z = fmaxf(acc2[j].z, 0.f); acc2[j].w = fmaxf(acc2[j].w, 0.f);
                }
            }
        }
#pragma unroll
        for (int j = 0; j < RPT; ++j) {
            int r = rg + j;
            if (r < nrows) {
                if (OUTBF) stbf4((u16*)out + (size_t)(tile + r) * 64 + c0, acc[j]);
                else *(float4*)((float*)out + (size_t)(tile + r) * 64 + c0) = acc[j];
                if (DUAL) {
                    if (OUTBF) stbf4((u16*)out2 + (size_t)(tile + r) * 64 + c0, acc2[j]);
                    else *(float4*)((float*)out2 + (size_t)(tile + r) * 64 + c0) = acc2[j];
                }
            }
        }
        if (STATS) {
            if (tid < SS) sStat[tid] = 0.f;
            __syncthreads();
            float sx = 0, sy = 0, sz = 0, sw = 0, qx = 0, qy = 0, qz = 0, qw = 0;
            float sx2 = 0, sy2 = 0, sz2 = 0, sw2 = 0, qx2 = 0, qy2 = 0, qz2 = 0, qw2 = 0;
#pragma unroll
            for (int j = 0; j < RPT; ++j) {
                if (rg + j < nrows) {
                    sx += acc[j].x; sy += acc[j].y; sz += acc[j].z; sw += acc[j].w;
                    qx += acc[j].x * acc[j].x; qy += acc[j].y * acc[j].y;
                    qz += acc[j].z * acc[j].z; qw += acc[j].w * acc[j].w;
                    if (DUAL) {
                        sx2 += acc2[j].x; sy2 += acc2[j].y; sz2 += acc2[j].z; sw2 += acc2[j].w;
                        qx2 += acc2[j].x * acc2[j].x; qy2 += acc2[j].y * acc2[j].y;
                        qz2 += acc2[j].z * acc2[j].z; qw2 += acc2[j].w * acc2[j].w;
                    }
                }
            }
            atomicAdd(&sStat[c0 + 0], sx); atomicAdd(&sStat[c0 + 1], sy);
            atomicAdd(&sStat[c0 + 2], sz); atomicAdd(&sStat[c0 + 3], sw);
            atomicAdd(&sStat[64 + c0 + 0], qx); atomicAdd(&sStat[64 + c0 + 1], qy);
            atomicAdd(&sStat[64 + c0 + 2], qz); atomicAdd(&sStat[64 + c0 + 3], qw);
            if (DUAL) {
                atomicAdd(&sStat[128 + c0 + 0], sx2); atomicAdd(&sStat[128 + c0 + 1], sy2);
                atomicAdd(&sStat[128 + c0 + 2], sz2); atomicAdd(&sStat[128 + c0 + 3], sw2);
                atomicAdd(&sStat[192 + c0 + 0], qx2); atomicAdd(&sStat[192 + c0 + 1], qy2);
                atomicAdd(&sStat[192 + c0 + 2], qz2); atomicAdd(&sStat[192 + c0 + 3], qw2);
            }
            __syncthreads();
            if (tid < 128) atomicAdd(&gstats[tid], sStat[tid]);
            if (DUAL && tid >= 128) atomicAdd(&gstats2[tid - 128], sStat[tid]);
        }
    }
}

// ---------------- paired batchnorm apply: bf16 inputs (node heads) ----------------

__global__ void bn_apply2b_k(const u16* __restrict__ in1, const u16* __restrict__ in2,
                             float* __restrict__ out1, float* __restrict__ out2, int rows,
                             const float* __restrict__ st1, const float* __restrict__ st2,
                             const float* __restrict__ g1, const float* __restrict__ b1,
                             const float* __restrict__ g2, const float* __restrict__ b2) {
    int n = rows * 64;
    float invr = 1.f / (float)rows;
    for (int i = blockIdx.x * blockDim.x + threadIdx.x; i < n; i += gridDim.x * blockDim.x) {
        int c = i & 63;
        float m1 = st1[c] * invr;
        float v1 = st1[64 + c] * invr - m1 * m1;
        out1[i] = (bf2f(in1[i]) - m1) * rsqrtf(v1 + 1e-5f) * g1[c] + b1[c];
        float m2 = st2[c] * invr;
        float v2 = st2[64 + c] * invr - m2 * m2;
        out2[i] = (bf2f(in2[i]) - m2) * rsqrtf(v2 + 1e-5f) * g2[c] + b2[c];
    }
}

// ---------------- paired batchnorm apply: fp32 inputs (graph heads) ----------------

__global__ void bn_apply2_k(const float* __restrict__ in1, const float* __restrict__ in2,
                            float* __restrict__ out1, float* __restrict__ out2, int rows,
                            const float* __restrict__ st1, const float* __restrict__ st2,
                            const float* __restrict__ g1, const float* __restrict__ b1,
                            const float* __restrict__ g2, const float* __restrict__ b2) {
    int n = rows * 64;
    float invr = 1.f / (float)rows;
    for (int i = blockIdx.x * blockDim.x + threadIdx.x; i < n; i += gridDim.x * blockDim.x) {
        int c = i & 63;
        float m1 = st1[c] * invr;
        float v1 = st1[64 + c] * invr - m1 * m1;
        out1[i] = (in1[i] - m1) * rsqrtf(v1 + 1e-5f) * g1[c] + b1[c];
        float m2 = st2[c] * invr;
        float v2 = st2[64 + c] * invr - m2 * m2;
        out2[i] = (in2[i] - m2) * rsqrtf(v2 + 1e-5f) * g2[c] + b2[c];
    }
}

// ---------------- attention on z (bf16) directly; 512 threads, 8 scan groups ----------------

__global__ __launch_bounds__(512) void attn3_k(
    const u16* __restrict__ z, const int* __restrict__ segst,
    const float* __restrict__ bnst, const float* __restrict__ gam, const float* __restrict__ bet,
    const float* __restrict__ Wq, const float* __restrict__ Wk, const float* __restrict__ Wv,
    const float* __restrict__ Wih, const float* __restrict__ Whh,
    const float* __restrict__ bih, const float* __restrict__ bhh,
    float* __restrict__ attn, float* __restrict__ slots_out)
{
    int g = blockIdx.x, tid = threadIdx.x, w = tid >> 6, lane = tid & 63;
    __shared__ float ssl[64], sq[64], swr[64], sm[64], supd[64], sred[512], ssum[8];
    __shared__ float aL[64], dL[64];
    __shared__ float sgi[192], sgh[192];
    __shared__ float sc, sinv;

    int s0 = segst[g], s1 = segst[g + 1];
    if (tid < 64) {
        float m = bnst[tid] * (1.f / NN);
        float v = bnst[64 + tid] * (1.f / NN) - m * m;
        float a = rsqrtf(v + 1e-5f) * gam[tid];
        aL[tid] = a;
        dL[tid] = bet[tid] - m * a;
    }
    __syncthreads();

    {
        float macc = 0.f;
        for (int n = s0 + w; n < s1; n += 8) macc += bf2f(z[(size_t)n * 64 + lane]);
        sred[tid] = macc;
        __syncthreads();
        if (tid < 64) {
            float s = 0.f;
#pragma unroll
            for (int k = 0; k < 8; ++k) s += sred[tid + 64 * k];
            ssl[tid] = fmaf(aL[tid], s / (float)max(s1 - s0, 1), dL[tid]);
        }
        __syncthreads();
    }

    for (int it = 0; it < 2; ++it) {
        {
            float p = 0.f;
#pragma unroll
            for (int kk = 0; kk < 8; ++kk) p += ssl[w * 8 + kk] * Wq[(w * 8 + kk) * 64 + lane];
            sred[tid] = p;
        }
        __syncthreads();
        if (tid < 64) {
            float s = 0.f;
#pragma unroll
            for (int k = 0; k < 8; ++k) s += sred[tid + 64 * k];
            sq[tid] = s;
        }
        __syncthreads();
        {
            float p = 0.f;
#pragma unroll
            for (int kk = 0; kk < 8; ++kk) p += Wk[lane * 64 + w * 8 + kk] * sq[w * 8 + kk];
            sred[tid] = p;
        }
        __syncthreads();
        if (tid < 64) {
            float s = 0.f;
#pragma unroll
            for (int k = 0; k < 8; ++k) s += sred[tid + 64 * k];
            swr[tid] = s;
        }
        __syncthreads();
        if (tid < 64) {
            float pr = dL[tid] * swr[tid];
            pr += __shfl_xor(pr, 1);  pr += __shfl_xor(pr, 2);  pr += __shfl_xor(pr, 4);
            pr += __shfl_xor(pr, 8);  pr += __shfl_xor(pr, 16); pr += __shfl_xor(pr, 32);
            if (tid == 0) sc = pr * 0.125f;
            swr[tid] = aL[tid] * swr[tid] * 0.125f;
        }
        __syncthreads();
        float wl = swr[lane], cc = sc;

        float s = 0.f, u = 0.f;
        for (int n = s0 + w; n < s1; n += 8) {
            float zl = bf2f(z[(size_t)n * 64 + lane]);
            float l = zl * wl;
            l += __shfl_xor(l, 1);  l += __shfl_xor(l, 2);  l += __shfl_xor(l, 4);
            l += __shfl_xor(l, 8);  l += __shfl_xor(l, 16); l += __shfl_xor(l, 32);
            float e = expf(l + cc);
            if (lane == 0) attn[n] = e;
            s += e;
            u = fmaf(e, zl, u);
        }
        sred[tid] = u;
        if (lane == 0) ssum[w] = s;
        __syncthreads();
        if (tid < 64) {
            float stot = ssum[0] + ssum[1] + ssum[2] + ssum[3]
                       + ssum[4] + ssum[5] + ssum[6] + ssum[7] + 1e-9f;
            if (tid == 0) sinv = 1.f / stot;
            float uu = 0.f;
#pragma unroll
            for (int k = 0; k < 8; ++k) uu += sred[tid + 64 * k];
            sm[tid] = fmaf(aL[tid], uu / stot, dL[tid]);
        }
        __syncthreads();
        {
            float p = 0.f;
#pragma unroll
            for (int kk = 0; kk < 8; ++kk) p += sm[w * 8 + kk] * Wv[(w * 8 + kk) * 64 + lane];
            sred[tid] = p;
        }
        __syncthreads();
        if (tid < 64) {
            float s2 = 0.f;
#pragma unroll
            for (int k = 0; k < 8; ++k) s2 += sred[tid + 64 * k];
            supd[tid] = s2;
        }
        __syncthreads();

        if (it == 1) {
            float inv = sinv;
            for (int n = s0 + tid; n < s1; n += 512) attn[n] *= inv;
        }

        if (tid < 192) {
            float a = bih[tid], b = bhh[tid];
            const float* wi = &Wih[tid * 64];
            const float* wh = &Whh[tid * 64];
#pragma unroll 8
            for (int j = 0; j < 64; ++j) { a += supd[j] * wi[j]; b += ssl[j] * wh[j]; }
            sgi[tid] = a; sgh[tid] = b;
        }
        __syncthreads();
        if (tid < 64) {
            float r  = 1.f / (1.f + expf(-(sgi[tid] + sgh[tid])));
            float zz = 1.f / (1.f + expf(-(sgi[64 + tid] + sgh[64 + tid])));
            float nn = tanhf(sgi[128 + tid] + r * sgh[128 + tid]);
            float ns = (1.f - zz) * nn + zz * ssl[tid];
            ssl[tid] = ns;
            if (it == 1) slots_out[g * 64 + tid] = ns;
        }
        __syncthreads();
    }
}

// ---------------- host side ----------------

extern "C" void kernel_launch(void* const* d_in, const int* in_sizes, int n_in,
                              void* d_out, int out_size, void* d_ws, size_t ws_size,
                              hipStream_t stream) {
    (void)in_sizes; (void)n_in; (void)out_size; (void)ws_size;

    const float* x      = (const float*)d_in[0];
    const int*   ei     = (const int*)d_in[1];
    const int*   srcI   = ei;
    const int*   dstI   = ei + EE;
    const int*   batch  = (const int*)d_in[2];
    const float* noise  = (const float*)d_in[3];
    const float* W1_0   = (const float*)d_in[4];
    const float* b1_0   = (const float*)d_in[5];
    const float* W2_0   = (const float*)d_in[6];
    const float* b2_0   = (const float*)d_in[7];
    const float* W1_r   = (const float*)d_in[8];
    const float* b1_r   = (const float*)d_in[9];
    const float* W2_r   = (const float*)d_in[10];
    const float* b2_r   = (const float*)d_in[11];
    const float* bn_g   = (const float*)d_in[12];
    const float* bn_b   = (const float*)d_in[13];
    const float* Wq     = (const float*)d_in[14];
    const float* Wk     = (const float*)d_in[15];
    const float* Wv     = (const float*)d_in[16];
    const float* Wih    = (const float*)d_in[17];
    const float* Whh    = (const float*)d_in[18];
    const float* bih    = (const float*)d_in[19];
    const float* bhh    = (const float*)d_in[20];
    const float* nmW    = (const float*)d_in[21];
    const float* nmb    = (const float*)d_in[22];
    const float* nlW    = (const float*)d_in[23];
    const float* nlb    = (const float*)d_in[24];
    const float* gmW    = (const float*)d_in[25];
    const float* gmb    = (const float*)d_in[26];
    const float* glW    = (const float*)d_in[27];
    const float* glb    = (const float*)d_in[28];
    const float* pj_g   = (const float*)d_in[29];
    const float* pj_b   = (const float*)d_in[30];

    char* w = (char*)d_ws;
    u16*   B0b   = (u16*)w;            w += (size_t)NN * 64 * 2;
    u16*   B1b   = (u16*)w;            w += (size_t)NN * 64 * 2;
    u16*   B2b   = (u16*)w;            w += (size_t)NN * 64 * 2;
    float* slots = (float*)w;          w += GG * 64 * 4;
    float* gpre1 = (float*)w;          w += GG * 64 * 4;
    float* gpre2 = (float*)w;          w += GG * 64 * 4;
    float* attn  = (float*)w;          w += NN * 4;
    float* stats = (float*)w;          w += 7 * 128 * 4;
    int*   segst = (int*)w;            w += (GG + 1) * 4;
    int*   rowst = (int*)w;            w += (NN + 1) * 4;
    int*   cursor= (int*)w;            w += NN * 4;
    int*   bsum  = (int*)w;            w += 64 * 4;
    int*   bofs  = (int*)w;            w += 64 * 4;
    u16*   csr16 = (u16*)w;            w += (size_t)EE * 2;

    float* s0 = stats, *s1 = stats + 128, *s2 = stats + 256, *s3 = stats + 384,
         * s4 = stats + 512, *s5 = stats + 640, *s6 = stats + 768;

    float* outp = (float*)d_out;
    float* out_nmu = outp;
    float* out_nlv = outp + NN * DD;
    float* out_gmu = outp + 2 * NN * DD;
    float* out_glv = outp + 2 * NN * DD + GG * DD;

    constexpr int NB = (NN + 1023) / 1024;       // 49 scan chunks
    constexpr int GE4 = (EE / 4 + 255) / 256;    // 782 (4 edges/thread)
    constexpr int NT64 = (NN + 63) / 64;         // 782 64-row tiles
    constexpr int NT16 = (NN + 15) / 16;         // 3125 16-row tiles
    const float* np = nullptr;

#define GK(...) <<<__VA_ARGS__, 0, stream>>>
    // ---------- init + CSR build + segments ----------
    init_k GK((NN + 255) / 256, 256)(cursor, stats, batch, segst);
    hist_k GK(GE4, 256)(dstI, cursor);
    scanA_k GK(NB, 1024)(cursor, rowst, bsum);
    scanB_k GK(1, 64)(bsum, bofs, NB);
    scanC_k GK((NN + 255) / 256, 256)(rowst, bofs, cursor);
    fill_k GK(GE4, 256)(srcI, dstI, cursor, csr16);

    // ---------- GIN layer 0: x@W1 (bf16 W, 16-row tiles), fused gather+W2 ----------
    gemm128_k GK(NT16, 256)(x, W1_0, B0b);
    agg_gemm_k GK(NT64, 256)(B0b, rowst, csr16, b1_0, W2_0, b2_0, B1b, s0);

    // ---------- GIN layers 1,2 (fully fused; bf16 in/out; 64-row tiles) ----------
    fused_layer_k GK(NT64, 256)(B1b, rowst, csr16, s0, bn_g + 0, bn_b + 0,
                                W1_r, b1_r, W2_r, b2_r, B2b, s1);
    fused_layer_k GK(NT64, 256)(B2b, rowst, csr16, s1, bn_g + 64, bn_b + 64,
                                W1_r + DD * DD, b1_r + DD, W2_r + DD * DD, b2_r + DD, B0b, s2);
    // B0b = z2 (pre-BN, relu'd, bf16); BN2 affine (s2, bn[2]) fused into all consumers.

    // ---------- summary maker: attention directly on z2 (512 threads) ----------
    attn3_k GK(GG, 512)(B0b, segst, s2, bn_g + 128, bn_b + 128,
                        Wq, Wk, Wv, Wih, Whh, bih, bhh, attn, slots);

    // ---------- node heads (noisy fused; bf16 outs into dead B1b/B2b) ----------
    gemm_k<64,true,true,true,true,true,true,true,true> GK(782, 256)
        (B0b, nmW, nlW, nmb, nlb, B1b, B2b, NN, s3, s4, attn, noise, s2, bn_g + 128, bn_b + 128);
    bn_apply2b_k GK(2048, 256)(B1b, B2b, out_nmu, out_nlv, NN, s3, s4,
                               pj_g + 0, pj_b + 0, pj_g + 64, pj_b + 64);

    // ---------- graph heads ----------
    gemm_k<64,true,true,true,false,false,true,false,false> GK(8, 256)
        (slots, gmW, glW, gmb, glb, gpre1, gpre2, GG, s5, s6, np, np, np, np, np);
    bn_apply2_k GK(128, 256)(gpre1, gpre2, out_gmu, out_glv, GG, s5, s6,
                             pj_g + 128, pj_b + 128, pj_g + 192, pj_b + 192);
#undef GK
}

// Round 19
// 376.770 us; speedup vs baseline: 1.0218x; 1.0218x over previous
//
#include <hip/hip_runtime.h>

#define NN 50000
#define EE 800000
#define FF 128
#define DD 64
#define GG 512

typedef unsigned short u16;

#define GE4 782     // fill blocks (4 edges/thread)
#define NT16 3125   // gemm128 16-row tiles

// ---------------- bf16 storage helpers (compute stays fp32) ----------------

__device__ __forceinline__ float bf2f(u16 h) {
    unsigned u = ((unsigned)h) << 16;
    return __builtin_bit_cast(float, u);
}
__device__ __forceinline__ u16 f2bf(float f) {
    unsigned u = __builtin_bit_cast(unsigned, f);
    u += 0x7fffu + ((u >> 16) & 1u);   // RNE
    return (u16)(u >> 16);
}
__device__ __forceinline__ float4 ldbf4(const u16* p) {
    uint2 v = *(const uint2*)p;
    float4 r;
    r.x = bf2f((u16)(v.x & 0xffffu)); r.y = bf2f((u16)(v.x >> 16));
    r.z = bf2f((u16)(v.y & 0xffffu)); r.w = bf2f((u16)(v.y >> 16));
    return r;
}
__device__ __forceinline__ float4 bfu2f4(uint2 v) {
    float4 r;
    r.x = bf2f((u16)(v.x & 0xffffu)); r.y = bf2f((u16)(v.x >> 16));
    r.z = bf2f((u16)(v.y & 0xffffu)); r.w = bf2f((u16)(v.y >> 16));
    return r;
}
__device__ __forceinline__ void stbf4(u16* p, float4 v) {
    uint2 o;
    o.x = (unsigned)f2bf(v.x) | ((unsigned)f2bf(v.y) << 16);
    o.y = (unsigned)f2bf(v.z) | ((unsigned)f2bf(v.w) << 16);
    *(uint2*)p = o;
}
__device__ __forceinline__ void fma4(float4& a, const float4& w, float s) {
    a.x = fmaf(s, w.x, a.x); a.y = fmaf(s, w.y, a.y);
    a.z = fmaf(s, w.z, a.z); a.w = fmaf(s, w.w, a.w);
}
__device__ __forceinline__ void add4(float4& a, float4 b) {
    a.x += b.x; a.y += b.y; a.z += b.z; a.w += b.w;
}

// 8-wide unrolled neighbor gather: 8 independent loads in flight per group
__device__ __forceinline__ void gather16(float4& acc, const u16* __restrict__ in,
                                         const u16* __restrict__ csr, int e0s, int e1s,
                                         int l16, int gbase) {
    for (int e0 = e0s; e0 < e1s; e0 += 16) {
        int cnt = min(16, e1s - e0);
        int srcv = (l16 < cnt) ? (int)csr[e0 + l16] : 0;
        int j = 0;
        for (; j + 8 <= cnt; j += 8) {
            int i0 = __shfl(srcv, gbase + j);
            int i1 = __shfl(srcv, gbase + j + 1);
            int i2 = __shfl(srcv, gbase + j + 2);
            int i3 = __shfl(srcv, gbase + j + 3);
            int i4 = __shfl(srcv, gbase + j + 4);
            int i5 = __shfl(srcv, gbase + j + 5);
            int i6 = __shfl(srcv, gbase + j + 6);
            int i7 = __shfl(srcv, gbase + j + 7);
            float4 h0 = ldbf4(in + (size_t)i0 * 64 + l16 * 4);
            float4 h1 = ldbf4(in + (size_t)i1 * 64 + l16 * 4);
            float4 h2 = ldbf4(in + (size_t)i2 * 64 + l16 * 4);
            float4 h3 = ldbf4(in + (size_t)i3 * 64 + l16 * 4);
            float4 h4 = ldbf4(in + (size_t)i4 * 64 + l16 * 4);
            float4 h5 = ldbf4(in + (size_t)i5 * 64 + l16 * 4);
            float4 h6 = ldbf4(in + (size_t)i6 * 64 + l16 * 4);
            float4 h7 = ldbf4(in + (size_t)i7 * 64 + l16 * 4);
            add4(h0, h1); add4(h2, h3); add4(h4, h5); add4(h6, h7);
            add4(h0, h2); add4(h4, h6);
            add4(h0, h4);
            add4(acc, h0);
        }
        for (; j + 4 <= cnt; j += 4) {
            int i0 = __shfl(srcv, gbase + j);
            int i1 = __shfl(srcv, gbase + j + 1);
            int i2 = __shfl(srcv, gbase + j + 2);
            int i3 = __shfl(srcv, gbase + j + 3);
            float4 h0 = ldbf4(in + (size_t)i0 * 64 + l16 * 4);
            float4 h1 = ldbf4(in + (size_t)i1 * 64 + l16 * 4);
            float4 h2 = ldbf4(in + (size_t)i2 * 64 + l16 * 4);
            float4 h3 = ldbf4(in + (size_t)i3 * 64 + l16 * 4);
            add4(h0, h1); add4(h2, h3); add4(h0, h2);
            add4(acc, h0);
        }
        for (; j < cnt; ++j) {
            int s = __shfl(srcv, gbase + j);
            float4 hv = ldbf4(in + (size_t)s * 64 + l16 * 4);
            add4(acc, hv);
        }
    }
}

// ---------------- init: zero cursor/stats + segment bounds (merged) ----------------

__global__ void init_k(int* __restrict__ cursor, float* __restrict__ stats_all,
                       const int* __restrict__ batch, int* __restrict__ segstart) {
    int i = blockIdx.x * blockDim.x + threadIdx.x;
    if (i < NN) cursor[i] = 0;
    if (i < 7 * 128) stats_all[i] = 0.f;
    if (i <= GG) {
        int lo = 0, hi = NN;
        while (lo < hi) {
            int mid = (lo + hi) >> 1;
            if (batch[mid] < i) lo = mid + 1; else hi = mid;
        }
        segstart[i] = lo;
    }
}

// ---------------- CSR build (counting sort by dst), 4 edges/thread ----------------

__global__ void hist_k(const int* __restrict__ dst, int* __restrict__ deg) {
    int e = (blockIdx.x * 256 + threadIdx.x) * 4;
    if (e + 4 <= EE) {
        int4 d = *(const int4*)&dst[e];
        atomicAdd(&deg[d.x], 1); atomicAdd(&deg[d.y], 1);
        atomicAdd(&deg[d.z], 1); atomicAdd(&deg[d.w], 1);
    } else {
        for (; e < EE; ++e) atomicAdd(&deg[dst[e]], 1);
    }
}

__global__ __launch_bounds__(1024) void scanA_k(const int* __restrict__ deg,
                                                int* __restrict__ rowstart,
                                                int* __restrict__ blocksum) {
    __shared__ int buf[1024];
    int tid = threadIdx.x;
    int base = blockIdx.x * 1024;
    int v = (base + tid < NN) ? deg[base + tid] : 0;
    buf[tid] = v;
    __syncthreads();
    for (int o = 1; o < 1024; o <<= 1) {
        int t = (tid >= o) ? buf[tid - o] : 0;
        __syncthreads();
        buf[tid] += t;
        __syncthreads();
    }
    if (base + tid < NN) rowstart[base + tid + 1] = buf[tid];
    if (tid == 1023) blocksum[blockIdx.x] = buf[1023];
}

__global__ void scanB_k(const int* __restrict__ blocksum, int* __restrict__ bofs, int nb) {
    int lane = threadIdx.x;  // 64 threads
    int v = (lane < nb) ? blocksum[lane] : 0;
    int orig = v;
    for (int o = 1; o < 64; o <<= 1) {
        int t = __shfl_up(v, o);
        if (lane >= o) v += t;
    }
    if (lane < nb) bofs[lane] = v - orig;
}

__global__ void scanC_k(int* __restrict__ rowstart, const int* __restrict__ bofs,
                        int* __restrict__ cursor) {
    int i = blockIdx.x * blockDim.x + threadIdx.x;
    if (i >= NN) return;
    int val = rowstart[i + 1] + bofs[i >> 10];
    rowstart[i + 1] = val;
    if (i + 1 < NN) cursor[i + 1] = val;
    if (i == 0) { rowstart[0] = 0; cursor[0] = 0; }
}

// ---------------- fused: CSR fill (blocks 0..GE4-1)  +  x@W1 gemm (blocks GE4..) ----------------
// fill and gemm128 are independent; co-running hides fill's atomic latency under
// gemm128's streaming BW work.

__global__ __launch_bounds__(256) void fillgemm_k(
    const int* __restrict__ src, const int* __restrict__ dst,
    int* __restrict__ cursor, u16* __restrict__ csr16,
    const float* __restrict__ x, const float* __restrict__ W, u16* __restrict__ out)
{
    __shared__ u16 sW16[128 * 64];
    __shared__ float sIn[16 * 132];
    const int tid = threadIdx.x;

    if (blockIdx.x < GE4) {
        // ---- fill ----
        int e = (blockIdx.x * 256 + tid) * 4;
        if (e + 4 <= EE) {
            int4 d = *(const int4*)&dst[e];
            int4 s = *(const int4*)&src[e];
            int p0 = atomicAdd(&cursor[d.x], 1);
            int p1 = atomicAdd(&cursor[d.y], 1);
            int p2 = atomicAdd(&cursor[d.z], 1);
            int p3 = atomicAdd(&cursor[d.w], 1);
            csr16[p0] = (u16)s.x; csr16[p1] = (u16)s.y;
            csr16[p2] = (u16)s.z; csr16[p3] = (u16)s.w;
        } else {
            for (; e < EE; ++e) { int p = atomicAdd(&cursor[dst[e]], 1); csr16[p] = (u16)src[e]; }
        }
        return;
    }

    // ---- gemm128: out_bf16[16 x 64] = x[16 x 128] @ W ----
    const int gb = blockIdx.x - GE4;
    for (int i = tid * 4; i < 128 * 64; i += 1024) {
        float4 w = *(const float4*)(W + i);
        uint2 pk;
        pk.x = (unsigned)f2bf(w.x) | ((unsigned)f2bf(w.y) << 16);
        pk.y = (unsigned)f2bf(w.z) | ((unsigned)f2bf(w.w) << 16);
        *(uint2*)&sW16[i] = pk;
    }
    const int tile = gb * 16;
    const int nrows = min(16, NN - tile);
    for (int i = tid; i < 16 * 32; i += 256) {
        int rr = i >> 5, kk = (i & 31) * 4;
        float4 t = (rr < nrows) ? *(const float4*)(x + (size_t)(tile + rr) * 128 + kk)
                                : make_float4(0.f, 0.f, 0.f, 0.f);
        *(float4*)&sIn[rr * 132 + kk] = t;
    }
    __syncthreads();
    int rg = tid >> 4, c0 = (tid & 15) << 2;
    float4 acc = make_float4(0.f, 0.f, 0.f, 0.f);
#pragma unroll 4
    for (int k4 = 0; k4 < 32; ++k4) {
        float4 av = *(const float4*)&sIn[rg * 132 + k4 * 4];
        float as[4] = {av.x, av.y, av.z, av.w};
#pragma unroll
        for (int kk = 0; kk < 4; ++kk) {
            uint2 wp = *(const uint2*)&sW16[(k4 * 4 + kk) * 64 + c0];
            fma4(acc, bfu2f4(wp), as[kk]);
        }
    }
    if (rg < nrows) stbf4(out + (size_t)(tile + rg) * 64 + c0, acc);
}

// ---------------- fused gather + W2 GEMM (layer 0 tail), 64-row tiles ----------------

__global__ __launch_bounds__(256) void agg_gemm_k(
    const u16* __restrict__ in,
    const int* __restrict__ rowstart, const u16* __restrict__ csr,
    const float* __restrict__ bias1,
    const float* __restrict__ W2, const float* __restrict__ bias2,
    u16* __restrict__ out, float* __restrict__ gstats)
{
    constexpr int KP = 68;
    __shared__ float sW[64 * 64];
    __shared__ float sIn[64 * KP];
    __shared__ float sStat[128];
    const int tid = threadIdx.x;

    for (int i = tid; i < 64 * 16; i += 256) ((float4*)sW)[i] = ((const float4*)W2)[i];

    const int tile = blockIdx.x * 64;
    const int nrows = min(64, NN - tile);
    const int l16 = tid & 15, gbase = tid & 48, grp = tid >> 4;
    float4 b1v = ((const float4*)bias1)[l16];
    for (int r = grp; r < nrows; r += 16) {
        int node = tile + r;
        float4 acc = ldbf4(in + (size_t)node * 64 + l16 * 4);
        gather16(acc, in, csr, rowstart[node], rowstart[node + 1], l16, gbase);
        acc.x = fmaxf(acc.x + b1v.x, 0.f); acc.y = fmaxf(acc.y + b1v.y, 0.f);
        acc.z = fmaxf(acc.z + b1v.z, 0.f); acc.w = fmaxf(acc.w + b1v.w, 0.f);
        *(float4*)&sIn[r * KP + l16 * 4] = acc;
    }
    __syncthreads();

    const int rg = (tid >> 4) * 4, c0 = (tid & 15) << 2;
    float4 bb = *(const float4*)&bias2[c0];
    float4 acc[4];
#pragma unroll
    for (int j = 0; j < 4; ++j) acc[j] = bb;
#pragma unroll 2
    for (int k4 = 0; k4 < 16; ++k4) {
        float4 av[4];
#pragma unroll
        for (int j = 0; j < 4; ++j) av[j] = *(const float4*)&sIn[(rg + j) * KP + k4 * 4];
        const float* wp = &sW[k4 * 4 * 64 + c0];
        float4 w0 = *(const float4*)(wp);
        float4 w1 = *(const float4*)(wp + 64);
        float4 w2 = *(const float4*)(wp + 128);
        float4 w3 = *(const float4*)(wp + 192);
#pragma unroll
        for (int j = 0; j < 4; ++j) {
            fma4(acc[j], w0, av[j].x); fma4(acc[j], w1, av[j].y);
            fma4(acc[j], w2, av[j].z); fma4(acc[j], w3, av[j].w);
        }
    }
#pragma unroll
    for (int j = 0; j < 4; ++j) {
        acc[j].x = fmaxf(acc[j].x, 0.f); acc[j].y = fmaxf(acc[j].y, 0.f);
        acc[j].z = fmaxf(acc[j].z, 0.f); acc[j].w = fmaxf(acc[j].w, 0.f);
        if (rg + j < nrows) stbf4(out + (size_t)(tile + rg + j) * 64 + c0, acc[j]);
    }
    if (tid < 128) sStat[tid] = 0.f;
    __syncthreads();
    float sx = 0, sy = 0, sz = 0, sw = 0, qx = 0, qy = 0, qz = 0, qw = 0;
#pragma unroll
    for (int j = 0; j < 4; ++j) {
        if (rg + j < nrows) {
            sx += acc[j].x; sy += acc[j].y; sz += acc[j].z; sw += acc[j].w;
            qx += acc[j].x * acc[j].x; qy += acc[j].y * acc[j].y;
            qz += acc[j].z * acc[j].z; qw += acc[j].w * acc[j].w;
        }
    }
    atomicAdd(&sStat[c0 + 0], sx); atomicAdd(&sStat[c0 + 1], sy);
    atomicAdd(&sStat[c0 + 2], sz); atomicAdd(&sStat[c0 + 3], sw);
    atomicAdd(&sStat[64 + c0 + 0], qx); atomicAdd(&sStat[64 + c0 + 1], qy);
    atomicAdd(&sStat[64 + c0 + 2], qz); atomicAdd(&sStat[64 + c0 + 3], qw);
    __syncthreads();
    if (tid < 128) atomicAdd(&gstats[tid], sStat[tid]);
}

// ---------------- fully fused GIN layer (layers 1,2), 64-row tiles ----------------

__global__ __launch_bounds__(256) void fused_layer_k(
    const u16* __restrict__ in,
    const int* __restrict__ rowstart, const u16* __restrict__ csr,
    const float* __restrict__ bnst, const float* __restrict__ gam, const float* __restrict__ bet,
    const float* __restrict__ W1, const float* __restrict__ b1,
    const float* __restrict__ W2, const float* __restrict__ b2,
    u16* __restrict__ out, float* __restrict__ gstats)
{
    constexpr int KP = 68;
    __shared__ float sW[64 * 64];      // W1 then reloaded with W2
    __shared__ float sAgg[64 * KP];
    __shared__ float sStat[128];
    __shared__ float aL[64], dL[64];
    const int tid = threadIdx.x;

    for (int i = tid; i < 64 * 16; i += 256) ((float4*)sW)[i] = ((const float4*)W1)[i];
    if (tid < 64) {
        float m = bnst[tid] * (1.f / NN);
        float v = bnst[64 + tid] * (1.f / NN) - m * m;
        float a = rsqrtf(v + 1e-5f) * gam[tid];
        aL[tid] = a;
        dL[tid] = bet[tid] - m * a;
    }
    __syncthreads();

    const int tile = blockIdx.x * 64;
    const int nrows = min(64, NN - tile);
    const int l16 = tid & 15, gbase = tid & 48, grp = tid >> 4;
    float4 av4 = *(const float4*)&aL[l16 * 4];
    float4 dv4 = *(const float4*)&dL[l16 * 4];
    for (int r = grp; r < nrows; r += 16) {
        int node = tile + r;
        int e0s = rowstart[node], e1s = rowstart[node + 1];
        float4 acc = ldbf4(in + (size_t)node * 64 + l16 * 4);
        gather16(acc, in, csr, e0s, e1s, l16, gbase);
        float dp1 = (float)(e1s - e0s + 1);
        acc.x = fmaf(av4.x, acc.x, dp1 * dv4.x);
        acc.y = fmaf(av4.y, acc.y, dp1 * dv4.y);
        acc.z = fmaf(av4.z, acc.z, dp1 * dv4.z);
        acc.w = fmaf(av4.w, acc.w, dp1 * dv4.w);
        *(float4*)&sAgg[r * KP + l16 * 4] = acc;
    }
    __syncthreads();

    const int rg = (tid >> 4) * 4, c0 = (tid & 15) << 2;
    float4 t[4];
    {
        float4 bb = *(const float4*)&b1[c0];
#pragma unroll
        for (int j = 0; j < 4; ++j) t[j] = bb;
#pragma unroll 2
        for (int k4 = 0; k4 < 16; ++k4) {
            float4 a0[4];
#pragma unroll
            for (int j = 0; j < 4; ++j) a0[j] = *(const float4*)&sAgg[(rg + j) * KP + k4 * 4];
            const float* wp = &sW[k4 * 4 * 64 + c0];
            float4 w0 = *(const float4*)(wp);
            float4 w1 = *(const float4*)(wp + 64);
            float4 w2 = *(const float4*)(wp + 128);
            float4 w3 = *(const float4*)(wp + 192);
#pragma unroll
            for (int j = 0; j < 4; ++j) {
                fma4(t[j], w0, a0[j].x); fma4(t[j], w1, a0[j].y);
                fma4(t[j], w2, a0[j].z); fma4(t[j], w3, a0[j].w);
            }
        }
#pragma unroll
        for (int j = 0; j < 4; ++j) {
            t[j].x = fmaxf(t[j].x, 0.f); t[j].y = fmaxf(t[j].y, 0.f);
            t[j].z = fmaxf(t[j].z, 0.f); t[j].w = fmaxf(t[j].w, 0.f);
        }
    }
    __syncthreads();

    for (int i = tid; i < 64 * 16; i += 256) ((float4*)sW)[i] = ((const float4*)W2)[i];
#pragma unroll
    for (int j = 0; j < 4; ++j) *(float4*)&sAgg[(rg + j) * KP + c0] = t[j];
    __syncthreads();

    float4 acc[4];
    {
        float4 bb = *(const float4*)&b2[c0];
#pragma unroll
        for (int j = 0; j < 4; ++j) acc[j] = bb;
#pragma unroll 2
        for (int k4 = 0; k4 < 16; ++k4) {
            float4 a0[4];
#pragma unroll
            for (int j = 0; j < 4; ++j) a0[j] = *(const float4*)&sAgg[(rg + j) * KP + k4 * 4];
            const float* wp = &sW[k4 * 4 * 64 + c0];
            float4 w0 = *(const float4*)(wp);
            float4 w1 = *(const float4*)(wp + 64);
            float4 w2 = *(const float4*)(wp + 128);
            float4 w3 = *(const float4*)(wp + 192);
#pragma unroll
            for (int j = 0; j < 4; ++j) {
                fma4(acc[j], w0, a0[j].x); fma4(acc[j], w1, a0[j].y);
                fma4(acc[j], w2, a0[j].z); fma4(acc[j], w3, a0[j].w);
            }
        }
    }
#pragma unroll
    for (int j = 0; j < 4; ++j) {
        acc[j].x = fmaxf(acc[j].x, 0.f); acc[j].y = fmaxf(acc[j].y, 0.f);
        acc[j].z = fmaxf(acc[j].z, 0.f); acc[j].w = fmaxf(acc[j].w, 0.f);
        if (rg + j < nrows) stbf4(out + (size_t)(tile + rg + j) * 64 + c0, acc[j]);
    }
    if (tid < 128) sStat[tid] = 0.f;
    __syncthreads();
    float sx = 0, sy = 0, sz = 0, sw = 0, qx = 0, qy = 0, qz = 0, qw = 0;
#pragma unroll
    for (int j = 0; j < 4; ++j) {
        if (rg + j < nrows) {
            sx += acc[j].x; sy += acc[j].y; sz += acc[j].z; sw += acc[j].w;
            qx += acc[j].x * acc[j].x; qy += acc[j].y * acc[j].y;
            qz += acc[j].z * acc[j].z; qw += acc[j].w * acc[j].w;
        }
    }
    atomicAdd(&sStat[c0 + 0], sx); atomicAdd(&sStat[c0 + 1], sy);
    atomicAdd(&sStat[c0 + 2], sz); atomicAdd(&sStat[c0 + 3], sw);
    atomicAdd(&sStat[64 + c0 + 0], qx); atomicAdd(&sStat[64 + c0 + 1], qy);
    atomicAdd(&sStat[64 + c0 + 2], qz); atomicAdd(&sStat[64 + c0 + 3], qw);
    __syncthreads();
    if (tid < 128) atomicAdd(&gstats[tid], sStat[tid]);
}

// ---------------- skinny fp32 GEMM (K=64 paths), templated bf16 in/out ----------------

template<int K, bool BIAS, bool RELU, bool STATS, bool ROWSCALE, bool BNIN, bool DUAL,
         bool INBF, bool OUTBF>
__global__ __launch_bounds__(256) void gemm_k(
    const void* __restrict__ in, const float* __restrict__ W, const float* __restrict__ Wb,
    const float* __restrict__ bias, const float* __restrict__ bias2,
    void* __restrict__ out, void* __restrict__ out2, int rows,
    float* __restrict__ gstats, float* __restrict__ gstats2,
    const float* __restrict__ attn, const float* __restrict__ noise,
    const float* __restrict__ bnstats, const float* __restrict__ gamma,
    const float* __restrict__ beta)
{
    constexpr int RPT = (K == 128) ? 2 : 4;
    constexpr int TR  = 16 * RPT;
    constexpr int KP  = K + 4;
    constexpr int SS  = DUAL ? 256 : 128;
    __shared__ float sW[K * 64];
    __shared__ float sWb[DUAL ? K * 64 : 4];
    __shared__ float sIn[TR * KP];
    __shared__ float sStat[STATS ? SS : 4];
    __shared__ float sA[BNIN ? 64 : 4];
    __shared__ float sD[BNIN ? 64 : 4];

    const int tid = threadIdx.x;
    for (int i = tid; i < K * 16; i += 256) ((float4*)sW)[i] = ((const float4*)W)[i];
    if (DUAL)
        for (int i = tid; i < K * 16; i += 256) ((float4*)sWb)[i] = ((const float4*)Wb)[i];
    if (BNIN && tid < 64) {
        float m   = bnstats[tid] * (1.f / NN);
        float v   = bnstats[64 + tid] * (1.f / NN) - m * m;
        float a   = rsqrtf(v + 1e-5f) * gamma[tid];
        sA[tid] = a;
        sD[tid] = beta[tid] - m * a;
    }

    int rg = (tid >> 4) * RPT;
    int c0 = (tid & 15) << 2;
    float4 bb  = make_float4(0.f, 0.f, 0.f, 0.f);
    float4 bb2 = make_float4(0.f, 0.f, 0.f, 0.f);
    if (BIAS) bb = *(const float4*)&bias[c0];
    if (BIAS && DUAL) bb2 = *(const float4*)&bias2[c0];

    for (int tile = blockIdx.x * TR; tile < rows; tile += gridDim.x * TR) {
        __syncthreads();
        int nrows = min(TR, rows - tile);
        const float4* igf = INBF ? nullptr : (const float4*)((const float*)in + (size_t)tile * K);
        const u16*    igb = INBF ? ((const u16*)in + (size_t)tile * K) : nullptr;
        const float4* ng  = ROWSCALE ? (const float4*)(noise + (size_t)tile * K) : nullptr;
        for (int i = tid; i < nrows * (K / 4); i += 256) {
            int rr = i / (K / 4), kk = (i - rr * (K / 4)) * 4;
            float4 t = INBF ? ldbf4(igb + i * 4) : igf[i];
            if (BNIN) {
                t.x = fmaf(sA[kk + 0], t.x, sD[kk + 0]);
                t.y = fmaf(sA[kk + 1], t.y, sD[kk + 1]);
                t.z = fmaf(sA[kk + 2], t.z, sD[kk + 2]);
                t.w = fmaf(sA[kk + 3], t.w, sD[kk + 3]);
            }
            if (ROWSCALE) {
                float4 nv = ng[i];
                float at = attn[tile + rr];
                t.x = fmaf(at, t.x, nv.x); t.y = fmaf(at, t.y, nv.y);
                t.z = fmaf(at, t.z, nv.z); t.w = fmaf(at, t.w, nv.w);
            }
            *(float4*)&sIn[rr * KP + kk] = t;
        }
        __syncthreads();

        float4 acc[RPT];
        float4 acc2[DUAL ? RPT : 1];
#pragma unroll
        for (int j = 0; j < RPT; ++j) acc[j] = bb;
        if (DUAL) {
#pragma unroll
            for (int j = 0; j < RPT; ++j) acc2[j] = bb2;
        }
#pragma unroll 2
        for (int k4 = 0; k4 < K / 4; ++k4) {
            float4 av[RPT];
#pragma unroll
            for (int j = 0; j < RPT; ++j)
                av[j] = *(const float4*)&sIn[(rg + j) * KP + k4 * 4];
            const float* wp = &sW[k4 * 4 * 64 + c0];
            float4 w0 = *(const float4*)(wp);
            float4 w1 = *(const float4*)(wp + 64);
            float4 w2 = *(const float4*)(wp + 128);
            float4 w3 = *(const float4*)(wp + 192);
#pragma unroll
            for (int j = 0; j < RPT; ++j) {
                fma4(acc[j], w0, av[j].x); fma4(acc[j], w1, av[j].y);
                fma4(acc[j], w2, av[j].z); fma4(acc[j], w3, av[j].w);
            }
            if (DUAL) {
                const float* wq = &sWb[k4 * 4 * 64 + c0];
                float4 u0 = *(const float4*)(wq);
                float4 u1 = *(const float4*)(wq + 64);
                float4 u2 = *(const float4*)(wq + 128);
                float4 u3 = *(const float4*)(wq + 192);
#pragma unroll
                for (int j = 0; j < RPT; ++j) {
                    fma4(acc2[j], u0, av[j].x); fma4(acc2[j], u1, av[j].y);
                    fma4(acc2[j], u2, av[j].z); fma4(acc2[j], u3, av[j].w);
                }
            }
        }
        if (RELU) {
#pragma unroll
            for (int j = 0; j < RPT; ++j) {
                acc[j].x = fmaxf(acc[j].x, 0.f); acc[j].y = fmaxf(acc[j].y, 0.f);
                acc[j].z = fmaxf(acc[j].z, 0.f); acc[j].w = fmaxf(acc[j].w, 0.f);
                if (DUAL) {
                    acc2[j].x = fmaxf(acc2[j].x, 0.f); acc2[j].y = fmaxf(acc2[j].y, 0.f);
                    acc2[j].z = fmaxf(acc2[j].z, 0.f); acc2[j].w = fmaxf(acc2[j].w, 0.f);
                }
            }
        }
#pragma unroll
        for (int j = 0; j < RPT; ++j) {
            int r = rg + j;
            if (r < nrows) {
                if (OUTBF) stbf4((u16*)out + (size_t)(tile + r) * 64 + c0, acc[j]);
                else *(float4*)((float*)out + (size_t)(tile + r) * 64 + c0) = acc[j];
                if (DUAL) {
                    if (OUTBF) stbf4((u16*)out2 + (size_t)(tile + r) * 64 + c0, acc2[j]);
                    else *(float4*)((float*)out2 + (size_t)(tile + r) * 64 + c0) = acc2[j];
                }
            }
        }
        if (STATS) {
            if (tid < SS) sStat[tid] = 0.f;
            __syncthreads();
            float sx = 0, sy = 0, sz = 0, sw = 0, qx = 0, qy = 0, qz = 0, qw = 0;
            float sx2 = 0, sy2 = 0, sz2 = 0, sw2 = 0, qx2 = 0, qy2 = 0, qz2 = 0, qw2 = 0;
#pragma unroll
            for (int j = 0; j < RPT; ++j) {
                if (rg + j < nrows) {
                    sx += acc[j].x; sy += acc[j].y; sz += acc[j].z; sw += acc[j].w;
                    qx += acc[j].x * acc[j].x; qy += acc[j].y * acc[j].y;
                    qz += acc[j].z * acc[j].z; qw += acc[j].w * acc[j].w;
                    if (DUAL) {
                        sx2 += acc2[j].x; sy2 += acc2[j].y; sz2 += acc2[j].z; sw2 += acc2[j].w;
                        qx2 += acc2[j].x * acc2[j].x; qy2 += acc2[j].y * acc2[j].y;
                        qz2 += acc2[j].z * acc2[j].z; qw2 += acc2[j].w * acc2[j].w;
                    }
                }
            }
            atomicAdd(&sStat[c0 + 0], sx); atomicAdd(&sStat[c0 + 1], sy);
            atomicAdd(&sStat[c0 + 2], sz); atomicAdd(&sStat[c0 + 3], sw);
            atomicAdd(&sStat[64 + c0 + 0], qx); atomicAdd(&sStat[64 + c0 + 1], qy);
            atomicAdd(&sStat[64 + c0 + 2], qz); atomicAdd(&sStat[64 + c0 + 3], qw);
            if (DUAL) {
                atomicAdd(&sStat[128 + c0 + 0], sx2); atomicAdd(&sStat[128 + c0 + 1], sy2);
                atomicAdd(&sStat[128 + c0 + 2], sz2); atomicAdd(&sStat[128 + c0 + 3], sw2);
                atomicAdd(&sStat[192 + c0 + 0], qx2); atomicAdd(&sStat[192 + c0 + 1], qy2);
                atomicAdd(&sStat[192 + c0 + 2], qz2); atomicAdd(&sStat[192 + c0 + 3], qw2);
            }
            __syncthreads();
            if (tid < 128) atomicAdd(&gstats[tid], sStat[tid]);
            if (DUAL && tid >= 128) atomicAdd(&gstats2[tid - 128], sStat[tid]);
        }
    }
}

// ---------------- paired batchnorm apply: bf16 inputs (node heads) ----------------

__global__ void bn_apply2b_k(const u16* __restrict__ in1, const u16* __restrict__ in2,
                             float* __restrict__ out1, float* __restrict__ out2, int rows,
                             const float* __restrict__ st1, const float* __restrict__ st2,
                             const float* __restrict__ g1, const float* __restrict__ b1,
                             const float* __restrict__ g2, const float* __restrict__ b2) {
    int n = rows * 64;
    float invr = 1.f / (float)rows;
    for (int i = blockIdx.x * blockDim.x + threadIdx.x; i < n; i += gridDim.x * blockDim.x) {
        int c = i & 63;
        float m1 = st1[c] * invr;
        float v1 = st1[64 + c] * invr - m1 * m1;
        out1[i] = (bf2f(in1[i]) - m1) * rsqrtf(v1 + 1e-5f) * g1[c] + b1[c];
        float m2 = st2[c] * invr;
        float v2 = st2[64 + c] * invr - m2 * m2;
        out2[i] = (bf2f(in2[i]) - m2) * rsqrtf(v2 + 1e-5f) * g2[c] + b2[c];
    }
}

// ---------------- paired batchnorm apply: fp32 inputs (graph heads) ----------------

__global__ void bn_apply2_k(const float* __restrict__ in1, const float* __restrict__ in2,
                            float* __restrict__ out1, float* __restrict__ out2, int rows,
                            const float* __restrict__ st1, const float* __restrict__ st2,
                            const float* __restrict__ g1, const float* __restrict__ b1,
                            const float* __restrict__ g2, const float* __restrict__ b2) {
    int n = rows * 64;
    float invr = 1.f / (float)rows;
    for (int i = blockIdx.x * blockDim.x + threadIdx.x; i < n; i += gridDim.x * blockDim.x) {
        int c = i & 63;
        float m1 = st1[c] * invr;
        float v1 = st1[64 + c] * invr - m1 * m1;
        out1[i] = (in1[i] - m1) * rsqrtf(v1 + 1e-5f) * g1[c] + b1[c];
        float m2 = st2[c] * invr;
        float v2 = st2[64 + c] * invr - m2 * m2;
        out2[i] = (in2[i] - m2) * rsqrtf(v2 + 1e-5f) * g2[c] + b2[c];
    }
}

// ---------------- attention on z (bf16) directly; 512 threads, 8 scan groups ----------------

__global__ __launch_bounds__(512) void attn3_k(
    const u16* __restrict__ z, const int* __restrict__ segst,
    const float* __restrict__ bnst, const float* __restrict__ gam, const float* __restrict__ bet,
    const float* __restrict__ Wq, const float* __restrict__ Wk, const float* __restrict__ Wv,
    const float* __restrict__ Wih, const float* __restrict__ Whh,
    const float* __restrict__ bih, const float* __restrict__ bhh,
    float* __restrict__ attn, float* __restrict__ slots_out)
{
    int g = blockIdx.x, tid = threadIdx.x, w = tid >> 6, lane = tid & 63;
    __shared__ float ssl[64], sq[64], swr[64], sm[64], supd[64], sred[512], ssum[8];
    __shared__ float aL[64], dL[64];
    __shared__ float sgi[192], sgh[192];
    __shared__ float sc, sinv;

    int s0 = segst[g], s1 = segst[g + 1];
    if (tid < 64) {
        float m = bnst[tid] * (1.f / NN);
        float v = bnst[64 + tid] * (1.f / NN) - m * m;
        float a = rsqrtf(v + 1e-5f) * gam[tid];
        aL[tid] = a;
        dL[tid] = bet[tid] - m * a;
    }
    __syncthreads();

    {
        float macc = 0.f;
        for (int n = s0 + w; n < s1; n += 8) macc += bf2f(z[(size_t)n * 64 + lane]);
        sred[tid] = macc;
        __syncthreads();
        if (tid < 64) {
            float s = 0.f;
#pragma unroll
            for (int k = 0; k < 8; ++k) s += sred[tid + 64 * k];
            ssl[tid] = fmaf(aL[tid], s / (float)max(s1 - s0, 1), dL[tid]);
        }
        __syncthreads();
    }

    for (int it = 0; it < 2; ++it) {
        {
            float p = 0.f;
#pragma unroll
            for (int kk = 0; kk < 8; ++kk) p += ssl[w * 8 + kk] * Wq[(w * 8 + kk) * 64 + lane];
            sred[tid] = p;
        }
        __syncthreads();
        if (tid < 64) {
            float s = 0.f;
#pragma unroll
            for (int k = 0; k < 8; ++k) s += sred[tid + 64 * k];
            sq[tid] = s;
        }
        __syncthreads();
        {
            float p = 0.f;
#pragma unroll
            for (int kk = 0; kk < 8; ++kk) p += Wk[lane * 64 + w * 8 + kk] * sq[w * 8 + kk];
            sred[tid] = p;
        }
        __syncthreads();
        if (tid < 64) {
            float s = 0.f;
#pragma unroll
            for (int k = 0; k < 8; ++k) s += sred[tid + 64 * k];
            swr[tid] = s;
        }
        __syncthreads();
        if (tid < 64) {
            float pr = dL[tid] * swr[tid];
            pr += __shfl_xor(pr, 1);  pr += __shfl_xor(pr, 2);  pr += __shfl_xor(pr, 4);
            pr += __shfl_xor(pr, 8);  pr += __shfl_xor(pr, 16); pr += __shfl_xor(pr, 32);
            if (tid == 0) sc = pr * 0.125f;
            swr[tid] = aL[tid] * swr[tid] * 0.125f;
        }
        __syncthreads();
        float wl = swr[lane], cc = sc;

        float s = 0.f, u = 0.f;
        for (int n = s0 + w; n < s1; n += 8) {
            float zl = bf2f(z[(size_t)n * 64 + lane]);
            float l = zl * wl;
            l += __shfl_xor(l, 1);  l += __shfl_xor(l, 2);  l += __shfl_xor(l, 4);
            l += __shfl_xor(l, 8);  l += __shfl_xor(l, 16); l += __shfl_xor(l, 32);
            float e = expf(l + cc);
            if (lane == 0) attn[n] = e;
            s += e;
            u = fmaf(e, zl, u);
        }
        sred[tid] = u;
        if (lane == 0) ssum[w] = s;
        __syncthreads();
        if (tid < 64) {
            float stot = ssum[0] + ssum[1] + ssum[2] + ssum[3]
                       + ssum[4] + ssum[5] + ssum[6] + ssum[7] + 1e-9f;
            if (tid == 0) sinv = 1.f / stot;
            float uu = 0.f;
#pragma unroll
            for (int k = 0; k < 8; ++k) uu += sred[tid + 64 * k];
            sm[tid] = fmaf(aL[tid], uu / stot, dL[tid]);
        }
        __syncthreads();
        {
            float p = 0.f;
#pragma unroll
            for (int kk = 0; kk < 8; ++kk) p += sm[w * 8 + kk] * Wv[(w * 8 + kk) * 64 + lane];
            sred[tid] = p;
        }
        __syncthreads();
        if (tid < 64) {
            float s2 = 0.f;
#pragma unroll
            for (int k = 0; k < 8; ++k) s2 += sred[tid + 64 * k];
            supd[tid] = s2;
        }
        __syncthreads();

        if (it == 1) {
            float inv = sinv;
            for (int n = s0 + tid; n < s1; n += 512) attn[n] *= inv;
        }

        if (tid < 192) {
            float a = bih[tid], b = bhh[tid];
            const float* wi = &Wih[tid * 64];
            const float* wh = &Whh[tid * 64];
#pragma unroll 8
            for (int j = 0; j < 64; ++j) { a += supd[j] * wi[j]; b += ssl[j] * wh[j]; }
            sgi[tid] = a; sgh[tid] = b;
        }
        __syncthreads();
        if (tid < 64) {
            float r  = 1.f / (1.f + expf(-(sgi[tid] + sgh[tid])));
            float zz = 1.f / (1.f + expf(-(sgi[64 + tid] + sgh[64 + tid])));
            float nn = tanhf(sgi[128 + tid] + r * sgh[128 + tid]);
            float ns = (1.f - zz) * nn + zz * ssl[tid];
            ssl[tid] = ns;
            if (it == 1) slots_out[g * 64 + tid] = ns;
        }
        __syncthreads();
    }
}

// ---------------- host side ----------------

extern "C" void kernel_launch(void* const* d_in, const int* in_sizes, int n_in,
                              void* d_out, int out_size, void* d_ws, size_t ws_size,
                              hipStream_t stream) {
    (void)in_sizes; (void)n_in; (void)out_size; (void)ws_size;

    const float* x      = (const float*)d_in[0];
    const int*   ei     = (const int*)d_in[1];
    const int*   srcI   = ei;
    const int*   dstI   = ei + EE;
    const int*   batch  = (const int*)d_in[2];
    const float* noise  = (const float*)d_in[3];
    const float* W1_0   = (const float*)d_in[4];
    const float* b1_0   = (const float*)d_in[5];
    const float* W2_0   = (const float*)d_in[6];
    const float* b2_0   = (const float*)d_in[7];
    const float* W1_r   = (const float*)d_in[8];
    const float* b1_r   = (const float*)d_in[9];
    const float* W2_r   = (const float*)d_in[10];
    const float* b2_r   = (const float*)d_in[11];
    const float* bn_g   = (const float*)d_in[12];
    const float* bn_b   = (const float*)d_in[13];
    const float* Wq     = (const float*)d_in[14];
    const float* Wk     = (const float*)d_in[15];
    const float* Wv     = (const float*)d_in[16];
    const float* Wih    = (const float*)d_in[17];
    const float* Whh    = (const float*)d_in[18];
    const float* bih    = (const float*)d_in[19];
    const float* bhh    = (const float*)d_in[20];
    const float* nmW    = (const float*)d_in[21];
    const float* nmb    = (const float*)d_in[22];
    const float* nlW    = (const float*)d_in[23];
    const float* nlb    = (const float*)d_in[24];
    const float* gmW    = (const float*)d_in[25];
    const float* gmb    = (const float*)d_in[26];
    const float* glW    = (const float*)d_in[27];
    const float* glb    = (const float*)d_in[28];
    const float* pj_g   = (const float*)d_in[29];
    const float* pj_b   = (const float*)d_in[30];

    char* w = (char*)d_ws;
    u16*   B0b   = (u16*)w;            w += (size_t)NN * 64 * 2;
    u16*   B1b   = (u16*)w;            w += (size_t)NN * 64 * 2;
    u16*   B2b   = (u16*)w;            w += (size_t)NN * 64 * 2;
    float* slots = (float*)w;          w += GG * 64 * 4;
    float* gpre1 = (float*)w;          w += GG * 64 * 4;
    float* gpre2 = (float*)w;          w += GG * 64 * 4;
    float* attn  = (float*)w;          w += NN * 4;
    float* stats = (float*)w;          w += 7 * 128 * 4;
    int*   segst = (int*)w;            w += (GG + 1) * 4;
    int*   rowst = (int*)w;            w += (NN + 1) * 4;
    int*   cursor= (int*)w;            w += NN * 4;
    int*   bsum  = (int*)w;            w += 64 * 4;
    int*   bofs  = (int*)w;            w += 64 * 4;
    u16*   csr16 = (u16*)w;            w += (size_t)EE * 2;

    float* s0 = stats, *s1 = stats + 128, *s2 = stats + 256, *s3 = stats + 384,
         * s4 = stats + 512, *s5 = stats + 640, *s6 = stats + 768;

    float* outp = (float*)d_out;
    float* out_nmu = outp;
    float* out_nlv = outp + NN * DD;
    float* out_gmu = outp + 2 * NN * DD;
    float* out_glv = outp + 2 * NN * DD + GG * DD;

    constexpr int NB = (NN + 1023) / 1024;       // 49 scan chunks
    constexpr int NT64 = (NN + 63) / 64;         // 782 64-row tiles
    const float* np = nullptr;

#define GK(...) <<<__VA_ARGS__, 0, stream>>>
    // ---------- init + CSR build ----------
    init_k GK((NN + 255) / 256, 256)(cursor, stats, batch, segst);
    hist_k GK(GE4, 256)(dstI, cursor);
    scanA_k GK(NB, 1024)(cursor, rowst, bsum);
    scanB_k GK(1, 64)(bsum, bofs, NB);
    scanC_k GK((NN + 255) / 256, 256)(rowst, bofs, cursor);

    // ---------- fused: CSR fill + x@W1 GEMM (independent, co-run) ----------
    fillgemm_k GK(GE4 + NT16, 256)(srcI, dstI, cursor, csr16, x, W1_0, B0b);

    // ---------- GIN layer 0 tail: fused gather+W2 ----------
    agg_gemm_k GK(NT64, 256)(B0b, rowst, csr16, b1_0, W2_0, b2_0, B1b, s0);

    // ---------- GIN layers 1,2 (fully fused; bf16 in/out; 64-row tiles) ----------
    fused_layer_k GK(NT64, 256)(B1b, rowst, csr16, s0, bn_g + 0, bn_b + 0,
                                W1_r, b1_r, W2_r, b2_r, B2b, s1);
    fused_layer_k GK(NT64, 256)(B2b, rowst, csr16, s1, bn_g + 64, bn_b + 64,
                                W1_r + DD * DD, b1_r + DD, W2_r + DD * DD, b2_r + DD, B0b, s2);
    // B0b = z2 (pre-BN, relu'd, bf16); BN2 affine (s2, bn[2]) fused into all consumers.

    // ---------- summary maker: attention directly on z2 (512 threads) ----------
    attn3_k GK(GG, 512)(B0b, segst, s2, bn_g + 128, bn_b + 128,
                        Wq, Wk, Wv, Wih, Whh, bih, bhh, attn, slots);

    // ---------- node heads (noisy fused; bf16 outs into dead B1b/B2b) ----------
    gemm_k<64,true,true,true,true,true,true,true,true> GK(782, 256)
        (B0b, nmW, nlW, nmb, nlb, B1b, B2b, NN, s3, s4, attn, noise, s2, bn_g + 128, bn_b + 128);
    bn_apply2b_k GK(2048, 256)(B1b, B2b, out_nmu, out_nlv, NN, s3, s4,
                               pj_g + 0, pj_b + 0, pj_g + 64, pj_b + 64);

    // ---------- graph heads ----------
    gemm_k<64,true,true,true,false,false,true,false,false> GK(8, 256)
        (slots, gmW, glW, gmb, glb, gpre1, gpre2, GG, s5, s6, np, np, np, np, np);
    bn_apply2_k GK(128, 256)(gpre1, gpre2, out_gmu, out_glv, GG, s5, s6,
                             pj_g + 128, pj_b + 128, pj_g + 192, pj_b + 192);
#undef GK
}

// Round 20
// 353.328 us; speedup vs baseline: 1.0896x; 1.0663x over previous
//
#include <hip/hip_runtime.h>

#define NN 50000
#define EE 800000
#define FF 128
#define DD 64
#define GG 512

typedef unsigned short u16;

#define GE4 782     // fill blocks (4 edges/thread)
#define NT16 3125   // gemm128 16-row tiles
#define NT64 782    // 64-row node tiles

// ---------------- bf16 storage helpers (compute stays fp32) ----------------

__device__ __forceinline__ float bf2f(u16 h) {
    unsigned u = ((unsigned)h) << 16;
    return __builtin_bit_cast(float, u);
}
__device__ __forceinline__ u16 f2bf(float f) {
    unsigned u = __builtin_bit_cast(unsigned, f);
    u += 0x7fffu + ((u >> 16) & 1u);   // RNE
    return (u16)(u >> 16);
}
__device__ __forceinline__ float4 ldbf4(const u16* p) {
    uint2 v = *(const uint2*)p;
    float4 r;
    r.x = bf2f((u16)(v.x & 0xffffu)); r.y = bf2f((u16)(v.x >> 16));
    r.z = bf2f((u16)(v.y & 0xffffu)); r.w = bf2f((u16)(v.y >> 16));
    return r;
}
__device__ __forceinline__ float4 bfu2f4(uint2 v) {
    float4 r;
    r.x = bf2f((u16)(v.x & 0xffffu)); r.y = bf2f((u16)(v.x >> 16));
    r.z = bf2f((u16)(v.y & 0xffffu)); r.w = bf2f((u16)(v.y >> 16));
    return r;
}
__device__ __forceinline__ void stbf4(u16* p, float4 v) {
    uint2 o;
    o.x = (unsigned)f2bf(v.x) | ((unsigned)f2bf(v.y) << 16);
    o.y = (unsigned)f2bf(v.z) | ((unsigned)f2bf(v.w) << 16);
    *(uint2*)p = o;
}
__device__ __forceinline__ void fma4(float4& a, const float4& w, float s) {
    a.x = fmaf(s, w.x, a.x); a.y = fmaf(s, w.y, a.y);
    a.z = fmaf(s, w.z, a.z); a.w = fmaf(s, w.w, a.w);
}
__device__ __forceinline__ void add4(float4& a, float4 b) {
    a.x += b.x; a.y += b.y; a.z += b.z; a.w += b.w;
}

// 8-wide unrolled neighbor gather
__device__ __forceinline__ void gather16(float4& acc, const u16* __restrict__ in,
                                         const u16* __restrict__ csr, int e0s, int e1s,
                                         int l16, int gbase) {
    for (int e0 = e0s; e0 < e1s; e0 += 16) {
        int cnt = min(16, e1s - e0);
        int srcv = (l16 < cnt) ? (int)csr[e0 + l16] : 0;
        int j = 0;
        for (; j + 8 <= cnt; j += 8) {
            int i0 = __shfl(srcv, gbase + j);
            int i1 = __shfl(srcv, gbase + j + 1);
            int i2 = __shfl(srcv, gbase + j + 2);
            int i3 = __shfl(srcv, gbase + j + 3);
            int i4 = __shfl(srcv, gbase + j + 4);
            int i5 = __shfl(srcv, gbase + j + 5);
            int i6 = __shfl(srcv, gbase + j + 6);
            int i7 = __shfl(srcv, gbase + j + 7);
            float4 h0 = ldbf4(in + (size_t)i0 * 64 + l16 * 4);
            float4 h1 = ldbf4(in + (size_t)i1 * 64 + l16 * 4);
            float4 h2 = ldbf4(in + (size_t)i2 * 64 + l16 * 4);
            float4 h3 = ldbf4(in + (size_t)i3 * 64 + l16 * 4);
            float4 h4 = ldbf4(in + (size_t)i4 * 64 + l16 * 4);
            float4 h5 = ldbf4(in + (size_t)i5 * 64 + l16 * 4);
            float4 h6 = ldbf4(in + (size_t)i6 * 64 + l16 * 4);
            float4 h7 = ldbf4(in + (size_t)i7 * 64 + l16 * 4);
            add4(h0, h1); add4(h2, h3); add4(h4, h5); add4(h6, h7);
            add4(h0, h2); add4(h4, h6);
            add4(h0, h4);
            add4(acc, h0);
        }
        for (; j + 4 <= cnt; j += 4) {
            int i0 = __shfl(srcv, gbase + j);
            int i1 = __shfl(srcv, gbase + j + 1);
            int i2 = __shfl(srcv, gbase + j + 2);
            int i3 = __shfl(srcv, gbase + j + 3);
            float4 h0 = ldbf4(in + (size_t)i0 * 64 + l16 * 4);
            float4 h1 = ldbf4(in + (size_t)i1 * 64 + l16 * 4);
            float4 h2 = ldbf4(in + (size_t)i2 * 64 + l16 * 4);
            float4 h3 = ldbf4(in + (size_t)i3 * 64 + l16 * 4);
            add4(h0, h1); add4(h2, h3); add4(h0, h2);
            add4(acc, h0);
        }
        for (; j < cnt; ++j) {
            int s = __shfl(srcv, gbase + j);
            float4 hv = ldbf4(in + (size_t)s * 64 + l16 * 4);
            add4(acc, hv);
        }
    }
}

// ---------------- init: zero cursor/stats + segment bounds (merged) ----------------

__global__ void init_k(int* __restrict__ cursor, float* __restrict__ stats_all,
                       const int* __restrict__ batch, int* __restrict__ segstart) {
    int i = blockIdx.x * blockDim.x + threadIdx.x;
    if (i < NN) cursor[i] = 0;
    if (i < 7 * 128) stats_all[i] = 0.f;
    if (i <= GG) {
        int lo = 0, hi = NN;
        while (lo < hi) {
            int mid = (lo + hi) >> 1;
            if (batch[mid] < i) lo = mid + 1; else hi = mid;
        }
        segstart[i] = lo;
    }
}

// ---------------- CSR build ----------------

__global__ void hist_k(const int* __restrict__ dst, int* __restrict__ deg) {
    int e = (blockIdx.x * 256 + threadIdx.x) * 4;
    if (e + 4 <= EE) {
        int4 d = *(const int4*)&dst[e];
        atomicAdd(&deg[d.x], 1); atomicAdd(&deg[d.y], 1);
        atomicAdd(&deg[d.z], 1); atomicAdd(&deg[d.w], 1);
    } else {
        for (; e < EE; ++e) atomicAdd(&deg[dst[e]], 1);
    }
}

__global__ __launch_bounds__(1024) void scanA_k(const int* __restrict__ deg,
                                                int* __restrict__ rowstart,
                                                int* __restrict__ blocksum) {
    __shared__ int buf[1024];
    int tid = threadIdx.x;
    int base = blockIdx.x * 1024;
    int v = (base + tid < NN) ? deg[base + tid] : 0;
    buf[tid] = v;
    __syncthreads();
    for (int o = 1; o < 1024; o <<= 1) {
        int t = (tid >= o) ? buf[tid - o] : 0;
        __syncthreads();
        buf[tid] += t;
        __syncthreads();
    }
    if (base + tid < NN) rowstart[base + tid + 1] = buf[tid];
    if (tid == 1023) blocksum[blockIdx.x] = buf[1023];
}

__global__ void scanB_k(const int* __restrict__ blocksum, int* __restrict__ bofs, int nb) {
    int lane = threadIdx.x;  // 64 threads
    int v = (lane < nb) ? blocksum[lane] : 0;
    int orig = v;
    for (int o = 1; o < 64; o <<= 1) {
        int t = __shfl_up(v, o);
        if (lane >= o) v += t;
    }
    if (lane < nb) bofs[lane] = v - orig;
}

__global__ void scanC_k(int* __restrict__ rowstart, const int* __restrict__ bofs,
                        int* __restrict__ cursor) {
    int i = blockIdx.x * blockDim.x + threadIdx.x;
    if (i >= NN) return;
    int val = rowstart[i + 1] + bofs[i >> 10];
    rowstart[i + 1] = val;
    if (i + 1 < NN) cursor[i + 1] = val;
    if (i == 0) { rowstart[0] = 0; cursor[0] = 0; }
}

// ---------------- fused: CSR fill + x@W1 gemm, INTERLEAVED block mapping ----------------
// fill blocks at b = 4k+3 (k < GE4) so fill/gemm are co-resident from dispatch start.

__global__ __launch_bounds__(256) void fillgemm_k(
    const int* __restrict__ src, const int* __restrict__ dst,
    int* __restrict__ cursor, u16* __restrict__ csr16,
    const float* __restrict__ x, const float* __restrict__ W, u16* __restrict__ out)
{
    __shared__ u16 sW16[128 * 64];
    __shared__ float sIn[16 * 132];
    const int tid = threadIdx.x;
    const int b = blockIdx.x;

    if ((b & 3) == 3 && (b >> 2) < GE4) {
        // ---- fill ----
        int e = ((b >> 2) * 256 + tid) * 4;
        if (e + 4 <= EE) {
            int4 d = *(const int4*)&dst[e];
            int4 s = *(const int4*)&src[e];
            int p0 = atomicAdd(&cursor[d.x], 1);
            int p1 = atomicAdd(&cursor[d.y], 1);
            int p2 = atomicAdd(&cursor[d.z], 1);
            int p3 = atomicAdd(&cursor[d.w], 1);
            csr16[p0] = (u16)s.x; csr16[p1] = (u16)s.y;
            csr16[p2] = (u16)s.z; csr16[p3] = (u16)s.w;
        } else {
            for (; e < EE; ++e) { int p = atomicAdd(&cursor[dst[e]], 1); csr16[p] = (u16)src[e]; }
        }
        return;
    }

    // ---- gemm128 ----
    const int gb = b - min(b >> 2, GE4);
    for (int i = tid * 4; i < 128 * 64; i += 1024) {
        float4 w = *(const float4*)(W + i);
        uint2 pk;
        pk.x = (unsigned)f2bf(w.x) | ((unsigned)f2bf(w.y) << 16);
        pk.y = (unsigned)f2bf(w.z) | ((unsigned)f2bf(w.w) << 16);
        *(uint2*)&sW16[i] = pk;
    }
    const int tile = gb * 16;
    const int nrows = min(16, NN - tile);
    for (int i = tid; i < 16 * 32; i += 256) {
        int rr = i >> 5, kk = (i & 31) * 4;
        float4 t = (rr < nrows) ? *(const float4*)(x + (size_t)(tile + rr) * 128 + kk)
                                : make_float4(0.f, 0.f, 0.f, 0.f);
        *(float4*)&sIn[rr * 132 + kk] = t;
    }
    __syncthreads();
    int rg = tid >> 4, c0 = (tid & 15) << 2;
    float4 acc = make_float4(0.f, 0.f, 0.f, 0.f);
#pragma unroll 4
    for (int k4 = 0; k4 < 32; ++k4) {
        float4 av = *(const float4*)&sIn[rg * 132 + k4 * 4];
        float as[4] = {av.x, av.y, av.z, av.w};
#pragma unroll
        for (int kk = 0; kk < 4; ++kk) {
            uint2 wp = *(const uint2*)&sW16[(k4 * 4 + kk) * 64 + c0];
            fma4(acc, bfu2f4(wp), as[kk]);
        }
    }
    if (rg < nrows) stbf4(out + (size_t)(tile + rg) * 64 + c0, acc);
}

// ---------------- fused gather + W2 GEMM (layer 0 tail), 64-row tiles ----------------

__global__ __launch_bounds__(256) void agg_gemm_k(
    const u16* __restrict__ in,
    const int* __restrict__ rowstart, const u16* __restrict__ csr,
    const float* __restrict__ bias1,
    const float* __restrict__ W2, const float* __restrict__ bias2,
    u16* __restrict__ out, float* __restrict__ gstats)
{
    constexpr int KP = 68;
    __shared__ float sW[64 * 64];
    __shared__ float sIn[64 * KP];
    __shared__ float sStat[128];
    const int tid = threadIdx.x;

    for (int i = tid; i < 64 * 16; i += 256) ((float4*)sW)[i] = ((const float4*)W2)[i];

    const int tile = blockIdx.x * 64;
    const int nrows = min(64, NN - tile);
    const int l16 = tid & 15, gbase = tid & 48, grp = tid >> 4;
    float4 b1v = ((const float4*)bias1)[l16];
    for (int r = grp; r < nrows; r += 16) {
        int node = tile + r;
        float4 acc = ldbf4(in + (size_t)node * 64 + l16 * 4);
        gather16(acc, in, csr, rowstart[node], rowstart[node + 1], l16, gbase);
        acc.x = fmaxf(acc.x + b1v.x, 0.f); acc.y = fmaxf(acc.y + b1v.y, 0.f);
        acc.z = fmaxf(acc.z + b1v.z, 0.f); acc.w = fmaxf(acc.w + b1v.w, 0.f);
        *(float4*)&sIn[r * KP + l16 * 4] = acc;
    }
    __syncthreads();

    const int rg = (tid >> 4) * 4, c0 = (tid & 15) << 2;
    float4 bb = *(const float4*)&bias2[c0];
    float4 acc[4];
#pragma unroll
    for (int j = 0; j < 4; ++j) acc[j] = bb;
#pragma unroll 2
    for (int k4 = 0; k4 < 16; ++k4) {
        float4 av[4];
#pragma unroll
        for (int j = 0; j < 4; ++j) av[j] = *(const float4*)&sIn[(rg + j) * KP + k4 * 4];
        const float* wp = &sW[k4 * 4 * 64 + c0];
        float4 w0 = *(const float4*)(wp);
        float4 w1 = *(const float4*)(wp + 64);
        float4 w2 = *(const float4*)(wp + 128);
        float4 w3 = *(const float4*)(wp + 192);
#pragma unroll
        for (int j = 0; j < 4; ++j) {
            fma4(acc[j], w0, av[j].x); fma4(acc[j], w1, av[j].y);
            fma4(acc[j], w2, av[j].z); fma4(acc[j], w3, av[j].w);
        }
    }
#pragma unroll
    for (int j = 0; j < 4; ++j) {
        acc[j].x = fmaxf(acc[j].x, 0.f); acc[j].y = fmaxf(acc[j].y, 0.f);
        acc[j].z = fmaxf(acc[j].z, 0.f); acc[j].w = fmaxf(acc[j].w, 0.f);
        if (rg + j < nrows) stbf4(out + (size_t)(tile + rg + j) * 64 + c0, acc[j]);
    }
    if (tid < 128) sStat[tid] = 0.f;
    __syncthreads();
    float sx = 0, sy = 0, sz = 0, sw = 0, qx = 0, qy = 0, qz = 0, qw = 0;
#pragma unroll
    for (int j = 0; j < 4; ++j) {
        if (rg + j < nrows) {
            sx += acc[j].x; sy += acc[j].y; sz += acc[j].z; sw += acc[j].w;
            qx += acc[j].x * acc[j].x; qy += acc[j].y * acc[j].y;
            qz += acc[j].z * acc[j].z; qw += acc[j].w * acc[j].w;
        }
    }
    atomicAdd(&sStat[c0 + 0], sx); atomicAdd(&sStat[c0 + 1], sy);
    atomicAdd(&sStat[c0 + 2], sz); atomicAdd(&sStat[c0 + 3], sw);
    atomicAdd(&sStat[64 + c0 + 0], qx); atomicAdd(&sStat[64 + c0 + 1], qy);
    atomicAdd(&sStat[64 + c0 + 2], qz); atomicAdd(&sStat[64 + c0 + 3], qw);
    __syncthreads();
    if (tid < 128) atomicAdd(&gstats[tid], sStat[tid]);
}

// ---------------- fully fused GIN layer (layers 1,2), 64-row tiles ----------------

__global__ __launch_bounds__(256) void fused_layer_k(
    const u16* __restrict__ in,
    const int* __restrict__ rowstart, const u16* __restrict__ csr,
    const float* __restrict__ bnst, const float* __restrict__ gam, const float* __restrict__ bet,
    const float* __restrict__ W1, const float* __restrict__ b1,
    const float* __restrict__ W2, const float* __restrict__ b2,
    u16* __restrict__ out, float* __restrict__ gstats)
{
    constexpr int KP = 68;
    __shared__ float sW[64 * 64];      // W1 then reloaded with W2
    __shared__ float sAgg[64 * KP];
    __shared__ float sStat[128];
    __shared__ float aL[64], dL[64];
    const int tid = threadIdx.x;

    for (int i = tid; i < 64 * 16; i += 256) ((float4*)sW)[i] = ((const float4*)W1)[i];
    if (tid < 64) {
        float m = bnst[tid] * (1.f / NN);
        float v = bnst[64 + tid] * (1.f / NN) - m * m;
        float a = rsqrtf(v + 1e-5f) * gam[tid];
        aL[tid] = a;
        dL[tid] = bet[tid] - m * a;
    }
    __syncthreads();

    const int tile = blockIdx.x * 64;
    const int nrows = min(64, NN - tile);
    const int l16 = tid & 15, gbase = tid & 48, grp = tid >> 4;
    float4 av4 = *(const float4*)&aL[l16 * 4];
    float4 dv4 = *(const float4*)&dL[l16 * 4];
    for (int r = grp; r < nrows; r += 16) {
        int node = tile + r;
        int e0s = rowstart[node], e1s = rowstart[node + 1];
        float4 acc = ldbf4(in + (size_t)node * 64 + l16 * 4);
        gather16(acc, in, csr, e0s, e1s, l16, gbase);
        float dp1 = (float)(e1s - e0s + 1);
        acc.x = fmaf(av4.x, acc.x, dp1 * dv4.x);
        acc.y = fmaf(av4.y, acc.y, dp1 * dv4.y);
        acc.z = fmaf(av4.z, acc.z, dp1 * dv4.z);
        acc.w = fmaf(av4.w, acc.w, dp1 * dv4.w);
        *(float4*)&sAgg[r * KP + l16 * 4] = acc;
    }
    __syncthreads();

    const int rg = (tid >> 4) * 4, c0 = (tid & 15) << 2;
    float4 t[4];
    {
        float4 bb = *(const float4*)&b1[c0];
#pragma unroll
        for (int j = 0; j < 4; ++j) t[j] = bb;
#pragma unroll 2
        for (int k4 = 0; k4 < 16; ++k4) {
            float4 a0[4];
#pragma unroll
            for (int j = 0; j < 4; ++j) a0[j] = *(const float4*)&sAgg[(rg + j) * KP + k4 * 4];
            const float* wp = &sW[k4 * 4 * 64 + c0];
            float4 w0 = *(const float4*)(wp);
            float4 w1 = *(const float4*)(wp + 64);
            float4 w2 = *(const float4*)(wp + 128);
            float4 w3 = *(const float4*)(wp + 192);
#pragma unroll
            for (int j = 0; j < 4; ++j) {
                fma4(t[j], w0, a0[j].x); fma4(t[j], w1, a0[j].y);
                fma4(t[j], w2, a0[j].z); fma4(t[j], w3, a0[j].w);
            }
        }
#pragma unroll
        for (int j = 0; j < 4; ++j) {
            t[j].x = fmaxf(t[j].x, 0.f); t[j].y = fmaxf(t[j].y, 0.f);
            t[j].z = fmaxf(t[j].z, 0.f); t[j].w = fmaxf(t[j].w, 0.f);
        }
    }
    __syncthreads();

    for (int i = tid; i < 64 * 16; i += 256) ((float4*)sW)[i] = ((const float4*)W2)[i];
#pragma unroll
    for (int j = 0; j < 4; ++j) *(float4*)&sAgg[(rg + j) * KP + c0] = t[j];
    __syncthreads();

    float4 acc[4];
    {
        float4 bb = *(const float4*)&b2[c0];
#pragma unroll
        for (int j = 0; j < 4; ++j) acc[j] = bb;
#pragma unroll 2
        for (int k4 = 0; k4 < 16; ++k4) {
            float4 a0[4];
#pragma unroll
            for (int j = 0; j < 4; ++j) a0[j] = *(const float4*)&sAgg[(rg + j) * KP + k4 * 4];
            const float* wp = &sW[k4 * 4 * 64 + c0];
            float4 w0 = *(const float4*)(wp);
            float4 w1 = *(const float4*)(wp + 64);
            float4 w2 = *(const float4*)(wp + 128);
            float4 w3 = *(const float4*)(wp + 192);
#pragma unroll
            for (int j = 0; j < 4; ++j) {
                fma4(acc[j], w0, a0[j].x); fma4(acc[j], w1, a0[j].y);
                fma4(acc[j], w2, a0[j].z); fma4(acc[j], w3, a0[j].w);
            }
        }
    }
#pragma unroll
    for (int j = 0; j < 4; ++j) {
        acc[j].x = fmaxf(acc[j].x, 0.f); acc[j].y = fmaxf(acc[j].y, 0.f);
        acc[j].z = fmaxf(acc[j].z, 0.f); acc[j].w = fmaxf(acc[j].w, 0.f);
        if (rg + j < nrows) stbf4(out + (size_t)(tile + rg + j) * 64 + c0, acc[j]);
    }
    if (tid < 128) sStat[tid] = 0.f;
    __syncthreads();
    float sx = 0, sy = 0, sz = 0, sw = 0, qx = 0, qy = 0, qz = 0, qw = 0;
#pragma unroll
    for (int j = 0; j < 4; ++j) {
        if (rg + j < nrows) {
            sx += acc[j].x; sy += acc[j].y; sz += acc[j].z; sw += acc[j].w;
            qx += acc[j].x * acc[j].x; qy += acc[j].y * acc[j].y;
            qz += acc[j].z * acc[j].z; qw += acc[j].w * acc[j].w;
        }
    }
    atomicAdd(&sStat[c0 + 0], sx); atomicAdd(&sStat[c0 + 1], sy);
    atomicAdd(&sStat[c0 + 2], sz); atomicAdd(&sStat[c0 + 3], sw);
    atomicAdd(&sStat[64 + c0 + 0], qx); atomicAdd(&sStat[64 + c0 + 1], qy);
    atomicAdd(&sStat[64 + c0 + 2], qz); atomicAdd(&sStat[64 + c0 + 3], qw);
    __syncthreads();
    if (tid < 128) atomicAdd(&gstats[tid], sStat[tid]);
}

// ---------------- generic 64-K GEMM tile body (dynamic LDS) ----------------
// Single tile per call. T(in): optional BNIN affine + ROWSCALE(attn*x+noise).

template<bool STATS, bool ROWSCALE, bool BNIN, bool INBF, bool OUTBF>
__device__ void gemm_dev(char* smem, int tile, int rows,
    const void* __restrict__ in, const float* __restrict__ W, const float* __restrict__ Wb,
    const float* __restrict__ bias, const float* __restrict__ bias2,
    void* __restrict__ out, void* __restrict__ out2,
    float* __restrict__ gstats, float* __restrict__ gstats2,
    const float* __restrict__ attn, const float* __restrict__ noise,
    const float* __restrict__ bnstats, const float* __restrict__ gamma,
    const float* __restrict__ beta)
{
    constexpr int KP = 68;
    float* sW    = (float*)smem;          // 64*64
    float* sWb   = sW + 64 * 64;          // 64*64
    float* sIn   = sWb + 64 * 64;         // 64*KP
    float* sStat = sIn + 64 * KP;         // 256
    float* sA    = sStat + 256;           // 64
    float* sD    = sA + 64;               // 64
    const int tid = threadIdx.x;

    for (int i = tid; i < 64 * 16; i += 256) {
        ((float4*)sW)[i]  = ((const float4*)W)[i];
        ((float4*)sWb)[i] = ((const float4*)Wb)[i];
    }
    if (BNIN && tid < 64) {
        float m = bnstats[tid] * (1.f / NN);
        float v = bnstats[64 + tid] * (1.f / NN) - m * m;
        float a = rsqrtf(v + 1e-5f) * gamma[tid];
        sA[tid] = a;
        sD[tid] = beta[tid] - m * a;
    }
    __syncthreads();

    int nrows = min(64, rows - tile);
    const float4* igf = INBF ? nullptr : (const float4*)((const float*)in + (size_t)tile * 64);
    const u16*    igb = INBF ? ((const u16*)in + (size_t)tile * 64) : nullptr;
    const float4* ng  = ROWSCALE ? (const float4*)(noise + (size_t)tile * 64) : nullptr;
    for (int i = tid; i < nrows * 16; i += 256) {
        int rr = i >> 4, kk = (i & 15) * 4;
        float4 t = INBF ? ldbf4(igb + i * 4) : igf[i];
        if (BNIN) {
            t.x = fmaf(sA[kk + 0], t.x, sD[kk + 0]);
            t.y = fmaf(sA[kk + 1], t.y, sD[kk + 1]);
            t.z = fmaf(sA[kk + 2], t.z, sD[kk + 2]);
            t.w = fmaf(sA[kk + 3], t.w, sD[kk + 3]);
        }
        if (ROWSCALE) {
            float4 nv = ng[i];
            float at = attn[tile + rr];
            t.x = fmaf(at, t.x, nv.x); t.y = fmaf(at, t.y, nv.y);
            t.z = fmaf(at, t.z, nv.z); t.w = fmaf(at, t.w, nv.w);
        }
        *(float4*)&sIn[rr * KP + kk] = t;
    }
    __syncthreads();

    const int rg = (tid >> 4) * 4, c0 = (tid & 15) << 2;
    float4 bb  = *(const float4*)&bias[c0];
    float4 bb2 = *(const float4*)&bias2[c0];
    float4 acc[4], acc2[4];
#pragma unroll
    for (int j = 0; j < 4; ++j) { acc[j] = bb; acc2[j] = bb2; }
#pragma unroll 2
    for (int k4 = 0; k4 < 16; ++k4) {
        float4 av[4];
#pragma unroll
        for (int j = 0; j < 4; ++j)
            av[j] = *(const float4*)&sIn[(rg + j) * KP + k4 * 4];
        const float* wp = &sW[k4 * 4 * 64 + c0];
        float4 w0 = *(const float4*)(wp);
        float4 w1 = *(const float4*)(wp + 64);
        float4 w2 = *(const float4*)(wp + 128);
        float4 w3 = *(const float4*)(wp + 192);
#pragma unroll
        for (int j = 0; j < 4; ++j) {
            fma4(acc[j], w0, av[j].x); fma4(acc[j], w1, av[j].y);
            fma4(acc[j], w2, av[j].z); fma4(acc[j], w3, av[j].w);
        }
        const float* wq = &sWb[k4 * 4 * 64 + c0];
        float4 u0 = *(const float4*)(wq);
        float4 u1 = *(const float4*)(wq + 64);
        float4 u2 = *(const float4*)(wq + 128);
        float4 u3 = *(const float4*)(wq + 192);
#pragma unroll
        for (int j = 0; j < 4; ++j) {
            fma4(acc2[j], u0, av[j].x); fma4(acc2[j], u1, av[j].y);
            fma4(acc2[j], u2, av[j].z); fma4(acc2[j], u3, av[j].w);
        }
    }
#pragma unroll
    for (int j = 0; j < 4; ++j) {
        acc[j].x = fmaxf(acc[j].x, 0.f);   acc[j].y = fmaxf(acc[j].y, 0.f);
        acc[j].z = fmaxf(acc[j].z, 0.f);   acc[j].w = fmaxf(acc[j].w, 0.f);
        acc2[j].x = fmaxf(acc2[j].x, 0.f); acc2[j].y = fmaxf(acc2[j].y, 0.f);
        acc2[j].z = fmaxf(acc2[j].z, 0.f); acc2[j].w = fmaxf(acc2[j].w, 0.f);
        int r = rg + j;
        if (r < nrows) {
            if (OUTBF) {
                stbf4((u16*)out  + (size_t)(tile + r) * 64 + c0, acc[j]);
                stbf4((u16*)out2 + (size_t)(tile + r) * 64 + c0, acc2[j]);
            } else {
                *(float4*)((float*)out  + (size_t)(tile + r) * 64 + c0) = acc[j];
                *(float4*)((float*)out2 + (size_t)(tile + r) * 64 + c0) = acc2[j];
            }
        }
    }
    if (STATS) {
        if (tid < 256) sStat[tid] = 0.f;
        __syncthreads();
        float sx = 0, sy = 0, sz = 0, sw = 0, qx = 0, qy = 0, qz = 0, qw = 0;
        float sx2 = 0, sy2 = 0, sz2 = 0, sw2 = 0, qx2 = 0, qy2 = 0, qz2 = 0, qw2 = 0;
#pragma unroll
        for (int j = 0; j < 4; ++j) {
            if (rg + j < nrows) {
                sx += acc[j].x; sy += acc[j].y; sz += acc[j].z; sw += acc[j].w;
                qx += acc[j].x * acc[j].x; qy += acc[j].y * acc[j].y;
                qz += acc[j].z * acc[j].z; qw += acc[j].w * acc[j].w;
                sx2 += acc2[j].x; sy2 += acc2[j].y; sz2 += acc2[j].z; sw2 += acc2[j].w;
                qx2 += acc2[j].x * acc2[j].x; qy2 += acc2[j].y * acc2[j].y;
                qz2 += acc2[j].z * acc2[j].z; qw2 += acc2[j].w * acc2[j].w;
            }
        }
        atomicAdd(&sStat[c0 + 0], sx); atomicAdd(&sStat[c0 + 1], sy);
        atomicAdd(&sStat[c0 + 2], sz); atomicAdd(&sStat[c0 + 3], sw);
        atomicAdd(&sStat[64 + c0 + 0], qx); atomicAdd(&sStat[64 + c0 + 1], qy);
        atomicAdd(&sStat[64 + c0 + 2], qz); atomicAdd(&sStat[64 + c0 + 3], qw);
        atomicAdd(&sStat[128 + c0 + 0], sx2); atomicAdd(&sStat[128 + c0 + 1], sy2);
        atomicAdd(&sStat[128 + c0 + 2], sz2); atomicAdd(&sStat[128 + c0 + 3], sw2);
        atomicAdd(&sStat[192 + c0 + 0], qx2); atomicAdd(&sStat[192 + c0 + 1], qy2);
        atomicAdd(&sStat[192 + c0 + 2], qz2); atomicAdd(&sStat[192 + c0 + 3], qw2);
        __syncthreads();
        if (tid < 128) atomicAdd(&gstats[tid], sStat[tid]);
        else atomicAdd(&gstats2[tid - 128], sStat[tid - 128 < 128 ? tid : tid]);
        if (tid >= 128) {} // handled above
    }
}

// ---------------- heads: node DUAL gemm (blocks 0..NT64-1) + graph DUAL gemm (blocks NT64..NT64+7) ----------------

__global__ __launch_bounds__(256) void heads_k(
    const u16* __restrict__ z2, const float* __restrict__ attn, const float* __restrict__ noise,
    const float* __restrict__ s2, const float* __restrict__ bng2, const float* __restrict__ bnb2,
    const float* __restrict__ nmW, const float* __restrict__ nmb,
    const float* __restrict__ nlW, const float* __restrict__ nlb,
    u16* __restrict__ nmu_b, u16* __restrict__ nlv_b,
    float* __restrict__ s3, float* __restrict__ s4,
    const float* __restrict__ slots,
    const float* __restrict__ gmW, const float* __restrict__ gmb,
    const float* __restrict__ glW, const float* __restrict__ glb,
    float* __restrict__ gpre1, float* __restrict__ gpre2,
    float* __restrict__ s5, float* __restrict__ s6)
{
    extern __shared__ char smem[];
    if (blockIdx.x < NT64) {
        gemm_dev<true, true, true, true, true>(smem, blockIdx.x * 64, NN,
            z2, nmW, nlW, nmb, nlb, nmu_b, nlv_b, s3, s4, attn, noise, s2, bng2, bnb2);
    } else {
        gemm_dev<true, false, false, false, false>(smem, (int)(blockIdx.x - NT64) * 64, GG,
            slots, gmW, glW, gmb, glb, gpre1, gpre2, s5, s6,
            nullptr, nullptr, nullptr, nullptr, nullptr);
    }
}

// ---------------- merged BN apply: node pair (bf16 in) + graph pair (fp32 in) ----------------

__global__ void bn_all_k(const u16* __restrict__ n1, const u16* __restrict__ n2,
                         const float* __restrict__ g1in, const float* __restrict__ g2in,
                         float* __restrict__ o1, float* __restrict__ o2,
                         float* __restrict__ o3, float* __restrict__ o4,
                         const float* __restrict__ st3, const float* __restrict__ st4,
                         const float* __restrict__ st5, const float* __restrict__ st6,
                         const float* __restrict__ pj_g, const float* __restrict__ pj_b) {
    int total = NN * 64 + GG * 64;
    for (int i = blockIdx.x * blockDim.x + threadIdx.x; i < total; i += gridDim.x * blockDim.x) {
        if (i < NN * 64) {
            int c = i & 63;
            float m1 = st3[c] * (1.f / NN);
            float v1 = st3[64 + c] * (1.f / NN) - m1 * m1;
            o1[i] = (bf2f(n1[i]) - m1) * rsqrtf(v1 + 1e-5f) * pj_g[c] + pj_b[c];
            float m2 = st4[c] * (1.f / NN);
            float v2 = st4[64 + c] * (1.f / NN) - m2 * m2;
            o2[i] = (bf2f(n2[i]) - m2) * rsqrtf(v2 + 1e-5f) * pj_g[64 + c] + pj_b[64 + c];
        } else {
            int j = i - NN * 64;
            int c = j & 63;
            float m1 = st5[c] * (1.f / GG);
            float v1 = st5[64 + c] * (1.f / GG) - m1 * m1;
            o3[j] = (g1in[j] - m1) * rsqrtf(v1 + 1e-5f) * pj_g[128 + c] + pj_b[128 + c];
            float m2 = st6[c] * (1.f / GG);
            float v2 = st6[64 + c] * (1.f / GG) - m2 * m2;
            o4[j] = (g2in[j] - m2) * rsqrtf(v2 + 1e-5f) * pj_g[192 + c] + pj_b[192 + c];
        }
    }
}

// ---------------- attention on z (bf16) directly; 512 threads, 8 scan groups ----------------

__global__ __launch_bounds__(512) void attn3_k(
    const u16* __restrict__ z, const int* __restrict__ segst,
    const float* __restrict__ bnst, const float* __restrict__ gam, const float* __restrict__ bet,
    const float* __restrict__ Wq, const float* __restrict__ Wk, const float* __restrict__ Wv,
    const float* __restrict__ Wih, const float* __restrict__ Whh,
    const float* __restrict__ bih, const float* __restrict__ bhh,
    float* __restrict__ attn, float* __restrict__ slots_out)
{
    int g = blockIdx.x, tid = threadIdx.x, w = tid >> 6, lane = tid & 63;
    __shared__ float ssl[64], sq[64], swr[64], sm[64], supd[64], sred[512], ssum[8];
    __shared__ float aL[64], dL[64];
    __shared__ float sgi[192], sgh[192];
    __shared__ float sc, sinv;

    int s0 = segst[g], s1 = segst[g + 1];
    if (tid < 64) {
        float m = bnst[tid] * (1.f / NN);
        float v = bnst[64 + tid] * (1.f / NN) - m * m;
        float a = rsqrtf(v + 1e-5f) * gam[tid];
        aL[tid] = a;
        dL[tid] = bet[tid] - m * a;
    }
    __syncthreads();

    {
        float macc = 0.f;
        for (int n = s0 + w; n < s1; n += 8) macc += bf2f(z[(size_t)n * 64 + lane]);
        sred[tid] = macc;
        __syncthreads();
        if (tid < 64) {
            float s = 0.f;
#pragma unroll
            for (int k = 0; k < 8; ++k) s += sred[tid + 64 * k];
            ssl[tid] = fmaf(aL[tid], s / (float)max(s1 - s0, 1), dL[tid]);
        }
        __syncthreads();
    }

    for (int it = 0; it < 2; ++it) {
        {
            float p = 0.f;
#pragma unroll
            for (int kk = 0; kk < 8; ++kk) p += ssl[w * 8 + kk] * Wq[(w * 8 + kk) * 64 + lane];
            sred[tid] = p;
        }
        __syncthreads();
        if (tid < 64) {
            float s = 0.f;
#pragma unroll
            for (int k = 0; k < 8; ++k) s += sred[tid + 64 * k];
            sq[tid] = s;
        }
        __syncthreads();
        {
            float p = 0.f;
#pragma unroll
            for (int kk = 0; kk < 8; ++kk) p += Wk[lane * 64 + w * 8 + kk] * sq[w * 8 + kk];
            sred[tid] = p;
        }
        __syncthreads();
        if (tid < 64) {
            float s = 0.f;
#pragma unroll
            for (int k = 0; k < 8; ++k) s += sred[tid + 64 * k];
            swr[tid] = s;
        }
        __syncthreads();
        if (tid < 64) {
            float pr = dL[tid] * swr[tid];
            pr += __shfl_xor(pr, 1);  pr += __shfl_xor(pr, 2);  pr += __shfl_xor(pr, 4);
            pr += __shfl_xor(pr, 8);  pr += __shfl_xor(pr, 16); pr += __shfl_xor(pr, 32);
            if (tid == 0) sc = pr * 0.125f;
            swr[tid] = aL[tid] * swr[tid] * 0.125f;
        }
        __syncthreads();
        float wl = swr[lane], cc = sc;

        float s = 0.f, u = 0.f;
        for (int n = s0 + w; n < s1; n += 8) {
            float zl = bf2f(z[(size_t)n * 64 + lane]);
            float l = zl * wl;
            l += __shfl_xor(l, 1);  l += __shfl_xor(l, 2);  l += __shfl_xor(l, 4);
            l += __shfl_xor(l, 8);  l += __shfl_xor(l, 16); l += __shfl_xor(l, 32);
            float e = expf(l + cc);
            if (lane == 0) attn[n] = e;
            s += e;
            u = fmaf(e, zl, u);
        }
        sred[tid] = u;
        if (lane == 0) ssum[w] = s;
        __syncthreads();
        if (tid < 64) {
            float stot = ssum[0] + ssum[1] + ssum[2] + ssum[3]
                       + ssum[4] + ssum[5] + ssum[6] + ssum[7] + 1e-9f;
            if (tid == 0) sinv = 1.f / stot;
            float uu = 0.f;
#pragma unroll
            for (int k = 0; k < 8; ++k) uu += sred[tid + 64 * k];
            sm[tid] = fmaf(aL[tid], uu / stot, dL[tid]);
        }
        __syncthreads();
        {
            float p = 0.f;
#pragma unroll
            for (int kk = 0; kk < 8; ++kk) p += sm[w * 8 + kk] * Wv[(w * 8 + kk) * 64 + lane];
            sred[tid] = p;
        }
        __syncthreads();
        if (tid < 64) {
            float s2 = 0.f;
#pragma unroll
            for (int k = 0; k < 8; ++k) s2 += sred[tid + 64 * k];
            supd[tid] = s2;
        }
        __syncthreads();

        if (it == 1) {
            float inv = sinv;
            for (int n = s0 + tid; n < s1; n += 512) attn[n] *= inv;
        }

        if (tid < 192) {
            float a = bih[tid], b = bhh[tid];
            const float* wi = &Wih[tid * 64];
            const float* wh = &Whh[tid * 64];
#pragma unroll 8
            for (int j = 0; j < 64; ++j) { a += supd[j] * wi[j]; b += ssl[j] * wh[j]; }
            sgi[tid] = a; sgh[tid] = b;
        }
        __syncthreads();
        if (tid < 64) {
            float r  = 1.f / (1.f + expf(-(sgi[tid] + sgh[tid])));
            float zz = 1.f / (1.f + expf(-(sgi[64 + tid] + sgh[64 + tid])));
            float nn = tanhf(sgi[128 + tid] + r * sgh[128 + tid]);
            float ns = (1.f - zz) * nn + zz * ssl[tid];
            ssl[tid] = ns;
            if (it == 1) slots_out[g * 64 + tid] = ns;
        }
        __syncthreads();
    }
}

// ---------------- host side ----------------

extern "C" void kernel_launch(void* const* d_in, const int* in_sizes, int n_in,
                              void* d_out, int out_size, void* d_ws, size_t ws_size,
                              hipStream_t stream) {
    (void)in_sizes; (void)n_in; (void)out_size; (void)ws_size;

    const float* x      = (const float*)d_in[0];
    const int*   ei     = (const int*)d_in[1];
    const int*   srcI   = ei;
    const int*   dstI   = ei + EE;
    const int*   batch  = (const int*)d_in[2];
    const float* noise  = (const float*)d_in[3];
    const float* W1_0   = (const float*)d_in[4];
    const float* b1_0   = (const float*)d_in[5];
    const float* W2_0   = (const float*)d_in[6];
    const float* b2_0   = (const float*)d_in[7];
    const float* W1_r   = (const float*)d_in[8];
    const float* b1_r   = (const float*)d_in[9];
    const float* W2_r   = (const float*)d_in[10];
    const float* b2_r   = (const float*)d_in[11];
    const float* bn_g   = (const float*)d_in[12];
    const float* bn_b   = (const float*)d_in[13];
    const float* Wq     = (const float*)d_in[14];
    const float* Wk     = (const float*)d_in[15];
    const float* Wv     = (const float*)d_in[16];
    const float* Wih    = (const float*)d_in[17];
    const float* Whh    = (const float*)d_in[18];
    const float* bih    = (const float*)d_in[19];
    const float* bhh    = (const float*)d_in[20];
    const float* nmW    = (const float*)d_in[21];
    const float* nmb    = (const float*)d_in[22];
    const float* nlW    = (const float*)d_in[23];
    const float* nlb    = (const float*)d_in[24];
    const float* gmW    = (const float*)d_in[25];
    const float* gmb    = (const float*)d_in[26];
    const float* glW    = (const float*)d_in[27];
    const float* glb    = (const float*)d_in[28];
    const float* pj_g   = (const float*)d_in[29];
    const float* pj_b   = (const float*)d_in[30];

    char* w = (char*)d_ws;
    u16*   B0b   = (u16*)w;            w += (size_t)NN * 64 * 2;
    u16*   B1b   = (u16*)w;            w += (size_t)NN * 64 * 2;
    u16*   B2b   = (u16*)w;            w += (size_t)NN * 64 * 2;
    float* slots = (float*)w;          w += GG * 64 * 4;
    float* gpre1 = (float*)w;          w += GG * 64 * 4;
    float* gpre2 = (float*)w;          w += GG * 64 * 4;
    float* attn  = (float*)w;          w += NN * 4;
    float* stats = (float*)w;          w += 7 * 128 * 4;
    int*   segst = (int*)w;            w += (GG + 1) * 4;
    int*   rowst = (int*)w;            w += (NN + 1) * 4;
    int*   cursor= (int*)w;            w += NN * 4;
    int*   bsum  = (int*)w;            w += 64 * 4;
    int*   bofs  = (int*)w;            w += 64 * 4;
    u16*   csr16 = (u16*)w;            w += (size_t)EE * 2;

    float* s0 = stats, *s1 = stats + 128, *s2 = stats + 256, *s3 = stats + 384,
         * s4 = stats + 512, *s5 = stats + 640, *s6 = stats + 768;

    float* outp = (float*)d_out;
    float* out_nmu = outp;
    float* out_nlv = outp + NN * DD;
    float* out_gmu = outp + 2 * NN * DD;
    float* out_glv = outp + 2 * NN * DD + GG * DD;

    constexpr int NB = (NN + 1023) / 1024;       // 49 scan chunks
    constexpr size_t HEAD_SMEM = (64 * 64 * 2 + 64 * 68 + 256 + 128) * sizeof(float);

#define GK(...) <<<__VA_ARGS__>>>
    // ---------- init + CSR build ----------
    init_k GK((NN + 255) / 256, 256, 0, stream)(cursor, stats, batch, segst);
    hist_k GK(GE4, 256, 0, stream)(dstI, cursor);
    scanA_k GK(NB, 1024, 0, stream)(cursor, rowst, bsum);
    scanB_k GK(1, 64, 0, stream)(bsum, bofs, NB);
    scanC_k GK((NN + 255) / 256, 256, 0, stream)(rowst, bofs, cursor);

    // ---------- fused: CSR fill + x@W1 GEMM (interleaved co-run) ----------
    fillgemm_k GK(GE4 + NT16, 256, 0, stream)(srcI, dstI, cursor, csr16, x, W1_0, B0b);

    // ---------- GIN layer 0 tail: fused gather+W2 ----------
    agg_gemm_k GK(NT64, 256, 0, stream)(B0b, rowst, csr16, b1_0, W2_0, b2_0, B1b, s0);

    // ---------- GIN layers 1,2 ----------
    fused_layer_k GK(NT64, 256, 0, stream)(B1b, rowst, csr16, s0, bn_g + 0, bn_b + 0,
                                           W1_r, b1_r, W2_r, b2_r, B2b, s1);
    fused_layer_k GK(NT64, 256, 0, stream)(B2b, rowst, csr16, s1, bn_g + 64, bn_b + 64,
                                           W1_r + DD * DD, b1_r + DD, W2_r + DD * DD, b2_r + DD,
                                           B0b, s2);
    // B0b = z2 (pre-BN, relu'd, bf16)

    // ---------- summary maker ----------
    attn3_k GK(GG, 512, 0, stream)(B0b, segst, s2, bn_g + 128, bn_b + 128,
                                   Wq, Wk, Wv, Wih, Whh, bih, bhh, attn, slots);

    // ---------- heads: node DUAL (782 blocks) + graph DUAL (8 blocks), one launch ----------
    heads_k GK(NT64 + 8, 256, HEAD_SMEM, stream)(
        B0b, attn, noise, s2, bn_g + 128, bn_b + 128,
        nmW, nmb, nlW, nlb, B1b, B2b, s3, s4,
        slots, gmW, gmb, glW, glb, gpre1, gpre2, s5, s6);

    // ---------- merged final BN (all four outputs) ----------
    bn_all_k GK(2048, 256, 0, stream)(B1b, B2b, gpre1, gpre2,
                                      out_nmu, out_nlv, out_gmu, out_glv,
                                      s3, s4, s5, s6, pj_g, pj_b);
#undef GK
}

// Round 21
// 352.381 us; speedup vs baseline: 1.0925x; 1.0027x over previous
//
#include <hip/hip_runtime.h>

#define NN 50000
#define EE 800000
#define FF 128
#define DD 64
#define GG 512

typedef unsigned short u16;

#define GE4 782     // fill/hist blocks (4 edges/thread)
#define NT16 3125   // gemm128 16-row tiles
#define NT64 782    // 64-row node tiles

// ---------------- bf16 storage helpers (compute stays fp32) ----------------

__device__ __forceinline__ float bf2f(u16 h) {
    unsigned u = ((unsigned)h) << 16;
    return __builtin_bit_cast(float, u);
}
__device__ __forceinline__ u16 f2bf(float f) {
    unsigned u = __builtin_bit_cast(unsigned, f);
    u += 0x7fffu + ((u >> 16) & 1u);   // RNE
    return (u16)(u >> 16);
}
__device__ __forceinline__ float4 ldbf4(const u16* p) {
    uint2 v = *(const uint2*)p;
    float4 r;
    r.x = bf2f((u16)(v.x & 0xffffu)); r.y = bf2f((u16)(v.x >> 16));
    r.z = bf2f((u16)(v.y & 0xffffu)); r.w = bf2f((u16)(v.y >> 16));
    return r;
}
__device__ __forceinline__ float4 bfu2f4(uint2 v) {
    float4 r;
    r.x = bf2f((u16)(v.x & 0xffffu)); r.y = bf2f((u16)(v.x >> 16));
    r.z = bf2f((u16)(v.y & 0xffffu)); r.w = bf2f((u16)(v.y >> 16));
    return r;
}
__device__ __forceinline__ void stbf4(u16* p, float4 v) {
    uint2 o;
    o.x = (unsigned)f2bf(v.x) | ((unsigned)f2bf(v.y) << 16);
    o.y = (unsigned)f2bf(v.z) | ((unsigned)f2bf(v.w) << 16);
    *(uint2*)p = o;
}
__device__ __forceinline__ void fma4(float4& a, const float4& w, float s) {
    a.x = fmaf(s, w.x, a.x); a.y = fmaf(s, w.y, a.y);
    a.z = fmaf(s, w.z, a.z); a.w = fmaf(s, w.w, a.w);
}
__device__ __forceinline__ void add4(float4& a, float4 b) {
    a.x += b.x; a.y += b.y; a.z += b.z; a.w += b.w;
}

// 8-wide unrolled neighbor gather
__device__ __forceinline__ void gather16(float4& acc, const u16* __restrict__ in,
                                         const u16* __restrict__ csr, int e0s, int e1s,
                                         int l16, int gbase) {
    for (int e0 = e0s; e0 < e1s; e0 += 16) {
        int cnt = min(16, e1s - e0);
        int srcv = (l16 < cnt) ? (int)csr[e0 + l16] : 0;
        int j = 0;
        for (; j + 8 <= cnt; j += 8) {
            int i0 = __shfl(srcv, gbase + j);
            int i1 = __shfl(srcv, gbase + j + 1);
            int i2 = __shfl(srcv, gbase + j + 2);
            int i3 = __shfl(srcv, gbase + j + 3);
            int i4 = __shfl(srcv, gbase + j + 4);
            int i5 = __shfl(srcv, gbase + j + 5);
            int i6 = __shfl(srcv, gbase + j + 6);
            int i7 = __shfl(srcv, gbase + j + 7);
            float4 h0 = ldbf4(in + (size_t)i0 * 64 + l16 * 4);
            float4 h1 = ldbf4(in + (size_t)i1 * 64 + l16 * 4);
            float4 h2 = ldbf4(in + (size_t)i2 * 64 + l16 * 4);
            float4 h3 = ldbf4(in + (size_t)i3 * 64 + l16 * 4);
            float4 h4 = ldbf4(in + (size_t)i4 * 64 + l16 * 4);
            float4 h5 = ldbf4(in + (size_t)i5 * 64 + l16 * 4);
            float4 h6 = ldbf4(in + (size_t)i6 * 64 + l16 * 4);
            float4 h7 = ldbf4(in + (size_t)i7 * 64 + l16 * 4);
            add4(h0, h1); add4(h2, h3); add4(h4, h5); add4(h6, h7);
            add4(h0, h2); add4(h4, h6);
            add4(h0, h4);
            add4(acc, h0);
        }
        for (; j + 4 <= cnt; j += 4) {
            int i0 = __shfl(srcv, gbase + j);
            int i1 = __shfl(srcv, gbase + j + 1);
            int i2 = __shfl(srcv, gbase + j + 2);
            int i3 = __shfl(srcv, gbase + j + 3);
            float4 h0 = ldbf4(in + (size_t)i0 * 64 + l16 * 4);
            float4 h1 = ldbf4(in + (size_t)i1 * 64 + l16 * 4);
            float4 h2 = ldbf4(in + (size_t)i2 * 64 + l16 * 4);
            float4 h3 = ldbf4(in + (size_t)i3 * 64 + l16 * 4);
            add4(h0, h1); add4(h2, h3); add4(h0, h2);
            add4(acc, h0);
        }
        for (; j < cnt; ++j) {
            int s = __shfl(srcv, gbase + j);
            float4 hv = ldbf4(in + (size_t)s * 64 + l16 * 4);
            add4(acc, hv);
        }
    }
}

// ---------------- hist (blocks 0..GE4-1) + segment bounds (blocks GE4..GE4+2) ----------------

__global__ void histseg_k(const int* __restrict__ dst, int* __restrict__ deg,
                          const int* __restrict__ batch, int* __restrict__ segstart) {
    const int b = blockIdx.x, tid = threadIdx.x;
    if (b < GE4) {
        int e = (b * 256 + tid) * 4;
        if (e + 4 <= EE) {
            int4 d = *(const int4*)&dst[e];
            atomicAdd(&deg[d.x], 1); atomicAdd(&deg[d.y], 1);
            atomicAdd(&deg[d.z], 1); atomicAdd(&deg[d.w], 1);
        } else {
            for (; e < EE; ++e) atomicAdd(&deg[dst[e]], 1);
        }
        return;
    }
    int g = (b - GE4) * 256 + tid;
    if (g <= GG) {
        int lo = 0, hi = NN;
        while (lo < hi) {
            int mid = (lo + hi) >> 1;
            if (batch[mid] < g) lo = mid + 1; else hi = mid;
        }
        segstart[g] = lo;
    }
}

// ---------------- per-1024-chunk inclusive scan ----------------

__global__ __launch_bounds__(1024) void scanA_k(const int* __restrict__ deg,
                                                int* __restrict__ rowstart,
                                                int* __restrict__ blocksum) {
    __shared__ int buf[1024];
    int tid = threadIdx.x;
    int base = blockIdx.x * 1024;
    int v = (base + tid < NN) ? deg[base + tid] : 0;
    buf[tid] = v;
    __syncthreads();
    for (int o = 1; o < 1024; o <<= 1) {
        int t = (tid >= o) ? buf[tid - o] : 0;
        __syncthreads();
        buf[tid] += t;
        __syncthreads();
    }
    if (base + tid < NN) rowstart[base + tid + 1] = buf[tid];
    if (tid == 1023) blocksum[blockIdx.x] = buf[1023];
}

// ---------------- scanC with inline chunk-offset reduction (replaces scanB+scanC) ----------------
// block b covers i in [b*256, b*256+256); all share chunk c = b>>2 (256*4 = 1024).
// bofs = sum(blocksum[0..c)) computed by wave 0 via masked reduce.

__global__ void scanC_k(int* __restrict__ rowstart, const int* __restrict__ blocksum,
                        int* __restrict__ cursor) {
    __shared__ int sOfs;
    const int b = blockIdx.x, tid = threadIdx.x;
    const int c = b >> 2;
    if (tid < 64) {
        int v = (tid < c) ? blocksum[tid] : 0;
        v += __shfl_xor(v, 1);  v += __shfl_xor(v, 2);  v += __shfl_xor(v, 4);
        v += __shfl_xor(v, 8);  v += __shfl_xor(v, 16); v += __shfl_xor(v, 32);
        if (tid == 0) sOfs = v;
    }
    __syncthreads();
    int i = b * 256 + tid;
    if (i >= NN) return;
    int val = rowstart[i + 1] + sOfs;
    rowstart[i + 1] = val;
    if (i + 1 < NN) cursor[i + 1] = val;
    if (i == 0) { rowstart[0] = 0; cursor[0] = 0; }
}

// ---------------- fused: CSR fill + x@W1 gemm, INTERLEAVED block mapping ----------------

__global__ __launch_bounds__(256) void fillgemm_k(
    const int* __restrict__ src, const int* __restrict__ dst,
    int* __restrict__ cursor, u16* __restrict__ csr16,
    const float* __restrict__ x, const float* __restrict__ W, u16* __restrict__ out)
{
    __shared__ u16 sW16[128 * 64];
    __shared__ float sIn[16 * 132];
    const int tid = threadIdx.x;
    const int b = blockIdx.x;

    if ((b & 3) == 3 && (b >> 2) < GE4) {
        // ---- fill ----
        int e = ((b >> 2) * 256 + tid) * 4;
        if (e + 4 <= EE) {
            int4 d = *(const int4*)&dst[e];
            int4 s = *(const int4*)&src[e];
            int p0 = atomicAdd(&cursor[d.x], 1);
            int p1 = atomicAdd(&cursor[d.y], 1);
            int p2 = atomicAdd(&cursor[d.z], 1);
            int p3 = atomicAdd(&cursor[d.w], 1);
            csr16[p0] = (u16)s.x; csr16[p1] = (u16)s.y;
            csr16[p2] = (u16)s.z; csr16[p3] = (u16)s.w;
        } else {
            for (; e < EE; ++e) { int p = atomicAdd(&cursor[dst[e]], 1); csr16[p] = (u16)src[e]; }
        }
        return;
    }

    // ---- gemm128 ----
    const int gb = b - min(b >> 2, GE4);
    for (int i = tid * 4; i < 128 * 64; i += 1024) {
        float4 w = *(const float4*)(W + i);
        uint2 pk;
        pk.x = (unsigned)f2bf(w.x) | ((unsigned)f2bf(w.y) << 16);
        pk.y = (unsigned)f2bf(w.z) | ((unsigned)f2bf(w.w) << 16);
        *(uint2*)&sW16[i] = pk;
    }
    const int tile = gb * 16;
    const int nrows = min(16, NN - tile);
    for (int i = tid; i < 16 * 32; i += 256) {
        int rr = i >> 5, kk = (i & 31) * 4;
        float4 t = (rr < nrows) ? *(const float4*)(x + (size_t)(tile + rr) * 128 + kk)
                                : make_float4(0.f, 0.f, 0.f, 0.f);
        *(float4*)&sIn[rr * 132 + kk] = t;
    }
    __syncthreads();
    int rg = tid >> 4, c0 = (tid & 15) << 2;
    float4 acc = make_float4(0.f, 0.f, 0.f, 0.f);
#pragma unroll 4
    for (int k4 = 0; k4 < 32; ++k4) {
        float4 av = *(const float4*)&sIn[rg * 132 + k4 * 4];
        float as[4] = {av.x, av.y, av.z, av.w};
#pragma unroll
        for (int kk = 0; kk < 4; ++kk) {
            uint2 wp = *(const uint2*)&sW16[(k4 * 4 + kk) * 64 + c0];
            fma4(acc, bfu2f4(wp), as[kk]);
        }
    }
    if (rg < nrows) stbf4(out + (size_t)(tile + rg) * 64 + c0, acc);
}

// ---------------- fused gather + W2 GEMM (layer 0 tail), 64-row tiles ----------------

__global__ __launch_bounds__(256) void agg_gemm_k(
    const u16* __restrict__ in,
    const int* __restrict__ rowstart, const u16* __restrict__ csr,
    const float* __restrict__ bias1,
    const float* __restrict__ W2, const float* __restrict__ bias2,
    u16* __restrict__ out, float* __restrict__ gstats)
{
    constexpr int KP = 68;
    __shared__ float sW[64 * 64];
    __shared__ float sIn[64 * KP];
    __shared__ float sStat[128];
    const int tid = threadIdx.x;

    for (int i = tid; i < 64 * 16; i += 256) ((float4*)sW)[i] = ((const float4*)W2)[i];

    const int tile = blockIdx.x * 64;
    const int nrows = min(64, NN - tile);
    const int l16 = tid & 15, gbase = tid & 48, grp = tid >> 4;
    float4 b1v = ((const float4*)bias1)[l16];
    for (int r = grp; r < nrows; r += 16) {
        int node = tile + r;
        float4 acc = ldbf4(in + (size_t)node * 64 + l16 * 4);
        gather16(acc, in, csr, rowstart[node], rowstart[node + 1], l16, gbase);
        acc.x = fmaxf(acc.x + b1v.x, 0.f); acc.y = fmaxf(acc.y + b1v.y, 0.f);
        acc.z = fmaxf(acc.z + b1v.z, 0.f); acc.w = fmaxf(acc.w + b1v.w, 0.f);
        *(float4*)&sIn[r * KP + l16 * 4] = acc;
    }
    __syncthreads();

    const int rg = (tid >> 4) * 4, c0 = (tid & 15) << 2;
    float4 bb = *(const float4*)&bias2[c0];
    float4 acc[4];
#pragma unroll
    for (int j = 0; j < 4; ++j) acc[j] = bb;
#pragma unroll 2
    for (int k4 = 0; k4 < 16; ++k4) {
        float4 av[4];
#pragma unroll
        for (int j = 0; j < 4; ++j) av[j] = *(const float4*)&sIn[(rg + j) * KP + k4 * 4];
        const float* wp = &sW[k4 * 4 * 64 + c0];
        float4 w0 = *(const float4*)(wp);
        float4 w1 = *(const float4*)(wp + 64);
        float4 w2 = *(const float4*)(wp + 128);
        float4 w3 = *(const float4*)(wp + 192);
#pragma unroll
        for (int j = 0; j < 4; ++j) {
            fma4(acc[j], w0, av[j].x); fma4(acc[j], w1, av[j].y);
            fma4(acc[j], w2, av[j].z); fma4(acc[j], w3, av[j].w);
        }
    }
#pragma unroll
    for (int j = 0; j < 4; ++j) {
        acc[j].x = fmaxf(acc[j].x, 0.f); acc[j].y = fmaxf(acc[j].y, 0.f);
        acc[j].z = fmaxf(acc[j].z, 0.f); acc[j].w = fmaxf(acc[j].w, 0.f);
        if (rg + j < nrows) stbf4(out + (size_t)(tile + rg + j) * 64 + c0, acc[j]);
    }
    if (tid < 128) sStat[tid] = 0.f;
    __syncthreads();
    float sx = 0, sy = 0, sz = 0, sw = 0, qx = 0, qy = 0, qz = 0, qw = 0;
#pragma unroll
    for (int j = 0; j < 4; ++j) {
        if (rg + j < nrows) {
            sx += acc[j].x; sy += acc[j].y; sz += acc[j].z; sw += acc[j].w;
            qx += acc[j].x * acc[j].x; qy += acc[j].y * acc[j].y;
            qz += acc[j].z * acc[j].z; qw += acc[j].w * acc[j].w;
        }
    }
    atomicAdd(&sStat[c0 + 0], sx); atomicAdd(&sStat[c0 + 1], sy);
    atomicAdd(&sStat[c0 + 2], sz); atomicAdd(&sStat[c0 + 3], sw);
    atomicAdd(&sStat[64 + c0 + 0], qx); atomicAdd(&sStat[64 + c0 + 1], qy);
    atomicAdd(&sStat[64 + c0 + 2], qz); atomicAdd(&sStat[64 + c0 + 3], qw);
    __syncthreads();
    if (tid < 128) atomicAdd(&gstats[tid], sStat[tid]);
}

// ---------------- fully fused GIN layer (layers 1,2), 64-row tiles ----------------

__global__ __launch_bounds__(256) void fused_layer_k(
    const u16* __restrict__ in,
    const int* __restrict__ rowstart, const u16* __restrict__ csr,
    const float* __restrict__ bnst, const float* __restrict__ gam, const float* __restrict__ bet,
    const float* __restrict__ W1, const float* __restrict__ b1,
    const float* __restrict__ W2, const float* __restrict__ b2,
    u16* __restrict__ out, float* __restrict__ gstats)
{
    constexpr int KP = 68;
    __shared__ float sW[64 * 64];      // W1 then reloaded with W2
    __shared__ float sAgg[64 * KP];
    __shared__ float sStat[128];
    __shared__ float aL[64], dL[64];
    const int tid = threadIdx.x;

    for (int i = tid; i < 64 * 16; i += 256) ((float4*)sW)[i] = ((const float4*)W1)[i];
    if (tid < 64) {
        float m = bnst[tid] * (1.f / NN);
        float v = bnst[64 + tid] * (1.f / NN) - m * m;
        float a = rsqrtf(v + 1e-5f) * gam[tid];
        aL[tid] = a;
        dL[tid] = bet[tid] - m * a;
    }
    __syncthreads();

    const int tile = blockIdx.x * 64;
    const int nrows = min(64, NN - tile);
    const int l16 = tid & 15, gbase = tid & 48, grp = tid >> 4;
    float4 av4 = *(const float4*)&aL[l16 * 4];
    float4 dv4 = *(const float4*)&dL[l16 * 4];
    for (int r = grp; r < nrows; r += 16) {
        int node = tile + r;
        int e0s = rowstart[node], e1s = rowstart[node + 1];
        float4 acc = ldbf4(in + (size_t)node * 64 + l16 * 4);
        gather16(acc, in, csr, e0s, e1s, l16, gbase);
        float dp1 = (float)(e1s - e0s + 1);
        acc.x = fmaf(av4.x, acc.x, dp1 * dv4.x);
        acc.y = fmaf(av4.y, acc.y, dp1 * dv4.y);
        acc.z = fmaf(av4.z, acc.z, dp1 * dv4.z);
        acc.w = fmaf(av4.w, acc.w, dp1 * dv4.w);
        *(float4*)&sAgg[r * KP + l16 * 4] = acc;
    }
    __syncthreads();

    const int rg = (tid >> 4) * 4, c0 = (tid & 15) << 2;
    float4 t[4];
    {
        float4 bb = *(const float4*)&b1[c0];
#pragma unroll
        for (int j = 0; j < 4; ++j) t[j] = bb;
#pragma unroll 2
        for (int k4 = 0; k4 < 16; ++k4) {
            float4 a0[4];
#pragma unroll
            for (int j = 0; j < 4; ++j) a0[j] = *(const float4*)&sAgg[(rg + j) * KP + k4 * 4];
            const float* wp = &sW[k4 * 4 * 64 + c0];
            float4 w0 = *(const float4*)(wp);
            float4 w1 = *(const float4*)(wp + 64);
            float4 w2 = *(const float4*)(wp + 128);
            float4 w3 = *(const float4*)(wp + 192);
#pragma unroll
            for (int j = 0; j < 4; ++j) {
                fma4(t[j], w0, a0[j].x); fma4(t[j], w1, a0[j].y);
                fma4(t[j], w2, a0[j].z); fma4(t[j], w3, a0[j].w);
            }
        }
#pragma unroll
        for (int j = 0; j < 4; ++j) {
            t[j].x = fmaxf(t[j].x, 0.f); t[j].y = fmaxf(t[j].y, 0.f);
            t[j].z = fmaxf(t[j].z, 0.f); t[j].w = fmaxf(t[j].w, 0.f);
        }
    }
    __syncthreads();

    for (int i = tid; i < 64 * 16; i += 256) ((float4*)sW)[i] = ((const float4*)W2)[i];
#pragma unroll
    for (int j = 0; j < 4; ++j) *(float4*)&sAgg[(rg + j) * KP + c0] = t[j];
    __syncthreads();

    float4 acc[4];
    {
        float4 bb = *(const float4*)&b2[c0];
#pragma unroll
        for (int j = 0; j < 4; ++j) acc[j] = bb;
#pragma unroll 2
        for (int k4 = 0; k4 < 16; ++k4) {
            float4 a0[4];
#pragma unroll
            for (int j = 0; j < 4; ++j) a0[j] = *(const float4*)&sAgg[(rg + j) * KP + k4 * 4];
            const float* wp = &sW[k4 * 4 * 64 + c0];
            float4 w0 = *(const float4*)(wp);
            float4 w1 = *(const float4*)(wp + 64);
            float4 w2 = *(const float4*)(wp + 128);
            float4 w3 = *(const float4*)(wp + 192);
#pragma unroll
            for (int j = 0; j < 4; ++j) {
                fma4(acc[j], w0, a0[j].x); fma4(acc[j], w1, a0[j].y);
                fma4(acc[j], w2, a0[j].z); fma4(acc[j], w3, a0[j].w);
            }
        }
    }
#pragma unroll
    for (int j = 0; j < 4; ++j) {
        acc[j].x = fmaxf(acc[j].x, 0.f); acc[j].y = fmaxf(acc[j].y, 0.f);
        acc[j].z = fmaxf(acc[j].z, 0.f); acc[j].w = fmaxf(acc[j].w, 0.f);
        if (rg + j < nrows) stbf4(out + (size_t)(tile + rg + j) * 64 + c0, acc[j]);
    }
    if (tid < 128) sStat[tid] = 0.f;
    __syncthreads();
    float sx = 0, sy = 0, sz = 0, sw = 0, qx = 0, qy = 0, qz = 0, qw = 0;
#pragma unroll
    for (int j = 0; j < 4; ++j) {
        if (rg + j < nrows) {
            sx += acc[j].x; sy += acc[j].y; sz += acc[j].z; sw += acc[j].w;
            qx += acc[j].x * acc[j].x; qy += acc[j].y * acc[j].y;
            qz += acc[j].z * acc[j].z; qw += acc[j].w * acc[j].w;
        }
    }
    atomicAdd(&sStat[c0 + 0], sx); atomicAdd(&sStat[c0 + 1], sy);
    atomicAdd(&sStat[c0 + 2], sz); atomicAdd(&sStat[c0 + 3], sw);
    atomicAdd(&sStat[64 + c0 + 0], qx); atomicAdd(&sStat[64 + c0 + 1], qy);
    atomicAdd(&sStat[64 + c0 + 2], qz); atomicAdd(&sStat[64 + c0 + 3], qw);
    __syncthreads();
    if (tid < 128) atomicAdd(&gstats[tid], sStat[tid]);
}

// ---------------- generic 64-K GEMM tile body (dynamic LDS) ----------------

template<bool STATS, bool ROWSCALE, bool BNIN, bool INBF, bool OUTBF>
__device__ void gemm_dev(char* smem, int tile, int rows,
    const void* __restrict__ in, const float* __restrict__ W, const float* __restrict__ Wb,
    const float* __restrict__ bias, const float* __restrict__ bias2,
    void* __restrict__ out, void* __restrict__ out2,
    float* __restrict__ gstats, float* __restrict__ gstats2,
    const float* __restrict__ attn, const float* __restrict__ noise,
    const float* __restrict__ bnstats, const float* __restrict__ gamma,
    const float* __restrict__ beta)
{
    constexpr int KP = 68;
    float* sW    = (float*)smem;          // 64*64
    float* sWb   = sW + 64 * 64;          // 64*64
    float* sIn   = sWb + 64 * 64;         // 64*KP
    float* sStat = sIn + 64 * KP;         // 256
    float* sA    = sStat + 256;           // 64
    float* sD    = sA + 64;               // 64
    const int tid = threadIdx.x;

    for (int i = tid; i < 64 * 16; i += 256) {
        ((float4*)sW)[i]  = ((const float4*)W)[i];
        ((float4*)sWb)[i] = ((const float4*)Wb)[i];
    }
    if (BNIN && tid < 64) {
        float m = bnstats[tid] * (1.f / NN);
        float v = bnstats[64 + tid] * (1.f / NN) - m * m;
        float a = rsqrtf(v + 1e-5f) * gamma[tid];
        sA[tid] = a;
        sD[tid] = beta[tid] - m * a;
    }
    __syncthreads();

    int nrows = min(64, rows - tile);
    const float4* igf = INBF ? nullptr : (const float4*)((const float*)in + (size_t)tile * 64);
    const u16*    igb = INBF ? ((const u16*)in + (size_t)tile * 64) : nullptr;
    const float4* ng  = ROWSCALE ? (const float4*)(noise + (size_t)tile * 64) : nullptr;
    for (int i = tid; i < nrows * 16; i += 256) {
        int rr = i >> 4, kk = (i & 15) * 4;
        float4 t = INBF ? ldbf4(igb + i * 4) : igf[i];
        if (BNIN) {
            t.x = fmaf(sA[kk + 0], t.x, sD[kk + 0]);
            t.y = fmaf(sA[kk + 1], t.y, sD[kk + 1]);
            t.z = fmaf(sA[kk + 2], t.z, sD[kk + 2]);
            t.w = fmaf(sA[kk + 3], t.w, sD[kk + 3]);
        }
        if (ROWSCALE) {
            float4 nv = ng[i];
            float at = attn[tile + rr];
            t.x = fmaf(at, t.x, nv.x); t.y = fmaf(at, t.y, nv.y);
            t.z = fmaf(at, t.z, nv.z); t.w = fmaf(at, t.w, nv.w);
        }
        *(float4*)&sIn[rr * KP + kk] = t;
    }
    __syncthreads();

    const int rg = (tid >> 4) * 4, c0 = (tid & 15) << 2;
    float4 bb  = *(const float4*)&bias[c0];
    float4 bb2 = *(const float4*)&bias2[c0];
    float4 acc[4], acc2[4];
#pragma unroll
    for (int j = 0; j < 4; ++j) { acc[j] = bb; acc2[j] = bb2; }
#pragma unroll 2
    for (int k4 = 0; k4 < 16; ++k4) {
        float4 av[4];
#pragma unroll
        for (int j = 0; j < 4; ++j)
            av[j] = *(const float4*)&sIn[(rg + j) * KP + k4 * 4];
        const float* wp = &sW[k4 * 4 * 64 + c0];
        float4 w0 = *(const float4*)(wp);
        float4 w1 = *(const float4*)(wp + 64);
        float4 w2 = *(const float4*)(wp + 128);
        float4 w3 = *(const float4*)(wp + 192);
#pragma unroll
        for (int j = 0; j < 4; ++j) {
            fma4(acc[j], w0, av[j].x); fma4(acc[j], w1, av[j].y);
            fma4(acc[j], w2, av[j].z); fma4(acc[j], w3, av[j].w);
        }
        const float* wq = &sWb[k4 * 4 * 64 + c0];
        float4 u0 = *(const float4*)(wq);
        float4 u1 = *(const float4*)(wq + 64);
        float4 u2 = *(const float4*)(wq + 128);
        float4 u3 = *(const float4*)(wq + 192);
#pragma unroll
        for (int j = 0; j < 4; ++j) {
            fma4(acc2[j], u0, av[j].x); fma4(acc2[j], u1, av[j].y);
            fma4(acc2[j], u2, av[j].z); fma4(acc2[j], u3, av[j].w);
        }
    }
#pragma unroll
    for (int j = 0; j < 4; ++j) {
        acc[j].x = fmaxf(acc[j].x, 0.f);   acc[j].y = fmaxf(acc[j].y, 0.f);
        acc[j].z = fmaxf(acc[j].z, 0.f);   acc[j].w = fmaxf(acc[j].w, 0.f);
        acc2[j].x = fmaxf(acc2[j].x, 0.f); acc2[j].y = fmaxf(acc2[j].y, 0.f);
        acc2[j].z = fmaxf(acc2[j].z, 0.f); acc2[j].w = fmaxf(acc2[j].w, 0.f);
        int r = rg + j;
        if (r < nrows) {
            if (OUTBF) {
                stbf4((u16*)out  + (size_t)(tile + r) * 64 + c0, acc[j]);
                stbf4((u16*)out2 + (size_t)(tile + r) * 64 + c0, acc2[j]);
            } else {
                *(float4*)((float*)out  + (size_t)(tile + r) * 64 + c0) = acc[j];
                *(float4*)((float*)out2 + (size_t)(tile + r) * 64 + c0) = acc2[j];
            }
        }
    }
    if (STATS) {
        if (tid < 256) sStat[tid] = 0.f;
        __syncthreads();
        float sx = 0, sy = 0, sz = 0, sw = 0, qx = 0, qy = 0, qz = 0, qw = 0;
        float sx2 = 0, sy2 = 0, sz2 = 0, sw2 = 0, qx2 = 0, qy2 = 0, qz2 = 0, qw2 = 0;
#pragma unroll
        for (int j = 0; j < 4; ++j) {
            if (rg + j < nrows) {
                sx += acc[j].x; sy += acc[j].y; sz += acc[j].z; sw += acc[j].w;
                qx += acc[j].x * acc[j].x; qy += acc[j].y * acc[j].y;
                qz += acc[j].z * acc[j].z; qw += acc[j].w * acc[j].w;
                sx2 += acc2[j].x; sy2 += acc2[j].y; sz2 += acc2[j].z; sw2 += acc2[j].w;
                qx2 += acc2[j].x * acc2[j].x; qy2 += acc2[j].y * acc2[j].y;
                qz2 += acc2[j].z * acc2[j].z; qw2 += acc2[j].w * acc2[j].w;
            }
        }
        atomicAdd(&sStat[c0 + 0], sx); atomicAdd(&sStat[c0 + 1], sy);
        atomicAdd(&sStat[c0 + 2], sz); atomicAdd(&sStat[c0 + 3], sw);
        atomicAdd(&sStat[64 + c0 + 0], qx); atomicAdd(&sStat[64 + c0 + 1], qy);
        atomicAdd(&sStat[64 + c0 + 2], qz); atomicAdd(&sStat[64 + c0 + 3], qw);
        atomicAdd(&sStat[128 + c0 + 0], sx2); atomicAdd(&sStat[128 + c0 + 1], sy2);
        atomicAdd(&sStat[128 + c0 + 2], sz2); atomicAdd(&sStat[128 + c0 + 3], sw2);
        atomicAdd(&sStat[192 + c0 + 0], qx2); atomicAdd(&sStat[192 + c0 + 1], qy2);
        atomicAdd(&sStat[192 + c0 + 2], qz2); atomicAdd(&sStat[192 + c0 + 3], qw2);
        __syncthreads();
        if (tid < 128) atomicAdd(&gstats[tid], sStat[tid]);
        else atomicAdd(&gstats2[tid - 128], sStat[tid]);
    }
}

// ---------------- heads: node DUAL gemm + graph DUAL gemm, one launch ----------------

__global__ __launch_bounds__(256) void heads_k(
    const u16* __restrict__ z2, const float* __restrict__ attn, const float* __restrict__ noise,
    const float* __restrict__ s2, const float* __restrict__ bng2, const float* __restrict__ bnb2,
    const float* __restrict__ nmW, const float* __restrict__ nmb,
    const float* __restrict__ nlW, const float* __restrict__ nlb,
    u16* __restrict__ nmu_b, u16* __restrict__ nlv_b,
    float* __restrict__ s3, float* __restrict__ s4,
    const float* __restrict__ slots,
    const float* __restrict__ gmW, const float* __restrict__ gmb,
    const float* __restrict__ glW, const float* __restrict__ glb,
    float* __restrict__ gpre1, float* __restrict__ gpre2,
    float* __restrict__ s5, float* __restrict__ s6)
{
    extern __shared__ char smem[];
    if (blockIdx.x < NT64) {
        gemm_dev<true, true, true, true, true>(smem, blockIdx.x * 64, NN,
            z2, nmW, nlW, nmb, nlb, nmu_b, nlv_b, s3, s4, attn, noise, s2, bng2, bnb2);
    } else {
        gemm_dev<true, false, false, false, false>(smem, (int)(blockIdx.x - NT64) * 64, GG,
            slots, gmW, glW, gmb, glb, gpre1, gpre2, s5, s6,
            nullptr, nullptr, nullptr, nullptr, nullptr);
    }
}

// ---------------- merged BN apply: node pair (bf16 in) + graph pair (fp32 in) ----------------

__global__ void bn_all_k(const u16* __restrict__ n1, const u16* __restrict__ n2,
                         const float* __restrict__ g1in, const float* __restrict__ g2in,
                         float* __restrict__ o1, float* __restrict__ o2,
                         float* __restrict__ o3, float* __restrict__ o4,
                         const float* __restrict__ st3, const float* __restrict__ st4,
                         const float* __restrict__ st5, const float* __restrict__ st6,
                         const float* __restrict__ pj_g, const float* __restrict__ pj_b) {
    int total = NN * 64 + GG * 64;
    for (int i = blockIdx.x * blockDim.x + threadIdx.x; i < total; i += gridDim.x * blockDim.x) {
        if (i < NN * 64) {
            int c = i & 63;
            float m1 = st3[c] * (1.f / NN);
            float v1 = st3[64 + c] * (1.f / NN) - m1 * m1;
            o1[i] = (bf2f(n1[i]) - m1) * rsqrtf(v1 + 1e-5f) * pj_g[c] + pj_b[c];
            float m2 = st4[c] * (1.f / NN);
            float v2 = st4[64 + c] * (1.f / NN) - m2 * m2;
            o2[i] = (bf2f(n2[i]) - m2) * rsqrtf(v2 + 1e-5f) * pj_g[64 + c] + pj_b[64 + c];
        } else {
            int j = i - NN * 64;
            int c = j & 63;
            float m1 = st5[c] * (1.f / GG);
            float v1 = st5[64 + c] * (1.f / GG) - m1 * m1;
            o3[j] = (g1in[j] - m1) * rsqrtf(v1 + 1e-5f) * pj_g[128 + c] + pj_b[128 + c];
            float m2 = st6[c] * (1.f / GG);
            float v2 = st6[64 + c] * (1.f / GG) - m2 * m2;
            o4[j] = (g2in[j] - m2) * rsqrtf(v2 + 1e-5f) * pj_g[192 + c] + pj_b[192 + c];
        }
    }
}

// ---------------- attention on z (bf16) directly; 512 threads, 8 scan groups ----------------

__global__ __launch_bounds__(512) void attn3_k(
    const u16* __restrict__ z, const int* __restrict__ segst,
    const float* __restrict__ bnst, const float* __restrict__ gam, const float* __restrict__ bet,
    const float* __restrict__ Wq, const float* __restrict__ Wk, const float* __restrict__ Wv,
    const float* __restrict__ Wih, const float* __restrict__ Whh,
    const float* __restrict__ bih, const float* __restrict__ bhh,
    float* __restrict__ attn, float* __restrict__ slots_out)
{
    int g = blockIdx.x, tid = threadIdx.x, w = tid >> 6, lane = tid & 63;
    __shared__ float ssl[64], sq[64], swr[64], sm[64], supd[64], sred[512], ssum[8];
    __shared__ float aL[64], dL[64];
    __shared__ float sgi[192], sgh[192];
    __shared__ float sc, sinv;

    int s0 = segst[g], s1 = segst[g + 1];
    if (tid < 64) {
        float m = bnst[tid] * (1.f / NN);
        float v = bnst[64 + tid] * (1.f / NN) - m * m;
        float a = rsqrtf(v + 1e-5f) * gam[tid];
        aL[tid] = a;
        dL[tid] = bet[tid] - m * a;
    }
    __syncthreads();

    {
        float macc = 0.f;
        for (int n = s0 + w; n < s1; n += 8) macc += bf2f(z[(size_t)n * 64 + lane]);
        sred[tid] = macc;
        __syncthreads();
        if (tid < 64) {
            float s = 0.f;
#pragma unroll
            for (int k = 0; k < 8; ++k) s += sred[tid + 64 * k];
            ssl[tid] = fmaf(aL[tid], s / (float)max(s1 - s0, 1), dL[tid]);
        }
        __syncthreads();
    }

    for (int it = 0; it < 2; ++it) {
        {
            float p = 0.f;
#pragma unroll
            for (int kk = 0; kk < 8; ++kk) p += ssl[w * 8 + kk] * Wq[(w * 8 + kk) * 64 + lane];
            sred[tid] = p;
        }
        __syncthreads();
        if (tid < 64) {
            float s = 0.f;
#pragma unroll
            for (int k = 0; k < 8; ++k) s += sred[tid + 64 * k];
            sq[tid] = s;
        }
        __syncthreads();
        {
            float p = 0.f;
#pragma unroll
            for (int kk = 0; kk < 8; ++kk) p += Wk[lane * 64 + w * 8 + kk] * sq[w * 8 + kk];
            sred[tid] = p;
        }
        __syncthreads();
        if (tid < 64) {
            float s = 0.f;
#pragma unroll
            for (int k = 0; k < 8; ++k) s += sred[tid + 64 * k];
            swr[tid] = s;
        }
        __syncthreads();
        if (tid < 64) {
            float pr = dL[tid] * swr[tid];
            pr += __shfl_xor(pr, 1);  pr += __shfl_xor(pr, 2);  pr += __shfl_xor(pr, 4);
            pr += __shfl_xor(pr, 8);  pr += __shfl_xor(pr, 16); pr += __shfl_xor(pr, 32);
            if (tid == 0) sc = pr * 0.125f;
            swr[tid] = aL[tid] * swr[tid] * 0.125f;
        }
        __syncthreads();
        float wl = swr[lane], cc = sc;

        float s = 0.f, u = 0.f;
        for (int n = s0 + w; n < s1; n += 8) {
            float zl = bf2f(z[(size_t)n * 64 + lane]);
            float l = zl * wl;
            l += __shfl_xor(l, 1);  l += __shfl_xor(l, 2);  l += __shfl_xor(l, 4);
            l += __shfl_xor(l, 8);  l += __shfl_xor(l, 16); l += __shfl_xor(l, 32);
            float e = expf(l + cc);
            if (lane == 0) attn[n] = e;
            s += e;
            u = fmaf(e, zl, u);
        }
        sred[tid] = u;
        if (lane == 0) ssum[w] = s;
        __syncthreads();
        if (tid < 64) {
            float stot = ssum[0] + ssum[1] + ssum[2] + ssum[3]
                       + ssum[4] + ssum[5] + ssum[6] + ssum[7] + 1e-9f;
            if (tid == 0) sinv = 1.f / stot;
            float uu = 0.f;
#pragma unroll
            for (int k = 0; k < 8; ++k) uu += sred[tid + 64 * k];
            sm[tid] = fmaf(aL[tid], uu / stot, dL[tid]);
        }
        __syncthreads();
        {
            float p = 0.f;
#pragma unroll
            for (int kk = 0; kk < 8; ++kk) p += sm[w * 8 + kk] * Wv[(w * 8 + kk) * 64 + lane];
            sred[tid] = p;
        }
        __syncthreads();
        if (tid < 64) {
            float s2 = 0.f;
#pragma unroll
            for (int k = 0; k < 8; ++k) s2 += sred[tid + 64 * k];
            supd[tid] = s2;
        }
        __syncthreads();

        if (it == 1) {
            float inv = sinv;
            for (int n = s0 + tid; n < s1; n += 512) attn[n] *= inv;
        }

        if (tid < 192) {
            float a = bih[tid], b = bhh[tid];
            const float* wi = &Wih[tid * 64];
            const float* wh = &Whh[tid * 64];
#pragma unroll 8
            for (int j = 0; j < 64; ++j) { a += supd[j] * wi[j]; b += ssl[j] * wh[j]; }
            sgi[tid] = a; sgh[tid] = b;
        }
        __syncthreads();
        if (tid < 64) {
            float r  = 1.f / (1.f + expf(-(sgi[tid] + sgh[tid])));
            float zz = 1.f / (1.f + expf(-(sgi[64 + tid] + sgh[64 + tid])));
            float nn = tanhf(sgi[128 + tid] + r * sgh[128 + tid]);
            float ns = (1.f - zz) * nn + zz * ssl[tid];
            ssl[tid] = ns;
            if (it == 1) slots_out[g * 64 + tid] = ns;
        }
        __syncthreads();
    }
}

// ---------------- host side ----------------

extern "C" void kernel_launch(void* const* d_in, const int* in_sizes, int n_in,
                              void* d_out, int out_size, void* d_ws, size_t ws_size,
                              hipStream_t stream) {
    (void)in_sizes; (void)n_in; (void)out_size; (void)ws_size;

    const float* x      = (const float*)d_in[0];
    const int*   ei     = (const int*)d_in[1];
    const int*   srcI   = ei;
    const int*   dstI   = ei + EE;
    const int*   batch  = (const int*)d_in[2];
    const float* noise  = (const float*)d_in[3];
    const float* W1_0   = (const float*)d_in[4];
    const float* b1_0   = (const float*)d_in[5];
    const float* W2_0   = (const float*)d_in[6];
    const float* b2_0   = (const float*)d_in[7];
    const float* W1_r   = (const float*)d_in[8];
    const float* b1_r   = (const float*)d_in[9];
    const float* W2_r   = (const float*)d_in[10];
    const float* b2_r   = (const float*)d_in[11];
    const float* bn_g   = (const float*)d_in[12];
    const float* bn_b   = (const float*)d_in[13];
    const float* Wq     = (const float*)d_in[14];
    const float* Wk     = (const float*)d_in[15];
    const float* Wv     = (const float*)d_in[16];
    const float* Wih    = (const float*)d_in[17];
    const float* Whh    = (const float*)d_in[18];
    const float* bih    = (const float*)d_in[19];
    const float* bhh    = (const float*)d_in[20];
    const float* nmW    = (const float*)d_in[21];
    const float* nmb    = (const float*)d_in[22];
    const float* nlW    = (const float*)d_in[23];
    const float* nlb    = (const float*)d_in[24];
    const float* gmW    = (const float*)d_in[25];
    const float* gmb    = (const float*)d_in[26];
    const float* glW    = (const float*)d_in[27];
    const float* glb    = (const float*)d_in[28];
    const float* pj_g   = (const float*)d_in[29];
    const float* pj_b   = (const float*)d_in[30];

    char* w = (char*)d_ws;
    u16*   B0b   = (u16*)w;            w += (size_t)NN * 64 * 2;
    u16*   B1b   = (u16*)w;            w += (size_t)NN * 64 * 2;
    u16*   B2b   = (u16*)w;            w += (size_t)NN * 64 * 2;
    float* slots = (float*)w;          w += GG * 64 * 4;
    float* gpre1 = (float*)w;          w += GG * 64 * 4;
    float* gpre2 = (float*)w;          w += GG * 64 * 4;
    float* attn  = (float*)w;          w += NN * 4;
    int*   cursor= (int*)w;            w += NN * 4;          // cursor + stats adjacent: one memset
    float* stats = (float*)w;          w += 7 * 128 * 4;
    int*   segst = (int*)w;            w += (GG + 1) * 4;
    int*   rowst = (int*)w;            w += (NN + 1) * 4;
    int*   bsum  = (int*)w;            w += 64 * 4;
    u16*   csr16 = (u16*)w;            w += (size_t)EE * 2;

    float* s0 = stats, *s1 = stats + 128, *s2 = stats + 256, *s3 = stats + 384,
         * s4 = stats + 512, *s5 = stats + 640, *s6 = stats + 768;

    float* outp = (float*)d_out;
    float* out_nmu = outp;
    float* out_nlv = outp + NN * DD;
    float* out_gmu = outp + 2 * NN * DD;
    float* out_glv = outp + 2 * NN * DD + GG * DD;

    constexpr int NB = (NN + 1023) / 1024;       // 49 scan chunks
    constexpr int NCB = (NN + 255) / 256;        // 196 scanC blocks
    constexpr size_t HEAD_SMEM = (64 * 64 * 2 + 64 * 68 + 256 + 128) * sizeof(float);

#define GK(...) <<<__VA_ARGS__>>>
    // ---------- init (memset) + hist/segbounds + prefix ----------
    hipMemsetAsync(cursor, 0, (size_t)NN * 4 + 7 * 128 * 4, stream);
    histseg_k GK(GE4 + 3, 256, 0, stream)(dstI, cursor, batch, segst);
    scanA_k GK(NB, 1024, 0, stream)(cursor, rowst, bsum);
    scanC_k GK(NCB, 256, 0, stream)(rowst, bsum, cursor);

    // ---------- fused: CSR fill + x@W1 GEMM (interleaved co-run) ----------
    fillgemm_k GK(GE4 + NT16, 256, 0, stream)(srcI, dstI, cursor, csr16, x, W1_0, B0b);

    // ---------- GIN layer 0 tail: fused gather+W2 ----------
    agg_gemm_k GK(NT64, 256, 0, stream)(B0b, rowst, csr16, b1_0, W2_0, b2_0, B1b, s0);

    // ---------- GIN layers 1,2 ----------
    fused_layer_k GK(NT64, 256, 0, stream)(B1b, rowst, csr16, s0, bn_g + 0, bn_b + 0,
                                           W1_r, b1_r, W2_r, b2_r, B2b, s1);
    fused_layer_k GK(NT64, 256, 0, stream)(B2b, rowst, csr16, s1, bn_g + 64, bn_b + 64,
                                           W1_r + DD * DD, b1_r + DD, W2_r + DD * DD, b2_r + DD,
                                           B0b, s2);
    // B0b = z2 (pre-BN, relu'd, bf16)

    // ---------- summary maker ----------
    attn3_k GK(GG, 512, 0, stream)(B0b, segst, s2, bn_g + 128, bn_b + 128,
                                   Wq, Wk, Wv, Wih, Whh, bih, bhh, attn, slots);

    // ---------- heads ----------
    heads_k GK(NT64 + 8, 256, HEAD_SMEM, stream)(
        B0b, attn, noise, s2, bn_g + 128, bn_b + 128,
        nmW, nmb, nlW, nlb, B1b, B2b, s3, s4,
        slots, gmW, gmb, glW, glb, gpre1, gpre2, s5, s6);

    // ---------- merged final BN ----------
    bn_all_k GK(2048, 256, 0, stream)(B1b, B2b, gpre1, gpre2,
                                      out_nmu, out_nlv, out_gmu, out_glv,
                                      s3, s4, s5, s6, pj_g, pj_b);
#undef GK
}

// Round 22
// 350.254 us; speedup vs baseline: 1.0992x; 1.0061x over previous
//
#include <hip/hip_runtime.h>

#define NN 50000
#define EE 800000
#define FF 128
#define DD 64
#define GG 512

typedef unsigned short u16;

#define GE4 782     // fill/hist blocks (4 edges/thread)
#define NT16 3125   // gemm128 16-row tiles total
#define NT64 782    // 64-row node tiles

// histgemm: hist(782) + seg(3) + gemm tiles [0,1564)
#define HG_BODY 2346          // 782*3: period-3 mapping (2 gemm : 1 hist)
#define HG_NBLK (HG_BODY + 3)
// fillgemm: fill(782) + gemm tiles [1564,3125)
#define FG_BODY 2343          // 781*3
#define FG_NBLK (FG_BODY + 1) // +1: fill block 781

// ---------------- bf16 storage helpers (compute stays fp32) ----------------

__device__ __forceinline__ float bf2f(u16 h) {
    unsigned u = ((unsigned)h) << 16;
    return __builtin_bit_cast(float, u);
}
__device__ __forceinline__ u16 f2bf(float f) {
    unsigned u = __builtin_bit_cast(unsigned, f);
    u += 0x7fffu + ((u >> 16) & 1u);   // RNE
    return (u16)(u >> 16);
}
__device__ __forceinline__ float4 ldbf4(const u16* p) {
    uint2 v = *(const uint2*)p;
    float4 r;
    r.x = bf2f((u16)(v.x & 0xffffu)); r.y = bf2f((u16)(v.x >> 16));
    r.z = bf2f((u16)(v.y & 0xffffu)); r.w = bf2f((u16)(v.y >> 16));
    return r;
}
__device__ __forceinline__ float4 bfu2f4(uint2 v) {
    float4 r;
    r.x = bf2f((u16)(v.x & 0xffffu)); r.y = bf2f((u16)(v.x >> 16));
    r.z = bf2f((u16)(v.y & 0xffffu)); r.w = bf2f((u16)(v.y >> 16));
    return r;
}
__device__ __forceinline__ void stbf4(u16* p, float4 v) {
    uint2 o;
    o.x = (unsigned)f2bf(v.x) | ((unsigned)f2bf(v.y) << 16);
    o.y = (unsigned)f2bf(v.z) | ((unsigned)f2bf(v.w) << 16);
    *(uint2*)p = o;
}
__device__ __forceinline__ void fma4(float4& a, const float4& w, float s) {
    a.x = fmaf(s, w.x, a.x); a.y = fmaf(s, w.y, a.y);
    a.z = fmaf(s, w.z, a.z); a.w = fmaf(s, w.w, a.w);
}
__device__ __forceinline__ void add4(float4& a, float4 b) {
    a.x += b.x; a.y += b.y; a.z += b.z; a.w += b.w;
}

// 8-wide unrolled neighbor gather
__device__ __forceinline__ void gather16(float4& acc, const u16* __restrict__ in,
                                         const u16* __restrict__ csr, int e0s, int e1s,
                                         int l16, int gbase) {
    for (int e0 = e0s; e0 < e1s; e0 += 16) {
        int cnt = min(16, e1s - e0);
        int srcv = (l16 < cnt) ? (int)csr[e0 + l16] : 0;
        int j = 0;
        for (; j + 8 <= cnt; j += 8) {
            int i0 = __shfl(srcv, gbase + j);
            int i1 = __shfl(srcv, gbase + j + 1);
            int i2 = __shfl(srcv, gbase + j + 2);
            int i3 = __shfl(srcv, gbase + j + 3);
            int i4 = __shfl(srcv, gbase + j + 4);
            int i5 = __shfl(srcv, gbase + j + 5);
            int i6 = __shfl(srcv, gbase + j + 6);
            int i7 = __shfl(srcv, gbase + j + 7);
            float4 h0 = ldbf4(in + (size_t)i0 * 64 + l16 * 4);
            float4 h1 = ldbf4(in + (size_t)i1 * 64 + l16 * 4);
            float4 h2 = ldbf4(in + (size_t)i2 * 64 + l16 * 4);
            float4 h3 = ldbf4(in + (size_t)i3 * 64 + l16 * 4);
            float4 h4 = ldbf4(in + (size_t)i4 * 64 + l16 * 4);
            float4 h5 = ldbf4(in + (size_t)i5 * 64 + l16 * 4);
            float4 h6 = ldbf4(in + (size_t)i6 * 64 + l16 * 4);
            float4 h7 = ldbf4(in + (size_t)i7 * 64 + l16 * 4);
            add4(h0, h1); add4(h2, h3); add4(h4, h5); add4(h6, h7);
            add4(h0, h2); add4(h4, h6);
            add4(h0, h4);
            add4(acc, h0);
        }
        for (; j + 4 <= cnt; j += 4) {
            int i0 = __shfl(srcv, gbase + j);
            int i1 = __shfl(srcv, gbase + j + 1);
            int i2 = __shfl(srcv, gbase + j + 2);
            int i3 = __shfl(srcv, gbase + j + 3);
            float4 h0 = ldbf4(in + (size_t)i0 * 64 + l16 * 4);
            float4 h1 = ldbf4(in + (size_t)i1 * 64 + l16 * 4);
            float4 h2 = ldbf4(in + (size_t)i2 * 64 + l16 * 4);
            float4 h3 = ldbf4(in + (size_t)i3 * 64 + l16 * 4);
            add4(h0, h1); add4(h2, h3); add4(h0, h2);
            add4(acc, h0);
        }
        for (; j < cnt; ++j) {
            int s = __shfl(srcv, gbase + j);
            float4 hv = ldbf4(in + (size_t)s * 64 + l16 * 4);
            add4(acc, hv);
        }
    }
}

// ---------------- gemm128 tile body (x[16x128] @ W1 -> bf16 out) ----------------

__device__ __forceinline__ void gemm128_tile(int gb, const float* __restrict__ x,
                                             const float* __restrict__ W,
                                             u16* __restrict__ out,
                                             u16* sW16, float* sIn) {
    const int tid = threadIdx.x;
    for (int i = tid * 4; i < 128 * 64; i += 1024) {
        float4 w = *(const float4*)(W + i);
        uint2 pk;
        pk.x = (unsigned)f2bf(w.x) | ((unsigned)f2bf(w.y) << 16);
        pk.y = (unsigned)f2bf(w.z) | ((unsigned)f2bf(w.w) << 16);
        *(uint2*)&sW16[i] = pk;
    }
    const int tile = gb * 16;
    const int nrows = min(16, NN - tile);
    if (nrows <= 0) { return; }
    for (int i = tid; i < 16 * 32; i += 256) {
        int rr = i >> 5, kk = (i & 31) * 4;
        float4 t = (rr < nrows) ? *(const float4*)(x + (size_t)(tile + rr) * 128 + kk)
                                : make_float4(0.f, 0.f, 0.f, 0.f);
        *(float4*)&sIn[rr * 132 + kk] = t;
    }
    __syncthreads();
    int rg = tid >> 4, c0 = (tid & 15) << 2;
    float4 acc = make_float4(0.f, 0.f, 0.f, 0.f);
#pragma unroll 4
    for (int k4 = 0; k4 < 32; ++k4) {
        float4 av = *(const float4*)&sIn[rg * 132 + k4 * 4];
        float as[4] = {av.x, av.y, av.z, av.w};
#pragma unroll
        for (int kk = 0; kk < 4; ++kk) {
            uint2 wp = *(const uint2*)&sW16[(k4 * 4 + kk) * 64 + c0];
            fma4(acc, bfu2f4(wp), as[kk]);
        }
    }
    if (rg < nrows) stbf4(out + (size_t)(tile + rg) * 64 + c0, acc);
}

// ---------------- fused: hist + seg-bounds + gemm128 tiles [0,1564) ----------------
// period-3 mapping: b<HG_BODY: r=b%3, g=b/3; r==2 -> hist g; else gemm tile g*2+r.
// b in [HG_BODY, HG_BODY+3): segment-bound blocks.

__global__ __launch_bounds__(256) void histgemm_k(
    const int* __restrict__ dst, int* __restrict__ deg,
    const int* __restrict__ batch, int* __restrict__ segstart,
    const float* __restrict__ x, const float* __restrict__ W, u16* __restrict__ out)
{
    __shared__ u16 sW16[128 * 64];
    __shared__ float sIn[16 * 132];
    const int b = blockIdx.x, tid = threadIdx.x;

    if (b >= HG_BODY) {
        int g = (b - HG_BODY) * 256 + tid;
        if (g <= GG) {
            int lo = 0, hi = NN;
            while (lo < hi) {
                int mid = (lo + hi) >> 1;
                if (batch[mid] < g) lo = mid + 1; else hi = mid;
            }
            segstart[g] = lo;
        }
        return;
    }
    const int r = b % 3, g = b / 3;
    if (r == 2) {
        // hist block g (g < 782)
        int e = (g * 256 + tid) * 4;
        if (e + 4 <= EE) {
            int4 d = *(const int4*)&dst[e];
            atomicAdd(&deg[d.x], 1); atomicAdd(&deg[d.y], 1);
            atomicAdd(&deg[d.z], 1); atomicAdd(&deg[d.w], 1);
        } else {
            for (; e < EE; ++e) atomicAdd(&deg[dst[e]], 1);
        }
        return;
    }
    gemm128_tile(g * 2 + r, x, W, out, sW16, sIn);   // tiles 0..1563
}

// ---------------- per-1024-chunk inclusive scan ----------------

__global__ __launch_bounds__(1024) void scanA_k(const int* __restrict__ deg,
                                                int* __restrict__ rowstart,
                                                int* __restrict__ blocksum) {
    __shared__ int buf[1024];
    int tid = threadIdx.x;
    int base = blockIdx.x * 1024;
    int v = (base + tid < NN) ? deg[base + tid] : 0;
    buf[tid] = v;
    __syncthreads();
    for (int o = 1; o < 1024; o <<= 1) {
        int t = (tid >= o) ? buf[tid - o] : 0;
        __syncthreads();
        buf[tid] += t;
        __syncthreads();
    }
    if (base + tid < NN) rowstart[base + tid + 1] = buf[tid];
    if (tid == 1023) blocksum[blockIdx.x] = buf[1023];
}

// ---------------- scanC with inline chunk-offset reduction ----------------

__global__ void scanC_k(int* __restrict__ rowstart, const int* __restrict__ blocksum,
                        int* __restrict__ cursor) {
    __shared__ int sOfs;
    const int b = blockIdx.x, tid = threadIdx.x;
    const int c = b >> 2;
    if (tid < 64) {
        int v = (tid < c) ? blocksum[tid] : 0;
        v += __shfl_xor(v, 1);  v += __shfl_xor(v, 2);  v += __shfl_xor(v, 4);
        v += __shfl_xor(v, 8);  v += __shfl_xor(v, 16); v += __shfl_xor(v, 32);
        if (tid == 0) sOfs = v;
    }
    __syncthreads();
    int i = b * 256 + tid;
    if (i >= NN) return;
    int val = rowstart[i + 1] + sOfs;
    rowstart[i + 1] = val;
    if (i + 1 < NN) cursor[i + 1] = val;
    if (i == 0) { rowstart[0] = 0; cursor[0] = 0; }
}

// ---------------- fused: CSR fill + gemm128 tiles [1564,3125) ----------------
// b<FG_BODY: r=b%3, g=b/3; r==2 -> fill g (g<781); else gemm tile 1564+g*2+r (guarded).
// b==FG_BODY: fill block 781.

__global__ __launch_bounds__(256) void fillgemm_k(
    const int* __restrict__ src, const int* __restrict__ dst,
    int* __restrict__ cursor, u16* __restrict__ csr16,
    const float* __restrict__ x, const float* __restrict__ W, u16* __restrict__ out)
{
    __shared__ u16 sW16[128 * 64];
    __shared__ float sIn[16 * 132];
    const int b = blockIdx.x, tid = threadIdx.x;

    int fillblk = -1;
    if (b == FG_BODY) fillblk = 781;
    else if (b % 3 == 2) fillblk = b / 3;   // < 781

    if (fillblk >= 0) {
        int e = (fillblk * 256 + tid) * 4;
        if (e + 4 <= EE) {
            int4 d = *(const int4*)&dst[e];
            int4 s = *(const int4*)&src[e];
            int p0 = atomicAdd(&cursor[d.x], 1);
            int p1 = atomicAdd(&cursor[d.y], 1);
            int p2 = atomicAdd(&cursor[d.z], 1);
            int p3 = atomicAdd(&cursor[d.w], 1);
            csr16[p0] = (u16)s.x; csr16[p1] = (u16)s.y;
            csr16[p2] = (u16)s.z; csr16[p3] = (u16)s.w;
        } else {
            for (; e < EE; ++e) { int p = atomicAdd(&cursor[dst[e]], 1); csr16[p] = (u16)src[e]; }
        }
        return;
    }
    const int r = b % 3, g = b / 3;
    int tile = 1564 + g * 2 + r;
    if (tile >= NT16) return;
    gemm128_tile(tile, x, W, out, sW16, sIn);
}

// ---------------- fused gather + W2 GEMM (layer 0 tail), 64-row tiles ----------------

__global__ __launch_bounds__(256) void agg_gemm_k(
    const u16* __restrict__ in,
    const int* __restrict__ rowstart, const u16* __restrict__ csr,
    const float* __restrict__ bias1,
    const float* __restrict__ W2, const float* __restrict__ bias2,
    u16* __restrict__ out, float* __restrict__ gstats)
{
    constexpr int KP = 68;
    __shared__ float sW[64 * 64];
    __shared__ float sIn[64 * KP];
    __shared__ float sStat[128];
    const int tid = threadIdx.x;

    for (int i = tid; i < 64 * 16; i += 256) ((float4*)sW)[i] = ((const float4*)W2)[i];

    const int tile = blockIdx.x * 64;
    const int nrows = min(64, NN - tile);
    const int l16 = tid & 15, gbase = tid & 48, grp = tid >> 4;
    float4 b1v = ((const float4*)bias1)[l16];
    for (int r = grp; r < nrows; r += 16) {
        int node = tile + r;
        float4 acc = ldbf4(in + (size_t)node * 64 + l16 * 4);
        gather16(acc, in, csr, rowstart[node], rowstart[node + 1], l16, gbase);
        acc.x = fmaxf(acc.x + b1v.x, 0.f); acc.y = fmaxf(acc.y + b1v.y, 0.f);
        acc.z = fmaxf(acc.z + b1v.z, 0.f); acc.w = fmaxf(acc.w + b1v.w, 0.f);
        *(float4*)&sIn[r * KP + l16 * 4] = acc;
    }
    __syncthreads();

    const int rg = (tid >> 4) * 4, c0 = (tid & 15) << 2;
    float4 bb = *(const float4*)&bias2[c0];
    float4 acc[4];
#pragma unroll
    for (int j = 0; j < 4; ++j) acc[j] = bb;
#pragma unroll 2
    for (int k4 = 0; k4 < 16; ++k4) {
        float4 av[4];
#pragma unroll
        for (int j = 0; j < 4; ++j) av[j] = *(const float4*)&sIn[(rg + j) * KP + k4 * 4];
        const float* wp = &sW[k4 * 4 * 64 + c0];
        float4 w0 = *(const float4*)(wp);
        float4 w1 = *(const float4*)(wp + 64);
        float4 w2 = *(const float4*)(wp + 128);
        float4 w3 = *(const float4*)(wp + 192);
#pragma unroll
        for (int j = 0; j < 4; ++j) {
            fma4(acc[j], w0, av[j].x); fma4(acc[j], w1, av[j].y);
            fma4(acc[j], w2, av[j].z); fma4(acc[j], w3, av[j].w);
        }
    }
#pragma unroll
    for (int j = 0; j < 4; ++j) {
        acc[j].x = fmaxf(acc[j].x, 0.f); acc[j].y = fmaxf(acc[j].y, 0.f);
        acc[j].z = fmaxf(acc[j].z, 0.f); acc[j].w = fmaxf(acc[j].w, 0.f);
        if (rg + j < nrows) stbf4(out + (size_t)(tile + rg + j) * 64 + c0, acc[j]);
    }
    if (tid < 128) sStat[tid] = 0.f;
    __syncthreads();
    float sx = 0, sy = 0, sz = 0, sw = 0, qx = 0, qy = 0, qz = 0, qw = 0;
#pragma unroll
    for (int j = 0; j < 4; ++j) {
        if (rg + j < nrows) {
            sx += acc[j].x; sy += acc[j].y; sz += acc[j].z; sw += acc[j].w;
            qx += acc[j].x * acc[j].x; qy += acc[j].y * acc[j].y;
            qz += acc[j].z * acc[j].z; qw += acc[j].w * acc[j].w;
        }
    }
    atomicAdd(&sStat[c0 + 0], sx); atomicAdd(&sStat[c0 + 1], sy);
    atomicAdd(&sStat[c0 + 2], sz); atomicAdd(&sStat[c0 + 3], sw);
    atomicAdd(&sStat[64 + c0 + 0], qx); atomicAdd(&sStat[64 + c0 + 1], qy);
    atomicAdd(&sStat[64 + c0 + 2], qz); atomicAdd(&sStat[64 + c0 + 3], qw);
    __syncthreads();
    if (tid < 128) atomicAdd(&gstats[tid], sStat[tid]);
}

// ---------------- fully fused GIN layer (layers 1,2), 64-row tiles ----------------

__global__ __launch_bounds__(256) void fused_layer_k(
    const u16* __restrict__ in,
    const int* __restrict__ rowstart, const u16* __restrict__ csr,
    const float* __restrict__ bnst, const float* __restrict__ gam, const float* __restrict__ bet,
    const float* __restrict__ W1, const float* __restrict__ b1,
    const float* __restrict__ W2, const float* __restrict__ b2,
    u16* __restrict__ out, float* __restrict__ gstats)
{
    constexpr int KP = 68;
    __shared__ float sW[64 * 64];      // W1 then reloaded with W2
    __shared__ float sAgg[64 * KP];
    __shared__ float sStat[128];
    __shared__ float aL[64], dL[64];
    const int tid = threadIdx.x;

    for (int i = tid; i < 64 * 16; i += 256) ((float4*)sW)[i] = ((const float4*)W1)[i];
    if (tid < 64) {
        float m = bnst[tid] * (1.f / NN);
        float v = bnst[64 + tid] * (1.f / NN) - m * m;
        float a = rsqrtf(v + 1e-5f) * gam[tid];
        aL[tid] = a;
        dL[tid] = bet[tid] - m * a;
    }
    __syncthreads();

    const int tile = blockIdx.x * 64;
    const int nrows = min(64, NN - tile);
    const int l16 = tid & 15, gbase = tid & 48, grp = tid >> 4;
    float4 av4 = *(const float4*)&aL[l16 * 4];
    float4 dv4 = *(const float4*)&dL[l16 * 4];
    for (int r = grp; r < nrows; r += 16) {
        int node = tile + r;
        int e0s = rowstart[node], e1s = rowstart[node + 1];
        float4 acc = ldbf4(in + (size_t)node * 64 + l16 * 4);
        gather16(acc, in, csr, e0s, e1s, l16, gbase);
        float dp1 = (float)(e1s - e0s + 1);
        acc.x = fmaf(av4.x, acc.x, dp1 * dv4.x);
        acc.y = fmaf(av4.y, acc.y, dp1 * dv4.y);
        acc.z = fmaf(av4.z, acc.z, dp1 * dv4.z);
        acc.w = fmaf(av4.w, acc.w, dp1 * dv4.w);
        *(float4*)&sAgg[r * KP + l16 * 4] = acc;
    }
    __syncthreads();

    const int rg = (tid >> 4) * 4, c0 = (tid & 15) << 2;
    float4 t[4];
    {
        float4 bb = *(const float4*)&b1[c0];
#pragma unroll
        for (int j = 0; j < 4; ++j) t[j] = bb;
#pragma unroll 2
        for (int k4 = 0; k4 < 16; ++k4) {
            float4 a0[4];
#pragma unroll
            for (int j = 0; j < 4; ++j) a0[j] = *(const float4*)&sAgg[(rg + j) * KP + k4 * 4];
            const float* wp = &sW[k4 * 4 * 64 + c0];
            float4 w0 = *(const float4*)(wp);
            float4 w1 = *(const float4*)(wp + 64);
            float4 w2 = *(const float4*)(wp + 128);
            float4 w3 = *(const float4*)(wp + 192);
#pragma unroll
            for (int j = 0; j < 4; ++j) {
                fma4(t[j], w0, a0[j].x); fma4(t[j], w1, a0[j].y);
                fma4(t[j], w2, a0[j].z); fma4(t[j], w3, a0[j].w);
            }
        }
#pragma unroll
        for (int j = 0; j < 4; ++j) {
            t[j].x = fmaxf(t[j].x, 0.f); t[j].y = fmaxf(t[j].y, 0.f);
            t[j].z = fmaxf(t[j].z, 0.f); t[j].w = fmaxf(t[j].w, 0.f);
        }
    }
    __syncthreads();

    for (int i = tid; i < 64 * 16; i += 256) ((float4*)sW)[i] = ((const float4*)W2)[i];
#pragma unroll
    for (int j = 0; j < 4; ++j) *(float4*)&sAgg[(rg + j) * KP + c0] = t[j];
    __syncthreads();

    float4 acc[4];
    {
        float4 bb = *(const float4*)&b2[c0];
#pragma unroll
        for (int j = 0; j < 4; ++j) acc[j] = bb;
#pragma unroll 2
        for (int k4 = 0; k4 < 16; ++k4) {
            float4 a0[4];
#pragma unroll
            for (int j = 0; j < 4; ++j) a0[j] = *(const float4*)&sAgg[(rg + j) * KP + k4 * 4];
            const float* wp = &sW[k4 * 4 * 64 + c0];
            float4 w0 = *(const float4*)(wp);
            float4 w1 = *(const float4*)(wp + 64);
            float4 w2 = *(const float4*)(wp + 128);
            float4 w3 = *(const float4*)(wp + 192);
#pragma unroll
            for (int j = 0; j < 4; ++j) {
                fma4(acc[j], w0, a0[j].x); fma4(acc[j], w1, a0[j].y);
                fma4(acc[j], w2, a0[j].z); fma4(acc[j], w3, a0[j].w);
            }
        }
    }
#pragma unroll
    for (int j = 0; j < 4; ++j) {
        acc[j].x = fmaxf(acc[j].x, 0.f); acc[j].y = fmaxf(acc[j].y, 0.f);
        acc[j].z = fmaxf(acc[j].z, 0.f); acc[j].w = fmaxf(acc[j].w, 0.f);
        if (rg + j < nrows) stbf4(out + (size_t)(tile + rg + j) * 64 + c0, acc[j]);
    }
    if (tid < 128) sStat[tid] = 0.f;
    __syncthreads();
    float sx = 0, sy = 0, sz = 0, sw = 0, qx = 0, qy = 0, qz = 0, qw = 0;
#pragma unroll
    for (int j = 0; j < 4; ++j) {
        if (rg + j < nrows) {
            sx += acc[j].x; sy += acc[j].y; sz += acc[j].z; sw += acc[j].w;
            qx += acc[j].x * acc[j].x; qy += acc[j].y * acc[j].y;
            qz += acc[j].z * acc[j].z; qw += acc[j].w * acc[j].w;
        }
    }
    atomicAdd(&sStat[c0 + 0], sx); atomicAdd(&sStat[c0 + 1], sy);
    atomicAdd(&sStat[c0 + 2], sz); atomicAdd(&sStat[c0 + 3], sw);
    atomicAdd(&sStat[64 + c0 + 0], qx); atomicAdd(&sStat[64 + c0 + 1], qy);
    atomicAdd(&sStat[64 + c0 + 2], qz); atomicAdd(&sStat[64 + c0 + 3], qw);
    __syncthreads();
    if (tid < 128) atomicAdd(&gstats[tid], sStat[tid]);
}

// ---------------- generic 64-K GEMM tile body (dynamic LDS) ----------------

template<bool STATS, bool ROWSCALE, bool BNIN, bool INBF, bool OUTBF>
__device__ void gemm_dev(char* smem, int tile, int rows,
    const void* __restrict__ in, const float* __restrict__ W, const float* __restrict__ Wb,
    const float* __restrict__ bias, const float* __restrict__ bias2,
    void* __restrict__ out, void* __restrict__ out2,
    float* __restrict__ gstats, float* __restrict__ gstats2,
    const float* __restrict__ attn, const float* __restrict__ noise,
    const float* __restrict__ bnstats, const float* __restrict__ gamma,
    const float* __restrict__ beta)
{
    constexpr int KP = 68;
    float* sW    = (float*)smem;
    float* sWb   = sW + 64 * 64;
    float* sIn   = sWb + 64 * 64;
    float* sStat = sIn + 64 * KP;
    float* sA    = sStat + 256;
    float* sD    = sA + 64;
    const int tid = threadIdx.x;

    for (int i = tid; i < 64 * 16; i += 256) {
        ((float4*)sW)[i]  = ((const float4*)W)[i];
        ((float4*)sWb)[i] = ((const float4*)Wb)[i];
    }
    if (BNIN && tid < 64) {
        float m = bnstats[tid] * (1.f / NN);
        float v = bnstats[64 + tid] * (1.f / NN) - m * m;
        float a = rsqrtf(v + 1e-5f) * gamma[tid];
        sA[tid] = a;
        sD[tid] = beta[tid] - m * a;
    }
    __syncthreads();

    int nrows = min(64, rows - tile);
    const float4* igf = INBF ? nullptr : (const float4*)((const float*)in + (size_t)tile * 64);
    const u16*    igb = INBF ? ((const u16*)in + (size_t)tile * 64) : nullptr;
    const float4* ng  = ROWSCALE ? (const float4*)(noise + (size_t)tile * 64) : nullptr;
    for (int i = tid; i < nrows * 16; i += 256) {
        int rr = i >> 4, kk = (i & 15) * 4;
        float4 t = INBF ? ldbf4(igb + i * 4) : igf[i];
        if (BNIN) {
            t.x = fmaf(sA[kk + 0], t.x, sD[kk + 0]);
            t.y = fmaf(sA[kk + 1], t.y, sD[kk + 1]);
            t.z = fmaf(sA[kk + 2], t.z, sD[kk + 2]);
            t.w = fmaf(sA[kk + 3], t.w, sD[kk + 3]);
        }
        if (ROWSCALE) {
            float4 nv = ng[i];
            float at = attn[tile + rr];
            t.x = fmaf(at, t.x, nv.x); t.y = fmaf(at, t.y, nv.y);
            t.z = fmaf(at, t.z, nv.z); t.w = fmaf(at, t.w, nv.w);
        }
        *(float4*)&sIn[rr * KP + kk] = t;
    }
    __syncthreads();

    const int rg = (tid >> 4) * 4, c0 = (tid & 15) << 2;
    float4 bb  = *(const float4*)&bias[c0];
    float4 bb2 = *(const float4*)&bias2[c0];
    float4 acc[4], acc2[4];
#pragma unroll
    for (int j = 0; j < 4; ++j) { acc[j] = bb; acc2[j] = bb2; }
#pragma unroll 2
    for (int k4 = 0; k4 < 16; ++k4) {
        float4 av[4];
#pragma unroll
        for (int j = 0; j < 4; ++j)
            av[j] = *(const float4*)&sIn[(rg + j) * KP + k4 * 4];
        const float* wp = &sW[k4 * 4 * 64 + c0];
        float4 w0 = *(const float4*)(wp);
        float4 w1 = *(const float4*)(wp + 64);
        float4 w2 = *(const float4*)(wp + 128);
        float4 w3 = *(const float4*)(wp + 192);
#pragma unroll
        for (int j = 0; j < 4; ++j) {
            fma4(acc[j], w0, av[j].x); fma4(acc[j], w1, av[j].y);
            fma4(acc[j], w2, av[j].z); fma4(acc[j], w3, av[j].w);
        }
        const float* wq = &sWb[k4 * 4 * 64 + c0];
        float4 u0 = *(const float4*)(wq);
        float4 u1 = *(const float4*)(wq + 64);
        float4 u2 = *(const float4*)(wq + 128);
        float4 u3 = *(const float4*)(wq + 192);
#pragma unroll
        for (int j = 0; j < 4; ++j) {
            fma4(acc2[j], u0, av[j].x); fma4(acc2[j], u1, av[j].y);
            fma4(acc2[j], u2, av[j].z); fma4(acc2[j], u3, av[j].w);
        }
    }
#pragma unroll
    for (int j = 0; j < 4; ++j) {
        acc[j].x = fmaxf(acc[j].x, 0.f);   acc[j].y = fmaxf(acc[j].y, 0.f);
        acc[j].z = fmaxf(acc[j].z, 0.f);   acc[j].w = fmaxf(acc[j].w, 0.f);
        acc2[j].x = fmaxf(acc2[j].x, 0.f); acc2[j].y = fmaxf(acc2[j].y, 0.f);
        acc2[j].z = fmaxf(acc2[j].z, 0.f); acc2[j].w = fmaxf(acc2[j].w, 0.f);
        int r = rg + j;
        if (r < nrows) {
            if (OUTBF) {
                stbf4((u16*)out  + (size_t)(tile + r) * 64 + c0, acc[j]);
                stbf4((u16*)out2 + (size_t)(tile + r) * 64 + c0, acc2[j]);
            } else {
                *(float4*)((float*)out  + (size_t)(tile + r) * 64 + c0) = acc[j];
                *(float4*)((float*)out2 + (size_t)(tile + r) * 64 + c0) = acc2[j];
            }
        }
    }
    if (STATS) {
        if (tid < 256) sStat[tid] = 0.f;
        __syncthreads();
        float sx = 0, sy = 0, sz = 0, sw = 0, qx = 0, qy = 0, qz = 0, qw = 0;
        float sx2 = 0, sy2 = 0, sz2 = 0, sw2 = 0, qx2 = 0, qy2 = 0, qz2 = 0, qw2 = 0;
#pragma unroll
        for (int j = 0; j < 4; ++j) {
            if (rg + j < nrows) {
                sx += acc[j].x; sy += acc[j].y; sz += acc[j].z; sw += acc[j].w;
                qx += acc[j].x * acc[j].x; qy += acc[j].y * acc[j].y;
                qz += acc[j].z * acc[j].z; qw += acc[j].w * acc[j].w;
                sx2 += acc2[j].x; sy2 += acc2[j].y; sz2 += acc2[j].z; sw2 += acc2[j].w;
                qx2 += acc2[j].x * acc2[j].x; qy2 += acc2[j].y * acc2[j].y;
                qz2 += acc2[j].z * acc2[j].z; qw2 += acc2[j].w * acc2[j].w;
            }
        }
        atomicAdd(&sStat[c0 + 0], sx); atomicAdd(&sStat[c0 + 1], sy);
        atomicAdd(&sStat[c0 + 2], sz); atomicAdd(&sStat[c0 + 3], sw);
        atomicAdd(&sStat[64 + c0 + 0], qx); atomicAdd(&sStat[64 + c0 + 1], qy);
        atomicAdd(&sStat[64 + c0 + 2], qz); atomicAdd(&sStat[64 + c0 + 3], qw);
        atomicAdd(&sStat[128 + c0 + 0], sx2); atomicAdd(&sStat[128 + c0 + 1], sy2);
        atomicAdd(&sStat[128 + c0 + 2], sz2); atomicAdd(&sStat[128 + c0 + 3], sw2);
        atomicAdd(&sStat[192 + c0 + 0], qx2); atomicAdd(&sStat[192 + c0 + 1], qy2);
        atomicAdd(&sStat[192 + c0 + 2], qz2); atomicAdd(&sStat[192 + c0 + 3], qw2);
        __syncthreads();
        if (tid < 128) atomicAdd(&gstats[tid], sStat[tid]);
        else atomicAdd(&gstats2[tid - 128], sStat[tid]);
    }
}

// ---------------- heads: node DUAL gemm + graph DUAL gemm, one launch ----------------

__global__ __launch_bounds__(256) void heads_k(
    const u16* __restrict__ z2, const float* __restrict__ attn, const float* __restrict__ noise,
    const float* __restrict__ s2, const float* __restrict__ bng2, const float* __restrict__ bnb2,
    const float* __restrict__ nmW, const float* __restrict__ nmb,
    const float* __restrict__ nlW, const float* __restrict__ nlb,
    u16* __restrict__ nmu_b, u16* __restrict__ nlv_b,
    float* __restrict__ s3, float* __restrict__ s4,
    const float* __restrict__ slots,
    const float* __restrict__ gmW, const float* __restrict__ gmb,
    const float* __restrict__ glW, const float* __restrict__ glb,
    float* __restrict__ gpre1, float* __restrict__ gpre2,
    float* __restrict__ s5, float* __restrict__ s6)
{
    extern __shared__ char smem[];
    if (blockIdx.x < NT64) {
        gemm_dev<true, true, true, true, true>(smem, blockIdx.x * 64, NN,
            z2, nmW, nlW, nmb, nlb, nmu_b, nlv_b, s3, s4, attn, noise, s2, bng2, bnb2);
    } else {
        gemm_dev<true, false, false, false, false>(smem, (int)(blockIdx.x - NT64) * 64, GG,
            slots, gmW, glW, gmb, glb, gpre1, gpre2, s5, s6,
            nullptr, nullptr, nullptr, nullptr, nullptr);
    }
}

// ---------------- merged BN apply: node pair (bf16 in) + graph pair (fp32 in) ----------------

__global__ void bn_all_k(const u16* __restrict__ n1, const u16* __restrict__ n2,
                         const float* __restrict__ g1in, const float* __restrict__ g2in,
                         float* __restrict__ o1, float* __restrict__ o2,
                         float* __restrict__ o3, float* __restrict__ o4,
                         const float* __restrict__ st3, const float* __restrict__ st4,
                         const float* __restrict__ st5, const float* __restrict__ st6,
                         const float* __restrict__ pj_g, const float* __restrict__ pj_b) {
    int total = NN * 64 + GG * 64;
    for (int i = blockIdx.x * blockDim.x + threadIdx.x; i < total; i += gridDim.x * blockDim.x) {
        if (i < NN * 64) {
            int c = i & 63;
            float m1 = st3[c] * (1.f / NN);
            float v1 = st3[64 + c] * (1.f / NN) - m1 * m1;
            o1[i] = (bf2f(n1[i]) - m1) * rsqrtf(v1 + 1e-5f) * pj_g[c] + pj_b[c];
            float m2 = st4[c] * (1.f / NN);
            float v2 = st4[64 + c] * (1.f / NN) - m2 * m2;
            o2[i] = (bf2f(n2[i]) - m2) * rsqrtf(v2 + 1e-5f) * pj_g[64 + c] + pj_b[64 + c];
        } else {
            int j = i - NN * 64;
            int c = j & 63;
            float m1 = st5[c] * (1.f / GG);
            float v1 = st5[64 + c] * (1.f / GG) - m1 * m1;
            o3[j] = (g1in[j] - m1) * rsqrtf(v1 + 1e-5f) * pj_g[128 + c] + pj_b[128 + c];
            float m2 = st6[c] * (1.f / GG);
            float v2 = st6[64 + c] * (1.f / GG) - m2 * m2;
            o4[j] = (g2in[j] - m2) * rsqrtf(v2 + 1e-5f) * pj_g[192 + c] + pj_b[192 + c];
        }
    }
}

// ---------------- attention on z (bf16) directly; 512 threads, 8 scan groups ----------------

__global__ __launch_bounds__(512) void attn3_k(
    const u16* __restrict__ z, const int* __restrict__ segst,
    const float* __restrict__ bnst, const float* __restrict__ gam, const float* __restrict__ bet,
    const float* __restrict__ Wq, const float* __restrict__ Wk, const float* __restrict__ Wv,
    const float* __restrict__ Wih, const float* __restrict__ Whh,
    const float* __restrict__ bih, const float* __restrict__ bhh,
    float* __restrict__ attn, float* __restrict__ slots_out)
{
    int g = blockIdx.x, tid = threadIdx.x, w = tid >> 6, lane = tid & 63;
    __shared__ float ssl[64], sq[64], swr[64], sm[64], supd[64], sred[512], ssum[8];
    __shared__ float aL[64], dL[64];
    __shared__ float sgi[192], sgh[192];
    __shared__ float sc, sinv;

    int s0 = segst[g], s1 = segst[g + 1];
    if (tid < 64) {
        float m = bnst[tid] * (1.f / NN);
        float v = bnst[64 + tid] * (1.f / NN) - m * m;
        float a = rsqrtf(v + 1e-5f) * gam[tid];
        aL[tid] = a;
        dL[tid] = bet[tid] - m * a;
    }
    __syncthreads();

    {
        float macc = 0.f;
        for (int n = s0 + w; n < s1; n += 8) macc += bf2f(z[(size_t)n * 64 + lane]);
        sred[tid] = macc;
        __syncthreads();
        if (tid < 64) {
            float s = 0.f;
#pragma unroll
            for (int k = 0; k < 8; ++k) s += sred[tid + 64 * k];
            ssl[tid] = fmaf(aL[tid], s / (float)max(s1 - s0, 1), dL[tid]);
        }
        __syncthreads();
    }

    for (int it = 0; it < 2; ++it) {
        {
            float p = 0.f;
#pragma unroll
            for (int kk = 0; kk < 8; ++kk) p += ssl[w * 8 + kk] * Wq[(w * 8 + kk) * 64 + lane];
            sred[tid] = p;
        }
        __syncthreads();
        if (tid < 64) {
            float s = 0.f;
#pragma unroll
            for (int k = 0; k < 8; ++k) s += sred[tid + 64 * k];
            sq[tid] = s;
        }
        __syncthreads();
        {
            float p = 0.f;
#pragma unroll
            for (int kk = 0; kk < 8; ++kk) p += Wk[lane * 64 + w * 8 + kk] * sq[w * 8 + kk];
            sred[tid] = p;
        }
        __syncthreads();
        if (tid < 64) {
            float s = 0.f;
#pragma unroll
            for (int k = 0; k < 8; ++k) s += sred[tid + 64 * k];
            swr[tid] = s;
        }
        __syncthreads();
        if (tid < 64) {
            float pr = dL[tid] * swr[tid];
            pr += __shfl_xor(pr, 1);  pr += __shfl_xor(pr, 2);  pr += __shfl_xor(pr, 4);
            pr += __shfl_xor(pr, 8);  pr += __shfl_xor(pr, 16); pr += __shfl_xor(pr, 32);
            if (tid == 0) sc = pr * 0.125f;
            swr[tid] = aL[tid] * swr[tid] * 0.125f;
        }
        __syncthreads();
        float wl = swr[lane], cc = sc;

        float s = 0.f, u = 0.f;
        for (int n = s0 + w; n < s1; n += 8) {
            float zl = bf2f(z[(size_t)n * 64 + lane]);
            float l = zl * wl;
            l += __shfl_xor(l, 1);  l += __shfl_xor(l, 2);  l += __shfl_xor(l, 4);
            l += __shfl_xor(l, 8);  l += __shfl_xor(l, 16); l += __shfl_xor(l, 32);
            float e = expf(l + cc);
            if (lane == 0) attn[n] = e;
            s += e;
            u = fmaf(e, zl, u);
        }
        sred[tid] = u;
        if (lane == 0) ssum[w] = s;
        __syncthreads();
        if (tid < 64) {
            float stot = ssum[0] + ssum[1] + ssum[2] + ssum[3]
                       + ssum[4] + ssum[5] + ssum[6] + ssum[7] + 1e-9f;
            if (tid == 0) sinv = 1.f / stot;
            float uu = 0.f;
#pragma unroll
            for (int k = 0; k < 8; ++k) uu += sred[tid + 64 * k];
            sm[tid] = fmaf(aL[tid], uu / stot, dL[tid]);
        }
        __syncthreads();
        {
            float p = 0.f;
#pragma unroll
            for (int kk = 0; kk < 8; ++kk) p += sm[w * 8 + kk] * Wv[(w * 8 + kk) * 64 + lane];
            sred[tid] = p;
        }
        __syncthreads();
        if (tid < 64) {
            float s2 = 0.f;
#pragma unroll
            for (int k = 0; k < 8; ++k) s2 += sred[tid + 64 * k];
            supd[tid] = s2;
        }
        __syncthreads();

        if (it == 1) {
            float inv = sinv;
            for (int n = s0 + tid; n < s1; n += 512) attn[n] *= inv;
        }

        if (tid < 192) {
            float a = bih[tid], b = bhh[tid];
            const float* wi = &Wih[tid * 64];
            const float* wh = &Whh[tid * 64];
#pragma unroll 8
            for (int j = 0; j < 64; ++j) { a += supd[j] * wi[j]; b += ssl[j] * wh[j]; }
            sgi[tid] = a; sgh[tid] = b;
        }
        __syncthreads();
        if (tid < 64) {
            float r  = 1.f / (1.f + expf(-(sgi[tid] + sgh[tid])));
            float zz = 1.f / (1.f + expf(-(sgi[64 + tid] + sgh[64 + tid])));
            float nn = tanhf(sgi[128 + tid] + r * sgh[128 + tid]);
            float ns = (1.f - zz) * nn + zz * ssl[tid];
            ssl[tid] = ns;
            if (it == 1) slots_out[g * 64 + tid] = ns;
        }
        __syncthreads();
    }
}

// ---------------- host side ----------------

extern "C" void kernel_launch(void* const* d_in, const int* in_sizes, int n_in,
                              void* d_out, int out_size, void* d_ws, size_t ws_size,
                              hipStream_t stream) {
    (void)in_sizes; (void)n_in; (void)out_size; (void)ws_size;

    const float* x      = (const float*)d_in[0];
    const int*   ei     = (const int*)d_in[1];
    const int*   srcI   = ei;
    const int*   dstI   = ei + EE;
    const int*   batch  = (const int*)d_in[2];
    const float* noise  = (const float*)d_in[3];
    const float* W1_0   = (const float*)d_in[4];
    const float* b1_0   = (const float*)d_in[5];
    const float* W2_0   = (const float*)d_in[6];
    const float* b2_0   = (const float*)d_in[7];
    const float* W1_r   = (const float*)d_in[8];
    const float* b1_r   = (const float*)d_in[9];
    const float* W2_r   = (const float*)d_in[10];
    const float* b2_r   = (const float*)d_in[11];
    const float* bn_g   = (const float*)d_in[12];
    const float* bn_b   = (const float*)d_in[13];
    const float* Wq     = (const float*)d_in[14];
    const float* Wk     = (const float*)d_in[15];
    const float* Wv     = (const float*)d_in[16];
    const float* Wih    = (const float*)d_in[17];
    const float* Whh    = (const float*)d_in[18];
    const float* bih    = (const float*)d_in[19];
    const float* bhh    = (const float*)d_in[20];
    const float* nmW    = (const float*)d_in[21];
    const float* nmb    = (const float*)d_in[22];
    const float* nlW    = (const float*)d_in[23];
    const float* nlb    = (const float*)d_in[24];
    const float* gmW    = (const float*)d_in[25];
    const float* gmb    = (const float*)d_in[26];
    const float* glW    = (const float*)d_in[27];
    const float* glb    = (const float*)d_in[28];
    const float* pj_g   = (const float*)d_in[29];
    const float* pj_b   = (const float*)d_in[30];

    char* w = (char*)d_ws;
    u16*   B0b   = (u16*)w;            w += (size_t)NN * 64 * 2;
    u16*   B1b   = (u16*)w;            w += (size_t)NN * 64 * 2;
    u16*   B2b   = (u16*)w;            w += (size_t)NN * 64 * 2;
    float* slots = (float*)w;          w += GG * 64 * 4;
    float* gpre1 = (float*)w;          w += GG * 64 * 4;
    float* gpre2 = (float*)w;          w += GG * 64 * 4;
    float* attn  = (float*)w;          w += NN * 4;
    int*   cursor= (int*)w;            w += NN * 4;          // cursor + stats adjacent: one memset
    float* stats = (float*)w;          w += 7 * 128 * 4;
    int*   segst = (int*)w;            w += (GG + 1) * 4;
    int*   rowst = (int*)w;            w += (NN + 1) * 4;
    int*   bsum  = (int*)w;            w += 64 * 4;
    u16*   csr16 = (u16*)w;            w += (size_t)EE * 2;

    float* s0 = stats, *s1 = stats + 128, *s2 = stats + 256, *s3 = stats + 384,
         * s4 = stats + 512, *s5 = stats + 640, *s6 = stats + 768;

    float* outp = (float*)d_out;
    float* out_nmu = outp;
    float* out_nlv = outp + NN * DD;
    float* out_gmu = outp + 2 * NN * DD;
    float* out_glv = outp + 2 * NN * DD + GG * DD;

    constexpr int NB = (NN + 1023) / 1024;       // 49 scan chunks
    constexpr int NCB = (NN + 255) / 256;        // 196 scanC blocks
    constexpr size_t HEAD_SMEM = (64 * 64 * 2 + 64 * 68 + 256 + 128) * sizeof(float);

#define GK(...) <<<__VA_ARGS__>>>
    // ---------- init (memset) + fused hist/seg/gemm-half1 + prefix ----------
    hipMemsetAsync(cursor, 0, (size_t)NN * 4 + 7 * 128 * 4, stream);
    histgemm_k GK(HG_NBLK, 256, 0, stream)(dstI, cursor, batch, segst, x, W1_0, B0b);
    scanA_k GK(NB, 1024, 0, stream)(cursor, rowst, bsum);
    scanC_k GK(NCB, 256, 0, stream)(rowst, bsum, cursor);

    // ---------- fused: CSR fill + gemm-half2 (interleaved co-run) ----------
    fillgemm_k GK(FG_NBLK, 256, 0, stream)(srcI, dstI, cursor, csr16, x, W1_0, B0b);

    // ---------- GIN layer 0 tail: fused gather+W2 ----------
    agg_gemm_k GK(NT64, 256, 0, stream)(B0b, rowst, csr16, b1_0, W2_0, b2_0, B1b, s0);

    // ---------- GIN layers 1,2 ----------
    fused_layer_k GK(NT64, 256, 0, stream)(B1b, rowst, csr16, s0, bn_g + 0, bn_b + 0,
                                           W1_r, b1_r, W2_r, b2_r, B2b, s1);
    fused_layer_k GK(NT64, 256, 0, stream)(B2b, rowst, csr16, s1, bn_g + 64, bn_b + 64,
                                           W1_r + DD * DD, b1_r + DD, W2_r + DD * DD, b2_r + DD,
                                           B0b, s2);
    // B0b = z2 (pre-BN, relu'd, bf16)

    // ---------- summary maker ----------
    attn3_k GK(GG, 512, 0, stream)(B0b, segst, s2, bn_g + 128, bn_b + 128,
                                   Wq, Wk, Wv, Wih, Whh, bih, bhh, attn, slots);

    // ---------- heads ----------
    heads_k GK(NT64 + 8, 256, HEAD_SMEM, stream)(
        B0b, attn, noise, s2, bn_g + 128, bn_b + 128,
        nmW, nmb, nlW, nlb, B1b, B2b, s3, s4,
        slots, gmW, gmb, glW, glb, gpre1, gpre2, s5, s6);

    // ---------- merged final BN ----------
    bn_all_k GK(2048, 256, 0, stream)(B1b, B2b, gpre1, gpre2,
                                      out_nmu, out_nlv, out_gmu, out_glv,
                                      s3, s4, s5, s6, pj_g, pj_b);
#undef GK
}